// Round 2
// baseline (322.824 us; speedup 1.0000x reference)
//
#include <hip/hip_runtime.h>
#include <hip/hip_bf16.h>
#include <cstdint>
#include <cstddef>

#define TOK    8192
#define DMODEL 1024
#define HDIM   2048
#define MDIM   64
#define NEXP   8
#define HHALF  1024

using f32x4  = __attribute__((ext_vector_type(4))) float;
using bf16x8 = __attribute__((ext_vector_type(8))) __bf16;
using bf16x4 = __attribute__((ext_vector_type(4))) __bf16;

// async global->LDS, 16B per lane. LDS dest is wave-uniform base + lane*16.
__device__ __forceinline__ void async16(const void* g, void* l) {
  __builtin_amdgcn_global_load_lds(
      (const __attribute__((address_space(1))) unsigned int*)g,
      (__attribute__((address_space(3))) unsigned int*)l, 16, 0, 0);
}
__device__ __forceinline__ void wait_vm6() { asm volatile("s_waitcnt vmcnt(6)" ::: "memory"); }
__device__ __forceinline__ void wait_vm0() { asm volatile("s_waitcnt vmcnt(0)" ::: "memory"); }

// One-launch preamble: cvt(X) + transpose-cvt of all 6 weight tensors.
__global__ __launch_bounds__(256) void preamble_kernel(
    const float* __restrict__ X, __bf16* __restrict__ Xb,
    const float* __restrict__ encW, __bf16* __restrict__ encWT,
    const float* __restrict__ s2cW, __bf16* __restrict__ s2cWT,
    const float* __restrict__ c2sW, __bf16* __restrict__ c2sWT,
    const float* __restrict__ decW, __bf16* __restrict__ decWT,
    const float* __restrict__ We1, __bf16* __restrict__ We1T,
    const float* __restrict__ We2, __bf16* __restrict__ We2T) {
  __shared__ float ts[32][33];
  const int tid = threadIdx.x;
  int b = blockIdx.x;
  if (b < 8192) {  // X: 8192x1024 fp32 -> bf16 (float4 per thread)
    int i = b * 256 + tid;
    float4 v = ((const float4*)X)[i];
    bf16x4 o = { (__bf16)v.x, (__bf16)v.y, (__bf16)v.z, (__bf16)v.w };
    ((bf16x4*)Xb)[i] = o;
    return;
  }
  b -= 8192;
  const float* in; __bf16* outp; int R, C, tx, ty;
  if (b < 2048)              { in = encW; outp = encWT; R = 1024; C = 2048; tx = b % 64; ty = b / 64; }
  else if ((b -= 2048) < 128){ in = s2cW; outp = s2cWT; R = 2048; C = 64;   tx = b % 2;  ty = b / 2;  }
  else if ((b -= 128) < 128) { in = c2sW; outp = c2sWT; R = 64;   C = 2048; tx = b % 64; ty = b / 64; }
  else if ((b -= 128) < 2048){ in = decW; outp = decWT; R = 2048; C = 1024; tx = b % 32; ty = b / 32; }
  else if ((b -= 2048) < 512){ int s = b / 64, t = b % 64;
                               in = We1 + (size_t)s * 65536; outp = We1T + (size_t)s * 65536;
                               R = 64; C = 1024; tx = t % 32; ty = t / 32; }
  else                       { b -= 512; int s = b / 64, t = b % 64;
                               in = We2 + (size_t)s * 65536; outp = We2T + (size_t)s * 65536;
                               R = 1024; C = 64; tx = t % 2; ty = t / 2; }
  const int c0 = tx * 32, r0 = ty * 32;
  const int x = tid & 31, y = tid >> 5;
  #pragma unroll
  for (int i = y; i < 32; i += 8) ts[i][x] = in[(size_t)(r0 + i) * C + c0 + x];
  __syncthreads();
  #pragma unroll
  for (int i = y; i < 32; i += 8)
    outp[(size_t)(c0 + i) * R + r0 + x] = (__bf16)ts[x][i];
}
#define PREAMBLE_BLOCKS (8192 + 2048 + 128 + 128 + 2048 + 512 + 512)

// C = act(A @ Bt^T [+ bias]); A: MxK bf16 (row-major), Bt: NxK bf16.
// BK=64, global_load_lds staging, XOR-swizzled 16B chunks, hoisted pointers.
// Non-SUMA: 3-buffer pipeline, 2 tiles in flight, counted vmcnt(6) (T4):
//   prologue: stage(b0); stage(b1);
//   iter it : wait vmcnt(6|0) [tile it landed, it+1 still flying]
//             s_barrier        [globalizes landing; proves tile it-1 readers done]
//             stage(b[it+2])   [overwrites tile it-1's buffer -- dead by barrier]
//             compute(b[it])
// One barrier per K-step; loads never drain to 0 in steady state. 1 block/CU
// at 144KB LDS for the 8-wave 128x256 config -- deep prefetch replaces
// cross-block overlap (2-buffer vmcnt(0) version measured MfmaUtil 25%,
// ~1200 cyc/iter exposed latency).
// Wave tiling: WAVES_M=2 x WAVES_N=WAVES/2; per-wave output 64x64 always.
// SUMA: A-tile = bf16(A + A2) staged via register path (K=64 one-shot),
// single-buffered (niter==1; 32KB LDS keeps occupancy).
// Split-K via gridDim.z: z-slice computes K/gridDim.z, writes slab at Cout + z*M*N.
template <int BM, int BN, int WAVES, int OUT_BF16, int ACT, int BIAS, int SUMA>
__global__ __launch_bounds__(WAVES * 64) void gemm_bt(
    const __bf16* __restrict__ A, const __bf16* __restrict__ Bt,
    const float* __restrict__ bias, void* __restrict__ Cout,
    int M, int N, int K, const __bf16* __restrict__ A2) {
  constexpr int BK = 64;               // 8 chunks of 16B per row
  constexpr int WAVES_N = WAVES / 2;
  constexpr int WTM = BM / 32;                  // per-wave M frags (wm span BM/2)
  constexpr int WTN = BN / (WAVES_N * 16);      // per-wave N frags
  constexpr int NBUF = SUMA ? 1 : 3;
  constexpr int A_ISSUES = BM / (8 * WAVES);
  constexpr int B_ISSUES = BN / (8 * WAVES);
  static_assert(SUMA || (A_ISSUES + B_ISSUES == 6), "vmcnt literal assumes 6 loads/stage");
  __shared__ __bf16 As[NBUF * BM * BK];
  __shared__ __bf16 Bs[NBUF * BN * BK];
  const int tid = threadIdx.x;
  const int wave = tid >> 6, lane = tid & 63;
  const int quad = lane >> 4, l16 = lane & 15;
  const int m0 = blockIdx.x * BM, n0 = blockIdx.y * BN;
  const int ks = K / gridDim.z;
  const int kbeg = blockIdx.z * ks;
  const int wm = (wave & 1) * (BM / 2);
  const int wn = (wave >> 1) * (BN / WAVES_N);
  const int lrow = lane >> 3;
  const int lchunk = lane & 7;
  f32x4 acc[WTM][WTN] = {};

  const __bf16* aSrc[A_ISSUES];
  const __bf16* bSrc[B_ISSUES];
  #pragma unroll
  for (int t = 0; t < A_ISSUES; ++t) {
    int row = (t * WAVES + wave) * 8 + lrow;
    aSrc[t] = A + (size_t)(m0 + row) * K + kbeg + (lchunk ^ (row & 7)) * 8;
  }
  #pragma unroll
  for (int t = 0; t < B_ISSUES; ++t) {
    int row = (t * WAVES + wave) * 8 + lrow;
    bSrc[t] = Bt + (size_t)(n0 + row) * K + kbeg + (lchunk ^ (row & 7)) * 8;
  }
  int aOff[WTM][2], bOff[WTN][2];
  #pragma unroll
  for (int i = 0; i < WTM; ++i) {
    int row = wm + i * 16 + l16;
    #pragma unroll
    for (int kk = 0; kk < 2; ++kk)
      aOff[i][kk] = row * BK + (((kk * 4 + quad) ^ (row & 7)) * 8);
  }
  #pragma unroll
  for (int j = 0; j < WTN; ++j) {
    int row = wn + j * 16 + l16;
    #pragma unroll
    for (int kk = 0; kk < 2; ++kk)
      bOff[j][kk] = row * BK + (((kk * 4 + quad) ^ (row & 7)) * 8);
  }

  // issue next tile's async loads (advances source pointers)
  auto stage = [&](__bf16* Ad, __bf16* Bd) {
    #pragma unroll
    for (int t = 0; t < A_ISSUES; ++t) {
      async16(aSrc[t], Ad + (t * WAVES + wave) * 8 * BK);
      aSrc[t] += BK;
    }
    #pragma unroll
    for (int t = 0; t < B_ISSUES; ++t) {
      async16(bSrc[t], Bd + (t * WAVES + wave) * 8 * BK);
      bSrc[t] += BK;
    }
  };
  // one BK=64 step of MFMAs from LDS tiles
  auto compute = [&](const __bf16* Ab, const __bf16* Bb) {
    #pragma unroll
    for (int kk = 0; kk < 2; ++kk) {
      bf16x8 af[WTM], bfr[WTN];
      #pragma unroll
      for (int i = 0; i < WTM; ++i) af[i] = *(const bf16x8*)(Ab + aOff[i][kk]);
      #pragma unroll
      for (int j = 0; j < WTN; ++j) bfr[j] = *(const bf16x8*)(Bb + bOff[j][kk]);
      #pragma unroll
      for (int i = 0; i < WTM; ++i)
        #pragma unroll
        for (int j = 0; j < WTN; ++j)
          acc[i][j] = __builtin_amdgcn_mfma_f32_16x16x32_bf16(af[i], bfr[j], acc[i][j], 0, 0, 0);
    }
  };

  const int niter = ks / BK;
  if constexpr (SUMA) {
    for (int it = 0; it < niter; ++it) {
      __syncthreads();
      // register-path A staging: bf16(A + A2), swizzled dest (same layout as
      // async path: LDS slot s holds source chunk s^(row&7))
      #pragma unroll
      for (int t = 0; t < A_ISSUES; ++t) {
        int row = (t * WAVES + wave) * 8 + lrow;
        size_t go = (size_t)(m0 + row) * K + kbeg + it * BK + lchunk * 8;
        bf16x8 a0 = *(const bf16x8*)(A + go);
        bf16x8 a1 = *(const bf16x8*)(A2 + go);
        bf16x8 s;
        #pragma unroll
        for (int q = 0; q < 8; ++q) s[q] = (__bf16)((float)a0[q] + (float)a1[q]);
        *(bf16x8*)(As + row * BK + ((lchunk ^ (row & 7)) * 8)) = s;
      }
      #pragma unroll
      for (int t = 0; t < B_ISSUES; ++t) {
        async16(bSrc[t], Bs + (t * WAVES + wave) * 8 * BK);
        bSrc[t] += BK;
      }
      __syncthreads();
      compute(As, Bs);
    }
  } else {
    __bf16* a0 = As;  __bf16* a1 = As + BM * BK;  __bf16* a2 = As + 2 * BM * BK;
    __bf16* b0 = Bs;  __bf16* b1 = Bs + BN * BK;  __bf16* b2 = Bs + 2 * BN * BK;
    stage(a0, b0);
    if (niter > 1) stage(a1, b1);
    for (int it = 0; it < niter; ++it) {
      if (it + 1 < niter) wait_vm6(); else wait_vm0();  // tile it landed (wave-local)
      __builtin_amdgcn_s_barrier();                     // global: landed + old readers done
      if (it + 2 < niter) stage(a2, b2);                // overwrites tile it-1's buffer
      compute(a0, b0);
      __bf16* t;
      t = a0; a0 = a1; a1 = a2; a2 = t;
      t = b0; b0 = b1; b1 = b2; b2 = t;
    }
  }

  char* Cz = (char*)Cout + (size_t)blockIdx.z * M * N * (OUT_BF16 ? 2 : 4);
  #pragma unroll
  for (int i = 0; i < WTM; ++i)
    #pragma unroll
    for (int j = 0; j < WTN; ++j)
      #pragma unroll
      for (int r = 0; r < 4; ++r) {
        int m = m0 + wm + i * 16 + quad * 4 + r;
        int n = n0 + wn + j * 16 + l16;
        float v = acc[i][j][r];
        if (BIAS) v += bias[n];
        if (ACT == 1) v = 1.0f / (1.0f + __expf(-v));
        if (OUT_BF16)
          ((__bf16*)Cz)[(size_t)m * N + n] = (__bf16)v;
        else
          ((float*)Cz)[(size_t)m * N + n] = v;
      }
}

// Router: split-K reduce + 2-layer router + top-2 -> packed e01 + g01.
__global__ __launch_bounds__(256) void router_kernel(
    const float* __restrict__ contP, const float* __restrict__ s2c_b,
    const float* __restrict__ rW1, const float* __restrict__ rb1,
    const float* __restrict__ rW2, const float* __restrict__ rb2,
    __bf16* __restrict__ contB, int* __restrict__ e01,
    float2* __restrict__ g01) {
  const int wave = threadIdx.x >> 6, lane = threadIdx.x & 63;
  const int n = blockIdx.x * 4 + wave;
  const size_t base = (size_t)n * 64 + lane;
  const size_t slab = (size_t)TOK * 64;
  float c = contP[base] + contP[base + slab] + contP[base + 2 * slab] +
            contP[base + 3 * slab] + s2c_b[lane];
  contB[base] = (__bf16)c;
  float acc = rb1[lane];
  #pragma unroll
  for (int i = 0; i < 64; ++i) {
    float ci = __shfl(c, i);
    acc = fmaf(ci, rW1[i * 64 + lane], acc);
  }
  float t = tanhf(acc);
  float logit[8];
  #pragma unroll
  for (int e = 0; e < 8; ++e) {
    float v = t * rW2[lane * 8 + e];
    #pragma unroll
    for (int o = 32; o; o >>= 1) v += __shfl_xor(v, o);
    logit[e] = v + rb2[e];
  }
  float mx = logit[0];
  #pragma unroll
  for (int e = 1; e < 8; ++e) mx = fmaxf(mx, logit[e]);
  float p[8];
  #pragma unroll
  for (int e = 0; e < 8; ++e) p[e] = __expf(logit[e] - mx);
  float v0 = p[0]; int e0 = 0;
  #pragma unroll
  for (int e = 1; e < 8; ++e) if (p[e] > v0) { v0 = p[e]; e0 = e; }
  float v1 = -1.0f; int e1 = 0;
  #pragma unroll
  for (int e = 0; e < 8; ++e) if (e != e0 && p[e] > v1) { v1 = p[e]; e1 = e; }
  float inv = 1.0f / (v0 + v1);
  if (lane == 0) {
    e01[n] = e0 | (e1 << 8);
    g01[n] = make_float2(v0 * inv, v1 * inv);
  }
}

// Dense MoE: block = 128 consecutive tokens x expert e; swizzled LDS tiles.
// Output: plain bf16 stores into rank-slabs (slab0 from each token's top-1
// expert block, slab1 from top-2). Exactly-once per token per slab; no atomics.
__global__ __launch_bounds__(256) void moe_fused_kernel(
    const __bf16* __restrict__ contB, const __bf16* __restrict__ We1T,
    const __bf16* __restrict__ We2T, const float* __restrict__ be1,
    const float* __restrict__ be2, const int* __restrict__ e01,
    const float2* __restrict__ g01, __bf16* __restrict__ slab0,
    __bf16* __restrict__ slab1) {
  constexpr int TT = 128;
  const int e = blockIdx.y;
  const int t0 = blockIdx.x * TT;
  __shared__ __bf16 cont_s[TT * 64];
  __shared__ __bf16 w1_s[64 * 64];
  __shared__ __bf16 w2_s[64 * 64];
  __shared__ __bf16 h_s[TT * 64];
  __shared__ int   e01_s[TT];
  __shared__ float g0_s[TT], g1_s[TT];
  const int tid = threadIdx.x;
  const int wave = tid >> 6, lane = tid & 63;
  const int quad = lane >> 4, l16 = lane & 15;
  if (tid < TT) {
    e01_s[tid] = e01[t0 + tid];
    float2 g = g01[t0 + tid];
    g0_s[tid] = g.x; g1_s[tid] = g.y;
  }
  for (int i = tid; i < TT * 8; i += 256) {
    int r = i >> 3, cc = i & 7;
    *(uint4*)(cont_s + r * 64 + ((cc ^ (r & 7)) * 8)) =
        *(const uint4*)(contB + (size_t)(t0 + r) * 64 + cc * 8);
  }
  const int wtok = wave * 32;
  f32x4 acc2[2][4] = {};
  for (int hc = 0; hc < HHALF; hc += 64) {
    __syncthreads();
    for (int c = tid; c < 512; c += 256) {
      int r = c >> 3, cc = c & 7;
      *(uint4*)(w1_s + r * 64 + ((cc ^ (r & 7)) * 8)) =
          *(const uint4*)(We1T + ((size_t)e * HHALF + hc + r) * 64 + cc * 8);
      *(uint4*)(w2_s + r * 64 + ((cc ^ (r & 7)) * 8)) =
          *(const uint4*)(We2T + ((size_t)e * 64 + r) * HHALF + hc + cc * 8);
    }
    __syncthreads();
    f32x4 acc1[2][4] = {};
    #pragma unroll
    for (int kk = 0; kk < 2; ++kk) {
      bf16x8 af[2], bfr[4];
      #pragma unroll
      for (int i = 0; i < 2; ++i) {
        int row = wtok + i * 16 + l16;
        af[i] = *(const bf16x8*)(cont_s + row * 64 + (((kk * 4 + quad) ^ (row & 7)) * 8));
      }
      #pragma unroll
      for (int j = 0; j < 4; ++j) {
        int row = j * 16 + l16;
        bfr[j] = *(const bf16x8*)(w1_s + row * 64 + (((kk * 4 + quad) ^ (row & 7)) * 8));
      }
      #pragma unroll
      for (int i = 0; i < 2; ++i)
        #pragma unroll
        for (int j = 0; j < 4; ++j)
          acc1[i][j] = __builtin_amdgcn_mfma_f32_16x16x32_bf16(af[i], bfr[j], acc1[i][j], 0, 0, 0);
    }
    #pragma unroll
    for (int i = 0; i < 2; ++i)
      #pragma unroll
      for (int j = 0; j < 4; ++j)
        #pragma unroll
        for (int r = 0; r < 4; ++r) {
          int tr = wtok + i * 16 + quad * 4 + r;
          int hcol = j * 16 + l16;
          float v = acc1[i][j][r] + be1[e * HHALF + hc + hcol];
          h_s[tr * 64 + (((hcol >> 3) ^ (tr & 7)) * 8) + (hcol & 7)] =
              (__bf16)fmaxf(v, 0.0f);
        }
    #pragma unroll
    for (int kk = 0; kk < 2; ++kk) {
      bf16x8 af[2], bfr[4];
      #pragma unroll
      for (int i = 0; i < 2; ++i) {
        int row = wtok + i * 16 + l16;
        af[i] = *(const bf16x8*)(h_s + row * 64 + (((kk * 4 + quad) ^ (row & 7)) * 8));
      }
      #pragma unroll
      for (int j = 0; j < 4; ++j) {
        int row = j * 16 + l16;
        bfr[j] = *(const bf16x8*)(w2_s + row * 64 + (((kk * 4 + quad) ^ (row & 7)) * 8));
      }
      #pragma unroll
      for (int i = 0; i < 2; ++i)
        #pragma unroll
        for (int j = 0; j < 4; ++j)
          acc2[i][j] = __builtin_amdgcn_mfma_f32_16x16x32_bf16(af[i], bfr[j], acc2[i][j], 0, 0, 0);
    }
  }
  #pragma unroll
  for (int i = 0; i < 2; ++i)
    #pragma unroll
    for (int j = 0; j < 4; ++j)
      #pragma unroll
      for (int r = 0; r < 4; ++r) {
        int tr = wtok + i * 16 + quad * 4 + r;
        int m = j * 16 + l16;
        int pe = e01_s[tr];
        size_t o = (size_t)(t0 + tr) * 64 + m;
        if ((pe & 0xff) == e)
          slab0[o] = (__bf16)(g0_s[tr] * (acc2[i][j][r] + be2[e * 64 + m]));
        else if (((pe >> 8) & 0xff) == e)
          slab1[o] = (__bf16)(g1_s[tr] * (acc2[i][j][r] + be2[e * 64 + m]));
      }
}

__global__ __launch_bounds__(256) void ln_kernel(
    const float* __restrict__ x, const float* __restrict__ g,
    const float* __restrict__ b, float* __restrict__ out) {
  const int row = blockIdx.x;
  const float4 v = ((const float4*)(x + (size_t)row * 1024))[threadIdx.x];
  float s1 = v.x + v.y + v.z + v.w;
  float s2 = v.x * v.x + v.y * v.y + v.z * v.z + v.w * v.w;
  #pragma unroll
  for (int o = 32; o; o >>= 1) { s1 += __shfl_xor(s1, o); s2 += __shfl_xor(s2, o); }
  __shared__ float ws1[4], ws2[4];
  const int wave = threadIdx.x >> 6, lane = threadIdx.x & 63;
  if (lane == 0) { ws1[wave] = s1; ws2[wave] = s2; }
  __syncthreads();
  s1 = ws1[0] + ws1[1] + ws1[2] + ws1[3];
  s2 = ws2[0] + ws2[1] + ws2[2] + ws2[3];
  const float mu = s1 * (1.0f / 1024.0f);
  const float var = s2 * (1.0f / 1024.0f) - mu * mu;
  const float inv = rsqrtf(var + 1e-5f);
  const int col = threadIdx.x * 4;
  const float4 gv = *(const float4*)(g + col);
  const float4 bv = *(const float4*)(b + col);
  float4 o;
  o.x = (v.x - mu) * inv * gv.x + bv.x;
  o.y = (v.y - mu) * inv * gv.y + bv.y;
  o.z = (v.z - mu) * inv * gv.z + bv.z;
  o.w = (v.w - mu) * inv * gv.w + bv.w;
  *(float4*)(out + (size_t)row * 1024 + col) = o;
}

extern "C" void kernel_launch(void* const* d_in, const int* in_sizes, int n_in,
                              void* d_out, int out_size, void* d_ws, size_t ws_size,
                              hipStream_t stream) {
  const float* X     = (const float*)d_in[0];
  const float* enc_W = (const float*)d_in[1];
  const float* enc_b = (const float*)d_in[2];
  const float* s2c_W = (const float*)d_in[3];
  const float* s2c_b = (const float*)d_in[4];
  const float* rW1   = (const float*)d_in[5];
  const float* rb1   = (const float*)d_in[6];
  const float* rW2   = (const float*)d_in[7];
  const float* rb2   = (const float*)d_in[8];
  const float* We1   = (const float*)d_in[9];
  const float* be1   = (const float*)d_in[10];
  const float* We2   = (const float*)d_in[11];
  const float* be2   = (const float*)d_in[12];
  const float* c2s_W = (const float*)d_in[13];
  const float* c2s_b = (const float*)d_in[14];
  const float* dec_W = (const float*)d_in[15];
  const float* dec_b = (const float*)d_in[16];
  const float* ln_g  = (const float*)d_in[17];
  const float* ln_b  = (const float*)d_in[18];
  float* out = (float*)d_out;

  // ---- workspace layout with explicit aliasing (~78 MB total) ----
  char* ws = (char*)d_ws;
  size_t off = 0;
  auto take = [&](size_t bytes) -> char* {
    char* p = ws + off;
    off = (off + bytes + 255) & ~(size_t)255;
    return p;
  };
  const size_t SLAB = (size_t)TOK * HDIM * 2;       // 33,554,432
  char*   slabA     = take(SLAB);
  char*   slabB     = take(SLAB);
  __bf16* encWT     = (__bf16*)take((size_t)HDIM * DMODEL * 2);
  __bf16* s2cWT     = (__bf16*)take((size_t)MDIM * HDIM * 2);
  __bf16* c2sWT     = (__bf16*)take((size_t)HDIM * MDIM * 2);
  __bf16* decWT     = (__bf16*)take((size_t)DMODEL * HDIM * 2);
  __bf16* We1T      = (__bf16*)take((size_t)NEXP * HHALF * MDIM * 2);
  __bf16* We2T      = (__bf16*)take((size_t)NEXP * MDIM * HHALF * 2);
  __bf16* contB     = (__bf16*)take((size_t)TOK * MDIM * 2);
  int*    e01       = (int*)take((size_t)TOK * 4);
  float2* g01       = (float2*)take((size_t)TOK * 8);
  __bf16* oslab0    = (__bf16*)take((size_t)TOK * MDIM * 2);
  __bf16* oslab1    = (__bf16*)take((size_t)TOK * MDIM * 2);
  if (off > ws_size) return;  // insufficient workspace -> clean correctness fail

  __bf16* Xb        = (__bf16*)slabA;                       // dead after GEMM1
  float*  contP     = (float*)(slabA + (size_t)TOK * DMODEL * 2);  // dead after router
  __bf16* spikesMoe = (__bf16*)slabA;                       // born at GEMM3
  __bf16* spikesEnc = (__bf16*)slabB;                       // dead after GEMM2
  float*  decoded   = (float*)slabB;                        // born at GEMM4

  // fused preamble: cvt(X) + 6 weight transposes in ONE launch
  preamble_kernel<<<PREAMBLE_BLOCKS, 256, 0, stream>>>(
      X, Xb, enc_W, encWT, s2c_W, s2cWT, c2s_W, c2sWT, dec_W, decWT,
      We1, We1T, We2, We2T);

  // GEMM1: spikesEnc = sigmoid(X @ enc_W + b)   8192x2048, K=1024 (8-wave 128x256)
  gemm_bt<128, 256, 8, 1, 1, 1, 0><<<dim3(TOK / 128, HDIM / 256, 1), 512, 0, stream>>>(
      Xb, encWT, enc_b, spikesEnc, TOK, HDIM, DMODEL, nullptr);
  // GEMM2 (split-K x4): contP[z] = spikesEnc @ s2c_W partials   8192x64, K=2048
  gemm_bt<128, 64, 4, 0, 0, 0, 0><<<dim3(TOK / 128, 1, 4), 256, 0, stream>>>(
      spikesEnc, s2cWT, nullptr, contP, TOK, MDIM, HDIM, nullptr);
  // router: reduce partials + bias, top-2 -> e01/g01 (no atomics)
  router_kernel<<<TOK / 4, 256, 0, stream>>>(contP, s2c_b, rW1, rb1, rW2, rb2,
                                             contB, e01, g01);
  // dense MoE -> rank-slabs (bf16 plain stores; no memset, no atomics)
  moe_fused_kernel<<<dim3(TOK / 128, NEXP), 256, 0, stream>>>(
      contB, We1T, We2T, be1, be2, e01, g01, oslab0, oslab1);
  // GEMM3 (SUMA): spikesMoe = sigmoid((slab0+slab1) @ c2s_W + b)  8192x2048, K=64
  gemm_bt<128, 128, 4, 1, 1, 1, 1><<<dim3(TOK / 128, HDIM / 128, 1), 256, 0, stream>>>(
      oslab0, c2sWT, c2s_b, spikesMoe, TOK, HDIM, MDIM, oslab1);
  // GEMM4: decoded = sigmoid(spikesMoe @ dec_W + b)   8192x1024, K=2048 (8-wave 128x256)
  gemm_bt<128, 256, 8, 0, 1, 1, 0><<<dim3(TOK / 128, DMODEL / 256, 1), 512, 0, stream>>>(
      spikesMoe, decWT, dec_b, decoded, TOK, DMODEL, HDIM, nullptr);
  ln_kernel<<<TOK, 256, 0, stream>>>(decoded, ln_g, ln_b, out);
}

// Round 3
// 320.349 us; speedup vs baseline: 1.0077x; 1.0077x over previous
//
#include <hip/hip_runtime.h>
#include <hip/hip_bf16.h>
#include <cstdint>
#include <cstddef>

#define TOK    8192
#define DMODEL 1024
#define HDIM   2048
#define MDIM   64
#define NEXP   8
#define HHALF  1024

using f32x4  = __attribute__((ext_vector_type(4))) float;
using bf16x8 = __attribute__((ext_vector_type(8))) __bf16;
using bf16x4 = __attribute__((ext_vector_type(4))) __bf16;

// async global->LDS, 16B per lane. LDS dest is wave-uniform base + lane*16.
__device__ __forceinline__ void async16(const void* g, void* l) {
  __builtin_amdgcn_global_load_lds(
      (const __attribute__((address_space(1))) unsigned int*)g,
      (__attribute__((address_space(3))) unsigned int*)l, 16, 0, 0);
}

// One-launch preamble: cvt(X) + transpose-cvt of all 6 weight tensors.
__global__ __launch_bounds__(256) void preamble_kernel(
    const float* __restrict__ X, __bf16* __restrict__ Xb,
    const float* __restrict__ encW, __bf16* __restrict__ encWT,
    const float* __restrict__ s2cW, __bf16* __restrict__ s2cWT,
    const float* __restrict__ c2sW, __bf16* __restrict__ c2sWT,
    const float* __restrict__ decW, __bf16* __restrict__ decWT,
    const float* __restrict__ We1, __bf16* __restrict__ We1T,
    const float* __restrict__ We2, __bf16* __restrict__ We2T) {
  __shared__ float ts[32][33];
  const int tid = threadIdx.x;
  int b = blockIdx.x;
  if (b < 8192) {  // X: 8192x1024 fp32 -> bf16 (float4 per thread)
    int i = b * 256 + tid;
    float4 v = ((const float4*)X)[i];
    bf16x4 o = { (__bf16)v.x, (__bf16)v.y, (__bf16)v.z, (__bf16)v.w };
    ((bf16x4*)Xb)[i] = o;
    return;
  }
  b -= 8192;
  const float* in; __bf16* outp; int R, C, tx, ty;
  if (b < 2048)              { in = encW; outp = encWT; R = 1024; C = 2048; tx = b % 64; ty = b / 64; }
  else if ((b -= 2048) < 128){ in = s2cW; outp = s2cWT; R = 2048; C = 64;   tx = b % 2;  ty = b / 2;  }
  else if ((b -= 128) < 128) { in = c2sW; outp = c2sWT; R = 64;   C = 2048; tx = b % 64; ty = b / 64; }
  else if ((b -= 128) < 2048){ in = decW; outp = decWT; R = 2048; C = 1024; tx = b % 32; ty = b / 32; }
  else if ((b -= 2048) < 512){ int s = b / 64, t = b % 64;
                               in = We1 + (size_t)s * 65536; outp = We1T + (size_t)s * 65536;
                               R = 64; C = 1024; tx = t % 32; ty = t / 32; }
  else                       { b -= 512; int s = b / 64, t = b % 64;
                               in = We2 + (size_t)s * 65536; outp = We2T + (size_t)s * 65536;
                               R = 1024; C = 64; tx = t % 2; ty = t / 2; }
  const int c0 = tx * 32, r0 = ty * 32;
  const int x = tid & 31, y = tid >> 5;
  #pragma unroll
  for (int i = y; i < 32; i += 8) ts[i][x] = in[(size_t)(r0 + i) * C + c0 + x];
  __syncthreads();
  #pragma unroll
  for (int i = y; i < 32; i += 8)
    outp[(size_t)(c0 + i) * R + r0 + x] = (__bf16)ts[x][i];
}
#define PREAMBLE_BLOCKS (8192 + 2048 + 128 + 128 + 2048 + 512 + 512)

// ============================================================================
// gemm_mt: 256-row mega-tile, per-wave 128x64 output (acc[8][4]), BK=64.
// ds_read ratio 0.375 KB/MFMA (24 reads : 64 MFMA per wave per K-tile) vs 0.5
// in the old template. 4-phase interleave, one-phase register read-ahead,
// setprio(1) around each 16-MFMA cluster, raw per-phase barriers.
// Counted vmcnt: NBUF=2 (vm8, 1-tile flight) or NBUF=3 (vm24/12, 2-tile).
// Safety: the buffer staged at tile-t entry was last READ in tile t-1; every
// ds_read's MFMA consumer precedes t-1's P3 barrier, so the buffer is sealed
// before the stage issues. Entry vmcnt+barrier publishes tile t.
// ============================================================================
template <int BN, int WAVES, int NBUF, int OUT_BF16, int ACT, int BIAS>
__global__ __launch_bounds__(WAVES * 64, WAVES == 8 ? 2 : 1) void gemm_mt(
    const __bf16* __restrict__ A, const __bf16* __restrict__ Bt,
    const float* __restrict__ bias, void* __restrict__ Cout,
    int M, int N, int K) {
  constexpr int BM = 256, BK = 64;
  constexpr int A_ISSUES = BM / (8 * WAVES);
  constexpr int B_ISSUES = BN / (8 * WAVES);
  constexpr int LOADS = A_ISSUES + B_ISSUES;
  static_assert((NBUF == 2 && LOADS == 8) || (NBUF == 3 && LOADS == 12),
                "vmcnt literals assume LOADS=8 (NBUF2) or 12 (NBUF3)");
  __shared__ __bf16 As[NBUF * BM * BK];
  __shared__ __bf16 Bs[NBUF * BN * BK];
  const int tid = threadIdx.x;
  const int wave = tid >> 6, lane = tid & 63;
  const int quad = lane >> 4, l16 = lane & 15;
  const int m0 = blockIdx.x * BM, n0 = blockIdx.y * BN;
  const int wm = (wave & 1) * 128;        // 2 waves in M
  const int wn = (wave >> 1) * 64;        // WAVES/2 waves in N
  const int lrow = lane >> 3, lchunk = lane & 7;
  f32x4 acc[8][4] = {};

  const __bf16* aSrc[A_ISSUES];
  const __bf16* bSrc[B_ISSUES];
  #pragma unroll
  for (int t = 0; t < A_ISSUES; ++t) {
    int row = (t * WAVES + wave) * 8 + lrow;
    aSrc[t] = A + (size_t)(m0 + row) * K + (lchunk ^ (row & 7)) * 8;
  }
  #pragma unroll
  for (int t = 0; t < B_ISSUES; ++t) {
    int row = (t * WAVES + wave) * 8 + lrow;
    bSrc[t] = Bt + (size_t)(n0 + row) * K + (lchunk ^ (row & 7)) * 8;
  }
  // element offsets for kk=0 fragments; kk=1 is ^32 (chunk XOR 4, *8 elems)
  int aOff[8], bOff[4];
  #pragma unroll
  for (int rf = 0; rf < 8; ++rf) {
    int row = wm + rf * 16 + l16;
    aOff[rf] = row * BK + ((quad ^ (row & 7)) * 8);
  }
  #pragma unroll
  for (int cf = 0; cf < 4; ++cf) {
    int row = wn + cf * 16 + l16;
    bOff[cf] = row * BK + ((quad ^ (row & 7)) * 8);
  }

  auto stage = [&](__bf16* Ad, __bf16* Bd) {
    #pragma unroll
    for (int t = 0; t < A_ISSUES; ++t) {
      async16(aSrc[t], Ad + (t * WAVES + wave) * 8 * BK);
      aSrc[t] += BK;
    }
    #pragma unroll
    for (int t = 0; t < B_ISSUES; ++t) {
      async16(bSrc[t], Bd + (t * WAVES + wave) * 8 * BK);
      bSrc[t] += BK;
    }
  };

  __bf16 *cA0 = As, *cA1 = As + BM * BK, *cA2 = As + 2 * BM * BK;
  __bf16 *cB0 = Bs, *cB1 = Bs + BN * BK, *cB2 = Bs + 2 * BN * BK;
  const int nt = K / BK;
  // prologue
  stage(cA0, cB0);
  if constexpr (NBUF == 3) stage(cA1, cB1);

  for (int t = 0; t < nt; ++t) {
    if constexpr (NBUF == 2) {
      if (t + 1 < nt) stage(cA1, cB1);
    } else {
      if (t + 2 < nt) stage(cA2, cB2);
    }
    const int ahead = nt - 1 - t;
    if constexpr (NBUF == 2) {
      if (ahead >= 1) asm volatile("s_waitcnt vmcnt(8)" ::: "memory");
      else            asm volatile("s_waitcnt vmcnt(0)" ::: "memory");
    } else {
      if (ahead >= 2)      asm volatile("s_waitcnt vmcnt(24)" ::: "memory");
      else if (ahead == 1) asm volatile("s_waitcnt vmcnt(12)" ::: "memory");
      else                 asm volatile("s_waitcnt vmcnt(0)" ::: "memory");
    }
    asm volatile("s_barrier" ::: "memory");  // tile t published; prev buffers sealed

    bf16x8 af[4], ag[4], bv[4], bw[4];
    // entry reads: A rf0-3 k0, B k0
    #pragma unroll
    for (int r = 0; r < 4; ++r) af[r] = *(const bf16x8*)(cA0 + aOff[r]);
    #pragma unroll
    for (int c = 0; c < 4; ++c) bv[c] = *(const bf16x8*)(cB0 + bOff[c]);
    // P0: prefetch A rf4-7 k0; MFMA rf0-3 x k0
    #pragma unroll
    for (int r = 0; r < 4; ++r) ag[r] = *(const bf16x8*)(cA0 + aOff[4 + r]);
    __builtin_amdgcn_s_setprio(1);
    #pragma unroll
    for (int c = 0; c < 4; ++c)
      #pragma unroll
      for (int r = 0; r < 4; ++r)
        acc[r][c] = __builtin_amdgcn_mfma_f32_16x16x32_bf16(af[r], bv[c], acc[r][c], 0, 0, 0);
    __builtin_amdgcn_s_setprio(0);
    asm volatile("s_barrier" ::: "memory");
    // P1: prefetch A rf0-3 k1 + B k1; MFMA rf4-7 x k0
    #pragma unroll
    for (int r = 0; r < 4; ++r) af[r] = *(const bf16x8*)(cA0 + (aOff[r] ^ 32));
    #pragma unroll
    for (int c = 0; c < 4; ++c) bw[c] = *(const bf16x8*)(cB0 + (bOff[c] ^ 32));
    __builtin_amdgcn_s_setprio(1);
    #pragma unroll
    for (int c = 0; c < 4; ++c)
      #pragma unroll
      for (int r = 0; r < 4; ++r)
        acc[4 + r][c] = __builtin_amdgcn_mfma_f32_16x16x32_bf16(ag[r], bv[c], acc[4 + r][c], 0, 0, 0);
    __builtin_amdgcn_s_setprio(0);
    asm volatile("s_barrier" ::: "memory");
    // P2: prefetch A rf4-7 k1; MFMA rf0-3 x k1
    #pragma unroll
    for (int r = 0; r < 4; ++r) ag[r] = *(const bf16x8*)(cA0 + (aOff[4 + r] ^ 32));
    __builtin_amdgcn_s_setprio(1);
    #pragma unroll
    for (int c = 0; c < 4; ++c)
      #pragma unroll
      for (int r = 0; r < 4; ++r)
        acc[r][c] = __builtin_amdgcn_mfma_f32_16x16x32_bf16(af[r], bw[c], acc[r][c], 0, 0, 0);
    __builtin_amdgcn_s_setprio(0);
    asm volatile("s_barrier" ::: "memory");
    // P3: MFMA rf4-7 x k1
    __builtin_amdgcn_s_setprio(1);
    #pragma unroll
    for (int c = 0; c < 4; ++c)
      #pragma unroll
      for (int r = 0; r < 4; ++r)
        acc[4 + r][c] = __builtin_amdgcn_mfma_f32_16x16x32_bf16(ag[r], bw[c], acc[4 + r][c], 0, 0, 0);
    __builtin_amdgcn_s_setprio(0);
    asm volatile("s_barrier" ::: "memory");  // tile seal (frees cA0/cB0 for staging)

    // rotate buffers
    if constexpr (NBUF == 2) {
      __bf16* x;
      x = cA0; cA0 = cA1; cA1 = x;
      x = cB0; cB0 = cB1; cB1 = x;
    } else {
      __bf16* x;
      x = cA0; cA0 = cA1; cA1 = cA2; cA2 = x;
      x = cB0; cB0 = cB1; cB1 = cB2; cB2 = x;
    }
  }

  #pragma unroll
  for (int rf = 0; rf < 8; ++rf)
    #pragma unroll
    for (int cf = 0; cf < 4; ++cf)
      #pragma unroll
      for (int r = 0; r < 4; ++r) {
        int m = m0 + wm + rf * 16 + quad * 4 + r;
        int n = n0 + wn + cf * 16 + l16;
        float v = acc[rf][cf][r];
        if (BIAS) v += bias[n];
        if (ACT == 1) v = 1.0f / (1.0f + __expf(-v));
        if (OUT_BF16)
          ((__bf16*)Cout)[(size_t)m * N + n] = (__bf16)v;
        else
          ((float*)Cout)[(size_t)m * N + n] = v;
      }
}

// ============================================================================
// Old template, kept for GEMM2 (N=64) and GEMM3 (SUMA, K=64 one-shot).
// ============================================================================
template <int BM, int BN, int WAVES, int OUT_BF16, int ACT, int BIAS, int SUMA>
__global__ __launch_bounds__(WAVES * 64) void gemm_bt(
    const __bf16* __restrict__ A, const __bf16* __restrict__ Bt,
    const float* __restrict__ bias, void* __restrict__ Cout,
    int M, int N, int K, const __bf16* __restrict__ A2) {
  constexpr int BK = 64;               // 8 chunks of 16B per row
  constexpr int WAVES_N = WAVES / 2;
  constexpr int WTM = BM / 32;
  constexpr int WTN = BN / (WAVES_N * 16);
  constexpr int NBUF = SUMA ? 1 : 3;
  constexpr int A_ISSUES = BM / (8 * WAVES);
  constexpr int B_ISSUES = BN / (8 * WAVES);
  static_assert(SUMA || (A_ISSUES + B_ISSUES == 6), "vmcnt literal assumes 6 loads/stage");
  __shared__ __bf16 As[NBUF * BM * BK];
  __shared__ __bf16 Bs[NBUF * BN * BK];
  const int tid = threadIdx.x;
  const int wave = tid >> 6, lane = tid & 63;
  const int quad = lane >> 4, l16 = lane & 15;
  const int m0 = blockIdx.x * BM, n0 = blockIdx.y * BN;
  const int ks = K / gridDim.z;
  const int kbeg = blockIdx.z * ks;
  const int wm = (wave & 1) * (BM / 2);
  const int wn = (wave >> 1) * (BN / WAVES_N);
  const int lrow = lane >> 3;
  const int lchunk = lane & 7;
  f32x4 acc[WTM][WTN] = {};

  const __bf16* aSrc[A_ISSUES];
  const __bf16* bSrc[B_ISSUES];
  #pragma unroll
  for (int t = 0; t < A_ISSUES; ++t) {
    int row = (t * WAVES + wave) * 8 + lrow;
    aSrc[t] = A + (size_t)(m0 + row) * K + kbeg + (lchunk ^ (row & 7)) * 8;
  }
  #pragma unroll
  for (int t = 0; t < B_ISSUES; ++t) {
    int row = (t * WAVES + wave) * 8 + lrow;
    bSrc[t] = Bt + (size_t)(n0 + row) * K + kbeg + (lchunk ^ (row & 7)) * 8;
  }
  int aOff[WTM][2], bOff[WTN][2];
  #pragma unroll
  for (int i = 0; i < WTM; ++i) {
    int row = wm + i * 16 + l16;
    #pragma unroll
    for (int kk = 0; kk < 2; ++kk)
      aOff[i][kk] = row * BK + (((kk * 4 + quad) ^ (row & 7)) * 8);
  }
  #pragma unroll
  for (int j = 0; j < WTN; ++j) {
    int row = wn + j * 16 + l16;
    #pragma unroll
    for (int kk = 0; kk < 2; ++kk)
      bOff[j][kk] = row * BK + (((kk * 4 + quad) ^ (row & 7)) * 8);
  }

  auto stage = [&](__bf16* Ad, __bf16* Bd) {
    #pragma unroll
    for (int t = 0; t < A_ISSUES; ++t) {
      async16(aSrc[t], Ad + (t * WAVES + wave) * 8 * BK);
      aSrc[t] += BK;
    }
    #pragma unroll
    for (int t = 0; t < B_ISSUES; ++t) {
      async16(bSrc[t], Bd + (t * WAVES + wave) * 8 * BK);
      bSrc[t] += BK;
    }
  };
  auto compute = [&](const __bf16* Ab, const __bf16* Bb) {
    #pragma unroll
    for (int kk = 0; kk < 2; ++kk) {
      bf16x8 af[WTM], bfr[WTN];
      #pragma unroll
      for (int i = 0; i < WTM; ++i) af[i] = *(const bf16x8*)(Ab + aOff[i][kk]);
      #pragma unroll
      for (int j = 0; j < WTN; ++j) bfr[j] = *(const bf16x8*)(Bb + bOff[j][kk]);
      #pragma unroll
      for (int i = 0; i < WTM; ++i)
        #pragma unroll
        for (int j = 0; j < WTN; ++j)
          acc[i][j] = __builtin_amdgcn_mfma_f32_16x16x32_bf16(af[i], bfr[j], acc[i][j], 0, 0, 0);
    }
  };

  const int niter = ks / BK;
  if constexpr (SUMA) {
    for (int it = 0; it < niter; ++it) {
      __syncthreads();
      #pragma unroll
      for (int t = 0; t < A_ISSUES; ++t) {
        int row = (t * WAVES + wave) * 8 + lrow;
        size_t go = (size_t)(m0 + row) * K + kbeg + it * BK + lchunk * 8;
        bf16x8 a0 = *(const bf16x8*)(A + go);
        bf16x8 a1 = *(const bf16x8*)(A2 + go);
        bf16x8 s;
        #pragma unroll
        for (int q = 0; q < 8; ++q) s[q] = (__bf16)((float)a0[q] + (float)a1[q]);
        *(bf16x8*)(As + row * BK + ((lchunk ^ (row & 7)) * 8)) = s;
      }
      #pragma unroll
      for (int t = 0; t < B_ISSUES; ++t) {
        async16(bSrc[t], Bs + (t * WAVES + wave) * 8 * BK);
        bSrc[t] += BK;
      }
      __syncthreads();
      compute(As, Bs);
    }
  } else {
    __bf16* a0 = As;  __bf16* a1 = As + BM * BK;  __bf16* a2 = As + 2 * BM * BK;
    __bf16* b0 = Bs;  __bf16* b1 = Bs + BN * BK;  __bf16* b2 = Bs + 2 * BN * BK;
    stage(a0, b0);
    if (niter > 1) stage(a1, b1);
    for (int it = 0; it < niter; ++it) {
      if (it + 1 < niter) asm volatile("s_waitcnt vmcnt(6)" ::: "memory");
      else                asm volatile("s_waitcnt vmcnt(0)" ::: "memory");
      __builtin_amdgcn_s_barrier();
      if (it + 2 < niter) stage(a2, b2);
      compute(a0, b0);
      __bf16* t;
      t = a0; a0 = a1; a1 = a2; a2 = t;
      t = b0; b0 = b1; b1 = b2; b2 = t;
    }
  }

  char* Cz = (char*)Cout + (size_t)blockIdx.z * M * N * (OUT_BF16 ? 2 : 4);
  #pragma unroll
  for (int i = 0; i < WTM; ++i)
    #pragma unroll
    for (int j = 0; j < WTN; ++j)
      #pragma unroll
      for (int r = 0; r < 4; ++r) {
        int m = m0 + wm + i * 16 + quad * 4 + r;
        int n = n0 + wn + j * 16 + l16;
        float v = acc[i][j][r];
        if (BIAS) v += bias[n];
        if (ACT == 1) v = 1.0f / (1.0f + __expf(-v));
        if (OUT_BF16)
          ((__bf16*)Cz)[(size_t)m * N + n] = (__bf16)v;
        else
          ((float*)Cz)[(size_t)m * N + n] = v;
      }
}

// Router: split-K reduce + 2-layer router + top-2 -> packed e01 + g01.
__global__ __launch_bounds__(256) void router_kernel(
    const float* __restrict__ contP, const float* __restrict__ s2c_b,
    const float* __restrict__ rW1, const float* __restrict__ rb1,
    const float* __restrict__ rW2, const float* __restrict__ rb2,
    __bf16* __restrict__ contB, int* __restrict__ e01,
    float2* __restrict__ g01) {
  const int wave = threadIdx.x >> 6, lane = threadIdx.x & 63;
  const int n = blockIdx.x * 4 + wave;
  const size_t base = (size_t)n * 64 + lane;
  const size_t slab = (size_t)TOK * 64;
  float c = contP[base] + contP[base + slab] + contP[base + 2 * slab] +
            contP[base + 3 * slab] + s2c_b[lane];
  contB[base] = (__bf16)c;
  float acc = rb1[lane];
  #pragma unroll
  for (int i = 0; i < 64; ++i) {
    float ci = __shfl(c, i);
    acc = fmaf(ci, rW1[i * 64 + lane], acc);
  }
  float t = tanhf(acc);
  float logit[8];
  #pragma unroll
  for (int e = 0; e < 8; ++e) {
    float v = t * rW2[lane * 8 + e];
    #pragma unroll
    for (int o = 32; o; o >>= 1) v += __shfl_xor(v, o);
    logit[e] = v + rb2[e];
  }
  float mx = logit[0];
  #pragma unroll
  for (int e = 1; e < 8; ++e) mx = fmaxf(mx, logit[e]);
  float p[8];
  #pragma unroll
  for (int e = 0; e < 8; ++e) p[e] = __expf(logit[e] - mx);
  float v0 = p[0]; int e0 = 0;
  #pragma unroll
  for (int e = 1; e < 8; ++e) if (p[e] > v0) { v0 = p[e]; e0 = e; }
  float v1 = -1.0f; int e1 = 0;
  #pragma unroll
  for (int e = 0; e < 8; ++e) if (e != e0 && p[e] > v1) { v1 = p[e]; e1 = e; }
  float inv = 1.0f / (v0 + v1);
  if (lane == 0) {
    e01[n] = e0 | (e1 << 8);
    g01[n] = make_float2(v0 * inv, v1 * inv);
  }
}

// Dense MoE: block = 128 consecutive tokens x expert e; swizzled LDS tiles.
__global__ __launch_bounds__(256) void moe_fused_kernel(
    const __bf16* __restrict__ contB, const __bf16* __restrict__ We1T,
    const __bf16* __restrict__ We2T, const float* __restrict__ be1,
    const float* __restrict__ be2, const int* __restrict__ e01,
    const float2* __restrict__ g01, __bf16* __restrict__ slab0,
    __bf16* __restrict__ slab1) {
  constexpr int TT = 128;
  const int e = blockIdx.y;
  const int t0 = blockIdx.x * TT;
  __shared__ __bf16 cont_s[TT * 64];
  __shared__ __bf16 w1_s[64 * 64];
  __shared__ __bf16 w2_s[64 * 64];
  __shared__ __bf16 h_s[TT * 64];
  __shared__ int   e01_s[TT];
  __shared__ float g0_s[TT], g1_s[TT];
  const int tid = threadIdx.x;
  const int wave = tid >> 6, lane = tid & 63;
  const int quad = lane >> 4, l16 = lane & 15;
  if (tid < TT) {
    e01_s[tid] = e01[t0 + tid];
    float2 g = g01[t0 + tid];
    g0_s[tid] = g.x; g1_s[tid] = g.y;
  }
  for (int i = tid; i < TT * 8; i += 256) {
    int r = i >> 3, cc = i & 7;
    *(uint4*)(cont_s + r * 64 + ((cc ^ (r & 7)) * 8)) =
        *(const uint4*)(contB + (size_t)(t0 + r) * 64 + cc * 8);
  }
  const int wtok = wave * 32;
  f32x4 acc2[2][4] = {};
  for (int hc = 0; hc < HHALF; hc += 64) {
    __syncthreads();
    for (int c = tid; c < 512; c += 256) {
      int r = c >> 3, cc = c & 7;
      *(uint4*)(w1_s + r * 64 + ((cc ^ (r & 7)) * 8)) =
          *(const uint4*)(We1T + ((size_t)e * HHALF + hc + r) * 64 + cc * 8);
      *(uint4*)(w2_s + r * 64 + ((cc ^ (r & 7)) * 8)) =
          *(const uint4*)(We2T + ((size_t)e * 64 + r) * HHALF + hc + cc * 8);
    }
    __syncthreads();
    f32x4 acc1[2][4] = {};
    #pragma unroll
    for (int kk = 0; kk < 2; ++kk) {
      bf16x8 af[2], bfr[4];
      #pragma unroll
      for (int i = 0; i < 2; ++i) {
        int row = wtok + i * 16 + l16;
        af[i] = *(const bf16x8*)(cont_s + row * 64 + (((kk * 4 + quad) ^ (row & 7)) * 8));
      }
      #pragma unroll
      for (int j = 0; j < 4; ++j) {
        int row = j * 16 + l16;
        bfr[j] = *(const bf16x8*)(w1_s + row * 64 + (((kk * 4 + quad) ^ (row & 7)) * 8));
      }
      #pragma unroll
      for (int i = 0; i < 2; ++i)
        #pragma unroll
        for (int j = 0; j < 4; ++j)
          acc1[i][j] = __builtin_amdgcn_mfma_f32_16x16x32_bf16(af[i], bfr[j], acc1[i][j], 0, 0, 0);
    }
    #pragma unroll
    for (int i = 0; i < 2; ++i)
      #pragma unroll
      for (int j = 0; j < 4; ++j)
        #pragma unroll
        for (int r = 0; r < 4; ++r) {
          int tr = wtok + i * 16 + quad * 4 + r;
          int hcol = j * 16 + l16;
          float v = acc1[i][j][r] + be1[e * HHALF + hc + hcol];
          h_s[tr * 64 + (((hcol >> 3) ^ (tr & 7)) * 8) + (hcol & 7)] =
              (__bf16)fmaxf(v, 0.0f);
        }
    #pragma unroll
    for (int kk = 0; kk < 2; ++kk) {
      bf16x8 af[2], bfr[4];
      #pragma unroll
      for (int i = 0; i < 2; ++i) {
        int row = wtok + i * 16 + l16;
        af[i] = *(const bf16x8*)(h_s + row * 64 + (((kk * 4 + quad) ^ (row & 7)) * 8));
      }
      #pragma unroll
      for (int j = 0; j < 4; ++j) {
        int row = j * 16 + l16;
        bfr[j] = *(const bf16x8*)(w2_s + row * 64 + (((kk * 4 + quad) ^ (row & 7)) * 8));
      }
      #pragma unroll
      for (int i = 0; i < 2; ++i)
        #pragma unroll
        for (int j = 0; j < 4; ++j)
          acc2[i][j] = __builtin_amdgcn_mfma_f32_16x16x32_bf16(af[i], bfr[j], acc2[i][j], 0, 0, 0);
    }
  }
  #pragma unroll
  for (int i = 0; i < 2; ++i)
    #pragma unroll
    for (int j = 0; j < 4; ++j)
      #pragma unroll
      for (int r = 0; r < 4; ++r) {
        int tr = wtok + i * 16 + quad * 4 + r;
        int m = j * 16 + l16;
        int pe = e01_s[tr];
        size_t o = (size_t)(t0 + tr) * 64 + m;
        if ((pe & 0xff) == e)
          slab0[o] = (__bf16)(g0_s[tr] * (acc2[i][j][r] + be2[e * 64 + m]));
        else if (((pe >> 8) & 0xff) == e)
          slab1[o] = (__bf16)(g1_s[tr] * (acc2[i][j][r] + be2[e * 64 + m]));
      }
}

__global__ __launch_bounds__(256) void ln_kernel(
    const float* __restrict__ x, const float* __restrict__ g,
    const float* __restrict__ b, float* __restrict__ out) {
  const int row = blockIdx.x;
  const float4 v = ((const float4*)(x + (size_t)row * 1024))[threadIdx.x];
  float s1 = v.x + v.y + v.z + v.w;
  float s2 = v.x * v.x + v.y * v.y + v.z * v.z + v.w * v.w;
  #pragma unroll
  for (int o = 32; o; o >>= 1) { s1 += __shfl_xor(s1, o); s2 += __shfl_xor(s2, o); }
  __shared__ float ws1[4], ws2[4];
  const int wave = threadIdx.x >> 6, lane = threadIdx.x & 63;
  if (lane == 0) { ws1[wave] = s1; ws2[wave] = s2; }
  __syncthreads();
  s1 = ws1[0] + ws1[1] + ws1[2] + ws1[3];
  s2 = ws2[0] + ws2[1] + ws2[2] + ws2[3];
  const float mu = s1 * (1.0f / 1024.0f);
  const float var = s2 * (1.0f / 1024.0f) - mu * mu;
  const float inv = rsqrtf(var + 1e-5f);
  const int col = threadIdx.x * 4;
  const float4 gv = *(const float4*)(g + col);
  const float4 bv = *(const float4*)(b + col);
  float4 o;
  o.x = (v.x - mu) * inv * gv.x + bv.x;
  o.y = (v.y - mu) * inv * gv.y + bv.y;
  o.z = (v.z - mu) * inv * gv.z + bv.z;
  o.w = (v.w - mu) * inv * gv.w + bv.w;
  *(float4*)(out + (size_t)row * 1024 + col) = o;
}

extern "C" void kernel_launch(void* const* d_in, const int* in_sizes, int n_in,
                              void* d_out, int out_size, void* d_ws, size_t ws_size,
                              hipStream_t stream) {
  const float* X     = (const float*)d_in[0];
  const float* enc_W = (const float*)d_in[1];
  const float* enc_b = (const float*)d_in[2];
  const float* s2c_W = (const float*)d_in[3];
  const float* s2c_b = (const float*)d_in[4];
  const float* rW1   = (const float*)d_in[5];
  const float* rb1   = (const float*)d_in[6];
  const float* rW2   = (const float*)d_in[7];
  const float* rb2   = (const float*)d_in[8];
  const float* We1   = (const float*)d_in[9];
  const float* be1   = (const float*)d_in[10];
  const float* We2   = (const float*)d_in[11];
  const float* be2   = (const float*)d_in[12];
  const float* c2s_W = (const float*)d_in[13];
  const float* c2s_b = (const float*)d_in[14];
  const float* dec_W = (const float*)d_in[15];
  const float* dec_b = (const float*)d_in[16];
  const float* ln_g  = (const float*)d_in[17];
  const float* ln_b  = (const float*)d_in[18];
  float* out = (float*)d_out;

  // ---- workspace layout with explicit aliasing (~78 MB total) ----
  char* ws = (char*)d_ws;
  size_t off = 0;
  auto take = [&](size_t bytes) -> char* {
    char* p = ws + off;
    off = (off + bytes + 255) & ~(size_t)255;
    return p;
  };
  const size_t SLAB = (size_t)TOK * HDIM * 2;       // 33,554,432
  char*   slabA     = take(SLAB);
  char*   slabB     = take(SLAB);
  __bf16* encWT     = (__bf16*)take((size_t)HDIM * DMODEL * 2);
  __bf16* s2cWT     = (__bf16*)take((size_t)MDIM * HDIM * 2);
  __bf16* c2sWT     = (__bf16*)take((size_t)HDIM * MDIM * 2);
  __bf16* decWT     = (__bf16*)take((size_t)DMODEL * HDIM * 2);
  __bf16* We1T      = (__bf16*)take((size_t)NEXP * HHALF * MDIM * 2);
  __bf16* We2T      = (__bf16*)take((size_t)NEXP * MDIM * HHALF * 2);
  __bf16* contB     = (__bf16*)take((size_t)TOK * MDIM * 2);
  int*    e01       = (int*)take((size_t)TOK * 4);
  float2* g01       = (float2*)take((size_t)TOK * 8);
  __bf16* oslab0    = (__bf16*)take((size_t)TOK * MDIM * 2);
  __bf16* oslab1    = (__bf16*)take((size_t)TOK * MDIM * 2);
  if (off > ws_size) return;  // insufficient workspace -> clean correctness fail

  __bf16* Xb        = (__bf16*)slabA;                       // dead after GEMM1
  float*  contP     = (float*)(slabA + (size_t)TOK * DMODEL * 2);  // dead after router
  __bf16* spikesMoe = (__bf16*)slabA;                       // born at GEMM3
  __bf16* spikesEnc = (__bf16*)slabB;                       // dead after GEMM2
  float*  decoded   = (float*)slabB;                        // born at GEMM4

  // fused preamble: cvt(X) + 6 weight transposes in ONE launch
  preamble_kernel<<<PREAMBLE_BLOCKS, 256, 0, stream>>>(
      X, Xb, enc_W, encWT, s2c_W, s2cWT, c2s_W, c2sWT, dec_W, decWT,
      We1, We1T, We2, We2T);

  // GEMM1: spikesEnc = sigmoid(X @ enc_W + b)  8192x2048, K=1024
  // mega-tile 256x256, 8 waves, NBUF=2 -> grid 32x8 = 256 blocks (1/CU)
  gemm_mt<256, 8, 2, 1, 1, 1><<<dim3(TOK / 256, HDIM / 256), 512, 0, stream>>>(
      Xb, encWT, enc_b, spikesEnc, TOK, HDIM, DMODEL);
  // GEMM2 (split-K x4): contP[z] = spikesEnc @ s2c_W partials   8192x64, K=2048
  gemm_bt<128, 64, 4, 0, 0, 0, 0><<<dim3(TOK / 128, 1, 4), 256, 0, stream>>>(
      spikesEnc, s2cWT, nullptr, contP, TOK, MDIM, HDIM, nullptr);
  // router: reduce partials + bias, top-2 -> e01/g01 (no atomics)
  router_kernel<<<TOK / 4, 256, 0, stream>>>(contP, s2c_b, rW1, rb1, rW2, rb2,
                                             contB, e01, g01);
  // dense MoE -> rank-slabs (bf16 plain stores; no memset, no atomics)
  moe_fused_kernel<<<dim3(TOK / 128, NEXP), 256, 0, stream>>>(
      contB, We1T, We2T, be1, be2, e01, g01, oslab0, oslab1);
  // GEMM3 (SUMA): spikesMoe = sigmoid((slab0+slab1) @ c2s_W + b)  8192x2048, K=64
  gemm_bt<128, 128, 4, 1, 1, 1, 1><<<dim3(TOK / 128, HDIM / 128, 1), 256, 0, stream>>>(
      oslab0, c2sWT, c2s_b, spikesMoe, TOK, HDIM, MDIM, oslab1);
  // GEMM4: decoded = sigmoid(spikesMoe @ dec_W + b)  8192x1024, K=2048
  // mega-tile 256x128, 4 waves, NBUF=3 -> grid 32x8 = 256 blocks (1/CU)
  gemm_mt<128, 4, 3, 0, 1, 1><<<dim3(TOK / 256, DMODEL / 128), 256, 0, stream>>>(
      spikesMoe, decWT, dec_b, decoded, TOK, DMODEL, HDIM);
  ln_kernel<<<TOK, 256, 0, stream>>>(decoded, ln_g, ln_b, out);
}

// Round 4
// 311.725 us; speedup vs baseline: 1.0356x; 1.0277x over previous
//
#include <hip/hip_runtime.h>
#include <hip/hip_bf16.h>
#include <cstdint>
#include <cstddef>

#define TOK    8192
#define DMODEL 1024
#define HDIM   2048
#define MDIM   64
#define NEXP   8
#define HHALF  1024

using f32x4  = __attribute__((ext_vector_type(4))) float;
using bf16x8 = __attribute__((ext_vector_type(8))) __bf16;
using bf16x4 = __attribute__((ext_vector_type(4))) __bf16;

// async global->LDS, 16B per lane. LDS dest is wave-uniform base + lane*16.
__device__ __forceinline__ void async16(const void* g, void* l) {
  __builtin_amdgcn_global_load_lds(
      (const __attribute__((address_space(1))) unsigned int*)g,
      (__attribute__((address_space(3))) unsigned int*)l, 16, 0, 0);
}

// One-launch preamble: cvt(X) + transpose-cvt of all 6 weight tensors.
__global__ __launch_bounds__(256) void preamble_kernel(
    const float* __restrict__ X, __bf16* __restrict__ Xb,
    const float* __restrict__ encW, __bf16* __restrict__ encWT,
    const float* __restrict__ s2cW, __bf16* __restrict__ s2cWT,
    const float* __restrict__ c2sW, __bf16* __restrict__ c2sWT,
    const float* __restrict__ decW, __bf16* __restrict__ decWT,
    const float* __restrict__ We1, __bf16* __restrict__ We1T,
    const float* __restrict__ We2, __bf16* __restrict__ We2T) {
  __shared__ float ts[32][33];
  const int tid = threadIdx.x;
  int b = blockIdx.x;
  if (b < 8192) {  // X: 8192x1024 fp32 -> bf16 (float4 per thread)
    int i = b * 256 + tid;
    float4 v = ((const float4*)X)[i];
    bf16x4 o = { (__bf16)v.x, (__bf16)v.y, (__bf16)v.z, (__bf16)v.w };
    ((bf16x4*)Xb)[i] = o;
    return;
  }
  b -= 8192;
  const float* in; __bf16* outp; int R, C, tx, ty;
  if (b < 2048)              { in = encW; outp = encWT; R = 1024; C = 2048; tx = b % 64; ty = b / 64; }
  else if ((b -= 2048) < 128){ in = s2cW; outp = s2cWT; R = 2048; C = 64;   tx = b % 2;  ty = b / 2;  }
  else if ((b -= 128) < 128) { in = c2sW; outp = c2sWT; R = 64;   C = 2048; tx = b % 64; ty = b / 64; }
  else if ((b -= 128) < 2048){ in = decW; outp = decWT; R = 2048; C = 1024; tx = b % 32; ty = b / 32; }
  else if ((b -= 2048) < 512){ int s = b / 64, t = b % 64;
                               in = We1 + (size_t)s * 65536; outp = We1T + (size_t)s * 65536;
                               R = 64; C = 1024; tx = t % 32; ty = t / 32; }
  else                       { b -= 512; int s = b / 64, t = b % 64;
                               in = We2 + (size_t)s * 65536; outp = We2T + (size_t)s * 65536;
                               R = 1024; C = 64; tx = t % 2; ty = t / 2; }
  const int c0 = tx * 32, r0 = ty * 32;
  const int x = tid & 31, y = tid >> 5;
  #pragma unroll
  for (int i = y; i < 32; i += 8) ts[i][x] = in[(size_t)(r0 + i) * C + c0 + x];
  __syncthreads();
  #pragma unroll
  for (int i = y; i < 32; i += 8)
    outp[(size_t)(c0 + i) * R + r0 + x] = (__bf16)ts[x][i];
}
#define PREAMBLE_BLOCKS (8192 + 2048 + 128 + 128 + 2048 + 512 + 512)

// ============================================================================
// gemm_mt: 256x256 mega-tile, 8 waves (2 waves/SIMD -- phase partners exist),
// per-wave 128x64 output (acc[8][4]), BK=64, NBUF=2, counted vmcnt(8),
// 4-phase interleave with setprio around MFMA clusters.  A/B candidate vs
// gemm_bt -- used for GEMM1 only this round.
// ============================================================================
template <int BN, int WAVES, int NBUF, int OUT_BF16, int ACT, int BIAS>
__global__ __launch_bounds__(WAVES * 64, 2) void gemm_mt(
    const __bf16* __restrict__ A, const __bf16* __restrict__ Bt,
    const float* __restrict__ bias, void* __restrict__ Cout,
    int M, int N, int K) {
  constexpr int BM = 256, BK = 64;
  constexpr int A_ISSUES = BM / (8 * WAVES);
  constexpr int B_ISSUES = BN / (8 * WAVES);
  constexpr int LOADS = A_ISSUES + B_ISSUES;
  static_assert(NBUF == 2 && LOADS == 8, "vmcnt literal assumes LOADS=8");
  __shared__ __bf16 As[NBUF * BM * BK];
  __shared__ __bf16 Bs[NBUF * BN * BK];
  const int tid = threadIdx.x;
  const int wave = tid >> 6, lane = tid & 63;
  const int quad = lane >> 4, l16 = lane & 15;
  const int m0 = blockIdx.x * BM, n0 = blockIdx.y * BN;
  const int wm = (wave & 1) * 128;        // 2 waves in M
  const int wn = (wave >> 1) * 64;        // WAVES/2 waves in N
  const int lrow = lane >> 3, lchunk = lane & 7;
  f32x4 acc[8][4] = {};

  const __bf16* aSrc[A_ISSUES];
  const __bf16* bSrc[B_ISSUES];
  #pragma unroll
  for (int t = 0; t < A_ISSUES; ++t) {
    int row = (t * WAVES + wave) * 8 + lrow;
    aSrc[t] = A + (size_t)(m0 + row) * K + (lchunk ^ (row & 7)) * 8;
  }
  #pragma unroll
  for (int t = 0; t < B_ISSUES; ++t) {
    int row = (t * WAVES + wave) * 8 + lrow;
    bSrc[t] = Bt + (size_t)(n0 + row) * K + (lchunk ^ (row & 7)) * 8;
  }
  int aOff[8], bOff[4];
  #pragma unroll
  for (int rf = 0; rf < 8; ++rf) {
    int row = wm + rf * 16 + l16;
    aOff[rf] = row * BK + ((quad ^ (row & 7)) * 8);
  }
  #pragma unroll
  for (int cf = 0; cf < 4; ++cf) {
    int row = wn + cf * 16 + l16;
    bOff[cf] = row * BK + ((quad ^ (row & 7)) * 8);
  }

  auto stage = [&](__bf16* Ad, __bf16* Bd) {
    #pragma unroll
    for (int t = 0; t < A_ISSUES; ++t) {
      async16(aSrc[t], Ad + (t * WAVES + wave) * 8 * BK);
      aSrc[t] += BK;
    }
    #pragma unroll
    for (int t = 0; t < B_ISSUES; ++t) {
      async16(bSrc[t], Bd + (t * WAVES + wave) * 8 * BK);
      bSrc[t] += BK;
    }
  };

  __bf16 *cA0 = As, *cA1 = As + BM * BK;
  __bf16 *cB0 = Bs, *cB1 = Bs + BN * BK;
  const int nt = K / BK;
  stage(cA0, cB0);

  for (int t = 0; t < nt; ++t) {
    if (t + 1 < nt) stage(cA1, cB1);
    if (t + 1 < nt) asm volatile("s_waitcnt vmcnt(8)" ::: "memory");
    else            asm volatile("s_waitcnt vmcnt(0)" ::: "memory");
    asm volatile("s_barrier" ::: "memory");  // tile t published; prev buffer sealed

    bf16x8 af[4], ag[4], bv[4], bw[4];
    #pragma unroll
    for (int r = 0; r < 4; ++r) af[r] = *(const bf16x8*)(cA0 + aOff[r]);
    #pragma unroll
    for (int c = 0; c < 4; ++c) bv[c] = *(const bf16x8*)(cB0 + bOff[c]);
    // P0: prefetch A rf4-7 k0; MFMA rf0-3 x k0
    #pragma unroll
    for (int r = 0; r < 4; ++r) ag[r] = *(const bf16x8*)(cA0 + aOff[4 + r]);
    __builtin_amdgcn_s_setprio(1);
    #pragma unroll
    for (int c = 0; c < 4; ++c)
      #pragma unroll
      for (int r = 0; r < 4; ++r)
        acc[r][c] = __builtin_amdgcn_mfma_f32_16x16x32_bf16(af[r], bv[c], acc[r][c], 0, 0, 0);
    __builtin_amdgcn_s_setprio(0);
    asm volatile("s_barrier" ::: "memory");
    // P1: prefetch A rf0-3 k1 + B k1; MFMA rf4-7 x k0
    #pragma unroll
    for (int r = 0; r < 4; ++r) af[r] = *(const bf16x8*)(cA0 + (aOff[r] ^ 32));
    #pragma unroll
    for (int c = 0; c < 4; ++c) bw[c] = *(const bf16x8*)(cB0 + (bOff[c] ^ 32));
    __builtin_amdgcn_s_setprio(1);
    #pragma unroll
    for (int c = 0; c < 4; ++c)
      #pragma unroll
      for (int r = 0; r < 4; ++r)
        acc[4 + r][c] = __builtin_amdgcn_mfma_f32_16x16x32_bf16(ag[r], bv[c], acc[4 + r][c], 0, 0, 0);
    __builtin_amdgcn_s_setprio(0);
    asm volatile("s_barrier" ::: "memory");
    // P2: prefetch A rf4-7 k1; MFMA rf0-3 x k1
    #pragma unroll
    for (int r = 0; r < 4; ++r) ag[r] = *(const bf16x8*)(cA0 + (aOff[4 + r] ^ 32));
    __builtin_amdgcn_s_setprio(1);
    #pragma unroll
    for (int c = 0; c < 4; ++c)
      #pragma unroll
      for (int r = 0; r < 4; ++r)
        acc[r][c] = __builtin_amdgcn_mfma_f32_16x16x32_bf16(af[r], bw[c], acc[r][c], 0, 0, 0);
    __builtin_amdgcn_s_setprio(0);
    asm volatile("s_barrier" ::: "memory");
    // P3: MFMA rf4-7 x k1
    __builtin_amdgcn_s_setprio(1);
    #pragma unroll
    for (int c = 0; c < 4; ++c)
      #pragma unroll
      for (int r = 0; r < 4; ++r)
        acc[4 + r][c] = __builtin_amdgcn_mfma_f32_16x16x32_bf16(ag[r], bw[c], acc[4 + r][c], 0, 0, 0);
    __builtin_amdgcn_s_setprio(0);
    asm volatile("s_barrier" ::: "memory");  // tile seal

    __bf16* x;
    x = cA0; cA0 = cA1; cA1 = x;
    x = cB0; cB0 = cB1; cB1 = x;
  }

  #pragma unroll
  for (int rf = 0; rf < 8; ++rf)
    #pragma unroll
    for (int cf = 0; cf < 4; ++cf)
      #pragma unroll
      for (int r = 0; r < 4; ++r) {
        int m = m0 + wm + rf * 16 + quad * 4 + r;
        int n = n0 + wn + cf * 16 + l16;
        float v = acc[rf][cf][r];
        if (BIAS) v += bias[n];
        if (ACT == 1) v = 1.0f / (1.0f + __expf(-v));
        if (OUT_BF16)
          ((__bf16*)Cout)[(size_t)m * N + n] = (__bf16)v;
        else
          ((float*)Cout)[(size_t)m * N + n] = v;
      }
}

// ============================================================================
// gemm_bt: the R1 measured-best structure (54.7us at 8192x1024x2048).
// 2-buf, stage(next) under compute(cur), vmcnt(0)+barrier per K-step.
// Used for GEMM2, GEMM3 (SUMA), GEMM4.
// ============================================================================
template <int BM, int BN, int WAVES, int OUT_BF16, int ACT, int BIAS, int SUMA>
__global__ __launch_bounds__(WAVES * 64) void gemm_bt(
    const __bf16* __restrict__ A, const __bf16* __restrict__ Bt,
    const float* __restrict__ bias, void* __restrict__ Cout,
    int M, int N, int K, const __bf16* __restrict__ A2) {
  constexpr int BK = 64;               // 8 chunks of 16B per row
  constexpr int WAVES_N = WAVES / 2;
  constexpr int WTM = BM / 32;
  constexpr int WTN = BN / (WAVES_N * 16);
  constexpr int NBUF = SUMA ? 1 : 2;
  constexpr int A_ISSUES = BM / (8 * WAVES);
  constexpr int B_ISSUES = BN / (8 * WAVES);
  __shared__ __bf16 As[NBUF * BM * BK];
  __shared__ __bf16 Bs[NBUF * BN * BK];
  const int tid = threadIdx.x;
  const int wave = tid >> 6, lane = tid & 63;
  const int quad = lane >> 4, l16 = lane & 15;
  const int m0 = blockIdx.x * BM, n0 = blockIdx.y * BN;
  const int ks = K / gridDim.z;
  const int kbeg = blockIdx.z * ks;
  const int wm = (wave & 1) * (BM / 2);
  const int wn = (wave >> 1) * (BN / WAVES_N);
  const int lrow = lane >> 3;
  const int lchunk = lane & 7;
  f32x4 acc[WTM][WTN] = {};

  const __bf16* aSrc[A_ISSUES];
  const __bf16* bSrc[B_ISSUES];
  #pragma unroll
  for (int t = 0; t < A_ISSUES; ++t) {
    int row = (t * WAVES + wave) * 8 + lrow;
    aSrc[t] = A + (size_t)(m0 + row) * K + kbeg + (lchunk ^ (row & 7)) * 8;
  }
  #pragma unroll
  for (int t = 0; t < B_ISSUES; ++t) {
    int row = (t * WAVES + wave) * 8 + lrow;
    bSrc[t] = Bt + (size_t)(n0 + row) * K + kbeg + (lchunk ^ (row & 7)) * 8;
  }
  int aOff[WTM][2], bOff[WTN][2];
  #pragma unroll
  for (int i = 0; i < WTM; ++i) {
    int row = wm + i * 16 + l16;
    #pragma unroll
    for (int kk = 0; kk < 2; ++kk)
      aOff[i][kk] = row * BK + (((kk * 4 + quad) ^ (row & 7)) * 8);
  }
  #pragma unroll
  for (int j = 0; j < WTN; ++j) {
    int row = wn + j * 16 + l16;
    #pragma unroll
    for (int kk = 0; kk < 2; ++kk)
      bOff[j][kk] = row * BK + (((kk * 4 + quad) ^ (row & 7)) * 8);
  }

  auto stage = [&](__bf16* Ad, __bf16* Bd) {
    #pragma unroll
    for (int t = 0; t < A_ISSUES; ++t) {
      async16(aSrc[t], Ad + (t * WAVES + wave) * 8 * BK);
      aSrc[t] += BK;
    }
    #pragma unroll
    for (int t = 0; t < B_ISSUES; ++t) {
      async16(bSrc[t], Bd + (t * WAVES + wave) * 8 * BK);
      bSrc[t] += BK;
    }
  };
  auto compute = [&](const __bf16* Ab, const __bf16* Bb) {
    #pragma unroll
    for (int kk = 0; kk < 2; ++kk) {
      bf16x8 af[WTM], bfr[WTN];
      #pragma unroll
      for (int i = 0; i < WTM; ++i) af[i] = *(const bf16x8*)(Ab + aOff[i][kk]);
      #pragma unroll
      for (int j = 0; j < WTN; ++j) bfr[j] = *(const bf16x8*)(Bb + bOff[j][kk]);
      #pragma unroll
      for (int i = 0; i < WTM; ++i)
        #pragma unroll
        for (int j = 0; j < WTN; ++j)
          acc[i][j] = __builtin_amdgcn_mfma_f32_16x16x32_bf16(af[i], bfr[j], acc[i][j], 0, 0, 0);
    }
  };

  const int niter = ks / BK;
  if constexpr (SUMA) {
    for (int it = 0; it < niter; ++it) {
      __syncthreads();
      #pragma unroll
      for (int t = 0; t < A_ISSUES; ++t) {
        int row = (t * WAVES + wave) * 8 + lrow;
        size_t go = (size_t)(m0 + row) * K + kbeg + it * BK + lchunk * 8;
        bf16x8 a0 = *(const bf16x8*)(A + go);
        bf16x8 a1 = *(const bf16x8*)(A2 + go);
        bf16x8 s;
        #pragma unroll
        for (int q = 0; q < 8; ++q) s[q] = (__bf16)((float)a0[q] + (float)a1[q]);
        *(bf16x8*)(As + row * BK + ((lchunk ^ (row & 7)) * 8)) = s;
      }
      #pragma unroll
      for (int t = 0; t < B_ISSUES; ++t) {
        async16(bSrc[t], Bs + (t * WAVES + wave) * 8 * BK);
        bSrc[t] += BK;
      }
      __syncthreads();
      compute(As, Bs);
    }
  } else {
    __bf16* curA = As;  __bf16* nxtA = As + BM * BK;
    __bf16* curB = Bs;  __bf16* nxtB = Bs + BN * BK;
    stage(curA, curB);
    asm volatile("s_waitcnt vmcnt(0)" ::: "memory");
    __builtin_amdgcn_s_barrier();
    for (int it = 0; it < niter - 1; ++it) {
      stage(nxtA, nxtB);            // tile it+1 flies under compute(it)
      compute(curA, curB);
      asm volatile("s_waitcnt vmcnt(0)" ::: "memory");
      __builtin_amdgcn_s_barrier();
      { __bf16* t = curA; curA = nxtA; nxtA = t; }
      { __bf16* t = curB; curB = nxtB; nxtB = t; }
    }
    compute(curA, curB);
  }

  char* Cz = (char*)Cout + (size_t)blockIdx.z * M * N * (OUT_BF16 ? 2 : 4);
  #pragma unroll
  for (int i = 0; i < WTM; ++i)
    #pragma unroll
    for (int j = 0; j < WTN; ++j)
      #pragma unroll
      for (int r = 0; r < 4; ++r) {
        int m = m0 + wm + i * 16 + quad * 4 + r;
        int n = n0 + wn + j * 16 + l16;
        float v = acc[i][j][r];
        if (BIAS) v += bias[n];
        if (ACT == 1) v = 1.0f / (1.0f + __expf(-v));
        if (OUT_BF16)
          ((__bf16*)Cz)[(size_t)m * N + n] = (__bf16)v;
        else
          ((float*)Cz)[(size_t)m * N + n] = v;
      }
}

// Router: split-K reduce + 2-layer router + top-2 -> packed e01 + g01.
// Block 0 also zeroes the per-expert counters for the fill kernel.
__global__ __launch_bounds__(256) void router_kernel(
    const float* __restrict__ contP, const float* __restrict__ s2c_b,
    const float* __restrict__ rW1, const float* __restrict__ rb1,
    const float* __restrict__ rW2, const float* __restrict__ rb2,
    __bf16* __restrict__ contB, int* __restrict__ e01,
    float2* __restrict__ g01, int* __restrict__ cnt) {
  if (blockIdx.x == 0 && threadIdx.x < NEXP) cnt[threadIdx.x] = 0;
  const int wave = threadIdx.x >> 6, lane = threadIdx.x & 63;
  const int n = blockIdx.x * 4 + wave;
  const size_t base = (size_t)n * 64 + lane;
  const size_t slab = (size_t)TOK * 64;
  float c = contP[base] + contP[base + slab] + contP[base + 2 * slab] +
            contP[base + 3 * slab] + s2c_b[lane];
  contB[base] = (__bf16)c;
  float acc = rb1[lane];
  #pragma unroll
  for (int i = 0; i < 64; ++i) {
    float ci = __shfl(c, i);
    acc = fmaf(ci, rW1[i * 64 + lane], acc);
  }
  float t = tanhf(acc);
  float logit[8];
  #pragma unroll
  for (int e = 0; e < 8; ++e) {
    float v = t * rW2[lane * 8 + e];
    #pragma unroll
    for (int o = 32; o; o >>= 1) v += __shfl_xor(v, o);
    logit[e] = v + rb2[e];
  }
  float mx = logit[0];
  #pragma unroll
  for (int e = 1; e < 8; ++e) mx = fmaxf(mx, logit[e]);
  float p[8];
  #pragma unroll
  for (int e = 0; e < 8; ++e) p[e] = __expf(logit[e] - mx);
  float v0 = p[0]; int e0 = 0;
  #pragma unroll
  for (int e = 1; e < 8; ++e) if (p[e] > v0) { v0 = p[e]; e0 = e; }
  float v1 = -1.0f; int e1 = 0;
  #pragma unroll
  for (int e = 0; e < 8; ++e) if (e != e0 && p[e] > v1) { v1 = p[e]; e1 = e; }
  float inv = 1.0f / (v0 + v1);
  if (lane == 0) {
    e01[n] = e0 | (e1 << 8);
    g01[n] = make_float2(v0 * inv, v1 * inv);
  }
}

// Fill: build per-expert token lists (tok | rank<<31) with LDS-aggregated
// histogram; 8 global atomics per block (256 total -- no hot-address serial).
__global__ __launch_bounds__(256) void fill_kernel(
    const int* __restrict__ e01, int* __restrict__ cnt,
    unsigned* __restrict__ idxb) {
  __shared__ int lcnt[NEXP], lbase[NEXP];
  const int tid = threadIdx.x;
  if (tid < NEXP) lcnt[tid] = 0;
  __syncthreads();
  const int n = blockIdx.x * 256 + tid;
  const int pe = e01[n];
  const int e0 = pe & 0xff, e1 = (pe >> 8) & 0xff;
  const int p0 = atomicAdd(&lcnt[e0], 1);
  const int p1 = atomicAdd(&lcnt[e1], 1);
  __syncthreads();
  if (tid < NEXP) lbase[tid] = atomicAdd(&cnt[tid], lcnt[tid]);
  __syncthreads();
  idxb[e0 * TOK + lbase[e0] + p0] = (unsigned)n;
  idxb[e1 * TOK + lbase[e1] + p1] = (unsigned)n | 0x80000000u;
}

// Sparse MoE: block = (chunk of 64 tokens of expert e's list). Gathers contB
// rows by token index (L2-resident), computes the expert MLP, scatters gated
// bf16 rows to slab0 (rank 0) / slab1 (rank 1). Per-token math identical to
// the dense version (row-independent MFMAs) -> bit-exact outputs.
__global__ __launch_bounds__(256) void moe_sparse_kernel(
    const __bf16* __restrict__ contB, const __bf16* __restrict__ We1T,
    const __bf16* __restrict__ We2T, const float* __restrict__ be1,
    const float* __restrict__ be2, const unsigned* __restrict__ idxb,
    const int* __restrict__ cnt, const float2* __restrict__ g01,
    __bf16* __restrict__ slab0, __bf16* __restrict__ slab1) {
  constexpr int TT = 64;
  const int e = blockIdx.y;
  const int start = blockIdx.x * TT;
  const int ne = cnt[e];
  if (start >= ne) return;
  const int nval = min(TT, ne - start);
  __shared__ __bf16 cont_s[TT * 64];
  __shared__ __bf16 w1_s[64 * 64];
  __shared__ __bf16 w2_s[64 * 64];
  __shared__ __bf16 h_s[TT * 64];
  __shared__ unsigned tok_s[TT];
  __shared__ float gate_s[TT];
  const int tid = threadIdx.x;
  const int wave = tid >> 6, lane = tid & 63;
  const int quad = lane >> 4, l16 = lane & 15;
  if (tid < TT) {
    unsigned v = idxb[e * TOK + start + ((tid < nval) ? tid : 0)];
    unsigned tok = v & 0x7fffffffu;
    float2 g = g01[tok];
    tok_s[tid] = v;
    gate_s[tid] = (v >> 31) ? g.y : g.x;
  }
  __syncthreads();
  // gather cont rows into swizzled LDS (rows are 128B contiguous in contB)
  for (int i = tid; i < TT * 8; i += 256) {
    int r = i >> 3, cc = i & 7;
    unsigned tok = tok_s[r] & 0x7fffffffu;
    *(uint4*)(cont_s + r * 64 + ((cc ^ (r & 7)) * 8)) =
        *(const uint4*)(contB + (size_t)tok * 64 + cc * 8);
  }
  const int wtok = wave * 16;
  f32x4 acc2[4] = {};
  for (int hc = 0; hc < HHALF; hc += 64) {
    __syncthreads();
    for (int c = tid; c < 512; c += 256) {
      int r = c >> 3, cc = c & 7;
      *(uint4*)(w1_s + r * 64 + ((cc ^ (r & 7)) * 8)) =
          *(const uint4*)(We1T + ((size_t)e * HHALF + hc + r) * 64 + cc * 8);
      *(uint4*)(w2_s + r * 64 + ((cc ^ (r & 7)) * 8)) =
          *(const uint4*)(We2T + ((size_t)e * 64 + r) * HHALF + hc + cc * 8);
    }
    __syncthreads();
    f32x4 acc1[4] = {};
    #pragma unroll
    for (int kk = 0; kk < 2; ++kk) {
      bf16x8 af, bfr[4];
      {
        int row = wtok + l16;
        af = *(const bf16x8*)(cont_s + row * 64 + (((kk * 4 + quad) ^ (row & 7)) * 8));
      }
      #pragma unroll
      for (int j = 0; j < 4; ++j) {
        int row = j * 16 + l16;
        bfr[j] = *(const bf16x8*)(w1_s + row * 64 + (((kk * 4 + quad) ^ (row & 7)) * 8));
      }
      #pragma unroll
      for (int j = 0; j < 4; ++j)
        acc1[j] = __builtin_amdgcn_mfma_f32_16x16x32_bf16(af, bfr[j], acc1[j], 0, 0, 0);
    }
    // h = relu(acc1 + be1) -> wave-private h_s rows (no barrier needed)
    #pragma unroll
    for (int j = 0; j < 4; ++j)
      #pragma unroll
      for (int r = 0; r < 4; ++r) {
        int tr = wtok + quad * 4 + r;
        int hcol = j * 16 + l16;
        float v = acc1[j][r] + be1[e * HHALF + hc + hcol];
        h_s[tr * 64 + (((hcol >> 3) ^ (tr & 7)) * 8) + (hcol & 7)] =
            (__bf16)fmaxf(v, 0.0f);
      }
    #pragma unroll
    for (int kk = 0; kk < 2; ++kk) {
      bf16x8 af, bfr[4];
      {
        int row = wtok + l16;
        af = *(const bf16x8*)(h_s + row * 64 + (((kk * 4 + quad) ^ (row & 7)) * 8));
      }
      #pragma unroll
      for (int j = 0; j < 4; ++j) {
        int row = j * 16 + l16;
        bfr[j] = *(const bf16x8*)(w2_s + row * 64 + (((kk * 4 + quad) ^ (row & 7)) * 8));
      }
      #pragma unroll
      for (int j = 0; j < 4; ++j)
        acc2[j] = __builtin_amdgcn_mfma_f32_16x16x32_bf16(af, bfr[j], acc2[j], 0, 0, 0);
    }
  }
  #pragma unroll
  for (int j = 0; j < 4; ++j)
    #pragma unroll
    for (int r = 0; r < 4; ++r) {
      int tr = wtok + quad * 4 + r;
      if (tr < nval) {
        unsigned v = tok_s[tr];
        unsigned tok = v & 0x7fffffffu;
        int m = j * 16 + l16;
        float o = gate_s[tr] * (acc2[j][r] + be2[e * 64 + m]);
        __bf16* slab = (v >> 31) ? slab1 : slab0;
        slab[(size_t)tok * 64 + m] = (__bf16)o;
      }
    }
}

__global__ __launch_bounds__(256) void ln_kernel(
    const float* __restrict__ x, const float* __restrict__ g,
    const float* __restrict__ b, float* __restrict__ out) {
  const int row = blockIdx.x;
  const float4 v = ((const float4*)(x + (size_t)row * 1024))[threadIdx.x];
  float s1 = v.x + v.y + v.z + v.w;
  float s2 = v.x * v.x + v.y * v.y + v.z * v.z + v.w * v.w;
  #pragma unroll
  for (int o = 32; o; o >>= 1) { s1 += __shfl_xor(s1, o); s2 += __shfl_xor(s2, o); }
  __shared__ float ws1[4], ws2[4];
  const int wave = threadIdx.x >> 6, lane = threadIdx.x & 63;
  if (lane == 0) { ws1[wave] = s1; ws2[wave] = s2; }
  __syncthreads();
  s1 = ws1[0] + ws1[1] + ws1[2] + ws1[3];
  s2 = ws2[0] + ws2[1] + ws2[2] + ws2[3];
  const float mu = s1 * (1.0f / 1024.0f);
  const float var = s2 * (1.0f / 1024.0f) - mu * mu;
  const float inv = rsqrtf(var + 1e-5f);
  const int col = threadIdx.x * 4;
  const float4 gv = *(const float4*)(g + col);
  const float4 bv = *(const float4*)(b + col);
  float4 o;
  o.x = (v.x - mu) * inv * gv.x + bv.x;
  o.y = (v.y - mu) * inv * gv.y + bv.y;
  o.z = (v.z - mu) * inv * gv.z + bv.z;
  o.w = (v.w - mu) * inv * gv.w + bv.w;
  *(float4*)(out + (size_t)row * 1024 + col) = o;
}

extern "C" void kernel_launch(void* const* d_in, const int* in_sizes, int n_in,
                              void* d_out, int out_size, void* d_ws, size_t ws_size,
                              hipStream_t stream) {
  const float* X     = (const float*)d_in[0];
  const float* enc_W = (const float*)d_in[1];
  const float* enc_b = (const float*)d_in[2];
  const float* s2c_W = (const float*)d_in[3];
  const float* s2c_b = (const float*)d_in[4];
  const float* rW1   = (const float*)d_in[5];
  const float* rb1   = (const float*)d_in[6];
  const float* rW2   = (const float*)d_in[7];
  const float* rb2   = (const float*)d_in[8];
  const float* We1   = (const float*)d_in[9];
  const float* be1   = (const float*)d_in[10];
  const float* We2   = (const float*)d_in[11];
  const float* be2   = (const float*)d_in[12];
  const float* c2s_W = (const float*)d_in[13];
  const float* c2s_b = (const float*)d_in[14];
  const float* dec_W = (const float*)d_in[15];
  const float* dec_b = (const float*)d_in[16];
  const float* ln_g  = (const float*)d_in[17];
  const float* ln_b  = (const float*)d_in[18];
  float* out = (float*)d_out;

  // ---- workspace layout with explicit aliasing (~78 MB total) ----
  char* ws = (char*)d_ws;
  size_t off = 0;
  auto take = [&](size_t bytes) -> char* {
    char* p = ws + off;
    off = (off + bytes + 255) & ~(size_t)255;
    return p;
  };
  const size_t SLAB = (size_t)TOK * HDIM * 2;       // 33,554,432
  char*   slabA     = take(SLAB);
  char*   slabB     = take(SLAB);
  __bf16* encWT     = (__bf16*)take((size_t)HDIM * DMODEL * 2);
  __bf16* s2cWT     = (__bf16*)take((size_t)MDIM * HDIM * 2);
  __bf16* c2sWT     = (__bf16*)take((size_t)HDIM * MDIM * 2);
  __bf16* decWT     = (__bf16*)take((size_t)DMODEL * HDIM * 2);
  __bf16* We1T      = (__bf16*)take((size_t)NEXP * HHALF * MDIM * 2);
  __bf16* We2T      = (__bf16*)take((size_t)NEXP * MDIM * HHALF * 2);
  __bf16* contB     = (__bf16*)take((size_t)TOK * MDIM * 2);
  int*    e01       = (int*)take((size_t)TOK * 4);
  float2* g01       = (float2*)take((size_t)TOK * 8);
  __bf16* oslab0    = (__bf16*)take((size_t)TOK * MDIM * 2);
  __bf16* oslab1    = (__bf16*)take((size_t)TOK * MDIM * 2);
  int*     cnt      = (int*)take((size_t)NEXP * 4);
  unsigned* idxb    = (unsigned*)take((size_t)NEXP * TOK * 4);
  if (off > ws_size) return;  // insufficient workspace -> clean correctness fail

  __bf16* Xb        = (__bf16*)slabA;                       // dead after GEMM1
  float*  contP     = (float*)(slabA + (size_t)TOK * DMODEL * 2);  // dead after router
  __bf16* spikesMoe = (__bf16*)slabA;                       // born at GEMM3
  __bf16* spikesEnc = (__bf16*)slabB;                       // dead after GEMM2
  float*  decoded   = (float*)slabB;                        // born at GEMM4

  // fused preamble: cvt(X) + 6 weight transposes in ONE launch
  preamble_kernel<<<PREAMBLE_BLOCKS, 256, 0, stream>>>(
      X, Xb, enc_W, encWT, s2c_W, s2cWT, c2s_W, c2sWT, dec_W, decWT,
      We1, We1T, We2, We2T);

  // GEMM1 (A/B: mega-tile 256x256, 8 waves, 2/SIMD): sigmoid(X @ enc_W + b)
  gemm_mt<256, 8, 2, 1, 1, 1><<<dim3(TOK / 256, HDIM / 256), 512, 0, stream>>>(
      Xb, encWT, enc_b, spikesEnc, TOK, HDIM, DMODEL);
  // GEMM2 (split-K x4): contP[z] = spikesEnc @ s2c_W partials   8192x64, K=2048
  gemm_bt<128, 64, 4, 0, 0, 0, 0><<<dim3(TOK / 128, 1, 4), 256, 0, stream>>>(
      spikesEnc, s2cWT, nullptr, contP, TOK, MDIM, HDIM, nullptr);
  // router: reduce partials + bias, top-2 -> e01/g01 (+ zero cnt)
  router_kernel<<<TOK / 4, 256, 0, stream>>>(contP, s2c_b, rW1, rb1, rW2, rb2,
                                             contB, e01, g01, cnt);
  // fill: per-expert token lists (LDS-aggregated; 256 global atomics total)
  fill_kernel<<<TOK / 256, 256, 0, stream>>>(e01, cnt, idxb);
  // sparse MoE (top-2 only: 4.3 GFLOP vs 17.2 dense) -> rank-slabs
  moe_sparse_kernel<<<dim3(TOK / 64, NEXP), 256, 0, stream>>>(
      contB, We1T, We2T, be1, be2, idxb, cnt, g01, oslab0, oslab1);
  // GEMM3 (SUMA): spikesMoe = sigmoid((slab0+slab1) @ c2s_W + b)  8192x2048, K=64
  gemm_bt<128, 128, 4, 1, 1, 1, 1><<<dim3(TOK / 128, HDIM / 128, 1), 256, 0, stream>>>(
      oslab0, c2sWT, c2s_b, spikesMoe, TOK, HDIM, MDIM, oslab1);
  // GEMM4 (R1 measured-best bt): decoded = sigmoid(spikesMoe @ dec_W + b)
  gemm_bt<128, 128, 4, 0, 1, 1, 0><<<dim3(TOK / 128, DMODEL / 128, 1), 256, 0, stream>>>(
      spikesMoe, decWT, dec_b, decoded, TOK, DMODEL, HDIM, nullptr);
  ln_kernel<<<TOK, 256, 0, stream>>>(decoded, ln_g, ln_b, out);
}

// Round 5
// 304.745 us; speedup vs baseline: 1.0593x; 1.0229x over previous
//
#include <hip/hip_runtime.h>
#include <hip/hip_bf16.h>
#include <cstdint>
#include <cstddef>

#define TOK    8192
#define DMODEL 1024
#define HDIM   2048
#define MDIM   64
#define NEXP   8
#define HHALF  1024

using f32x4  = __attribute__((ext_vector_type(4))) float;
using bf16x8 = __attribute__((ext_vector_type(8))) __bf16;
using bf16x4 = __attribute__((ext_vector_type(4))) __bf16;

// async global->LDS, 16B per lane. LDS dest is wave-uniform base + lane*16.
__device__ __forceinline__ void async16(const void* g, void* l) {
  __builtin_amdgcn_global_load_lds(
      (const __attribute__((address_space(1))) unsigned int*)g,
      (__attribute__((address_space(3))) unsigned int*)l, 16, 0, 0);
}

// One-launch preamble: cvt(X) + transpose-cvt of all 6 weight tensors.
__global__ __launch_bounds__(256) void preamble_kernel(
    const float* __restrict__ X, __bf16* __restrict__ Xb,
    const float* __restrict__ encW, __bf16* __restrict__ encWT,
    const float* __restrict__ s2cW, __bf16* __restrict__ s2cWT,
    const float* __restrict__ c2sW, __bf16* __restrict__ c2sWT,
    const float* __restrict__ decW, __bf16* __restrict__ decWT,
    const float* __restrict__ We1, __bf16* __restrict__ We1T,
    const float* __restrict__ We2, __bf16* __restrict__ We2T) {
  __shared__ float ts[32][33];
  const int tid = threadIdx.x;
  int b = blockIdx.x;
  if (b < 8192) {  // X: 8192x1024 fp32 -> bf16 (float4 per thread)
    int i = b * 256 + tid;
    float4 v = ((const float4*)X)[i];
    bf16x4 o = { (__bf16)v.x, (__bf16)v.y, (__bf16)v.z, (__bf16)v.w };
    ((bf16x4*)Xb)[i] = o;
    return;
  }
  b -= 8192;
  const float* in; __bf16* outp; int R, C, tx, ty;
  if (b < 2048)              { in = encW; outp = encWT; R = 1024; C = 2048; tx = b % 64; ty = b / 64; }
  else if ((b -= 2048) < 128){ in = s2cW; outp = s2cWT; R = 2048; C = 64;   tx = b % 2;  ty = b / 2;  }
  else if ((b -= 128) < 128) { in = c2sW; outp = c2sWT; R = 64;   C = 2048; tx = b % 64; ty = b / 64; }
  else if ((b -= 128) < 2048){ in = decW; outp = decWT; R = 2048; C = 1024; tx = b % 32; ty = b / 32; }
  else if ((b -= 2048) < 512){ int s = b / 64, t = b % 64;
                               in = We1 + (size_t)s * 65536; outp = We1T + (size_t)s * 65536;
                               R = 64; C = 1024; tx = t % 32; ty = t / 32; }
  else                       { b -= 512; int s = b / 64, t = b % 64;
                               in = We2 + (size_t)s * 65536; outp = We2T + (size_t)s * 65536;
                               R = 1024; C = 64; tx = t % 2; ty = t / 2; }
  const int c0 = tx * 32, r0 = ty * 32;
  const int x = tid & 31, y = tid >> 5;
  #pragma unroll
  for (int i = y; i < 32; i += 8) ts[i][x] = in[(size_t)(r0 + i) * C + c0 + x];
  __syncthreads();
  #pragma unroll
  for (int i = y; i < 32; i += 8)
    outp[(size_t)(c0 + i) * R + r0 + x] = (__bf16)ts[x][i];
}
#define PREAMBLE_BLOCKS (8192 + 2048 + 128 + 128 + 2048 + 512 + 512)

// ============================================================================
// gemm_8p: faithful m201-style phase schedule. BM=256, BK=64, 8 waves,
// NBUF=2. Per-wave output 128 x (BN/4): BN=256 -> acc[8][4], BN=128 -> acc[8][2].
// Per K-tile, 4 phases; each phase:
//   { ds_read quadrant frags ; stage one 2-load group ; [vmcnt(2)] ;
//     s_barrier ; sched_barrier(0) ; setprio(1) ; MFMA quadrant ; setprio(0) ;
//     s_barrier }
// Stage groups ordered by consumption: B01, [B23,] A02, A13.
//   Quadrant reads: P0 af(rows wm..wm+63 = A-even chunk) + bv(B chunk wn/64);
//   P1 ag(rows wm+64.. = A-odd chunk); P2 af2+bw (kk1, same chunks); P3 ag2.
// Publication chain (race audit):
//   - A-even+B of tile t land before the vmcnt(2) at t-1's LAST stage phase
//     (only A13(t) still in flight); published by that phase's trailing
//     barrier -> safe for t.P0 reads.
//   - A13(t) lands before the vmcnt(2) at t.P0 (only B01(t+1) in flight);
//     published by P0's first barrier -> safe for t.P1 reads.
//   - Buffer overwrite: stage into nxt at t.P* targets tile t-1's buffer;
//     all t-1 readers' lgkm waits precede their MFMA which precedes t-1.P3's
//     trailing barrier, which precedes any t.P0 stage issue.
// Arithmetic order per acc element: K-tiles in order, kk0 then kk1 (identical
// to prior kernels -> same absmax).
// ============================================================================
template <int BN, int OUT_BF16, int ACT, int BIAS>
__global__ __launch_bounds__(512, 2) void gemm_8p(
    const __bf16* __restrict__ A, const __bf16* __restrict__ Bt,
    const float* __restrict__ bias, void* __restrict__ Cout,
    int M, int N, int K) {
  constexpr int BM = 256, BK = 64;
  constexpr int WTN = BN / 64;            // per-wave N frags (4 or 2)
  constexpr int A_LOADS = 4;              // BM / (8 waves * 8 rows)
  constexpr int B_LOADS = BN / 64;        // 4 or 2
  __shared__ __bf16 As[2 * BM * BK];
  __shared__ __bf16 Bs[2 * BN * BK];
  const int tid = threadIdx.x;
  const int wave = tid >> 6, lane = tid & 63;
  const int quad = lane >> 4, l16 = lane & 15;
  const int m0 = blockIdx.x * BM, n0 = blockIdx.y * BN;
  const int wm = (wave & 1) * 128;        // 2 waves in M
  const int wn = (wave >> 1) * (BN / 4);  // 4 waves in N
  const int lrow = lane >> 3, lchunk = lane & 7;
  f32x4 acc[8][WTN] = {};

  const __bf16* aSrc[A_LOADS];
  const __bf16* bSrc[B_LOADS];
  #pragma unroll
  for (int t = 0; t < A_LOADS; ++t) {
    int row = (t * 8 + wave) * 8 + lrow;
    aSrc[t] = A + (size_t)(m0 + row) * K + (lchunk ^ (row & 7)) * 8;
  }
  #pragma unroll
  for (int t = 0; t < B_LOADS; ++t) {
    int row = (t * 8 + wave) * 8 + lrow;
    bSrc[t] = Bt + (size_t)(n0 + row) * K + (lchunk ^ (row & 7)) * 8;
  }
  int aOff[8], bOff[WTN];
  #pragma unroll
  for (int rf = 0; rf < 8; ++rf) {
    int row = wm + rf * 16 + l16;
    aOff[rf] = row * BK + ((quad ^ (row & 7)) * 8);
  }
  #pragma unroll
  for (int cf = 0; cf < WTN; ++cf) {
    int row = wn + cf * 16 + l16;
    bOff[cf] = row * BK + ((quad ^ (row & 7)) * 8);
  }

  auto stageA = [&](int t, __bf16* Ad) {
    async16(aSrc[t], Ad + (t * 8 + wave) * 8 * BK);
    aSrc[t] += BK;
  };
  auto stageB = [&](int t, __bf16* Bd) {
    async16(bSrc[t], Bd + (t * 8 + wave) * 8 * BK);
    bSrc[t] += BK;
  };

  __bf16 *curA = As, *nxtA = As + BM * BK;
  __bf16 *curB = Bs, *nxtB = Bs + BN * BK;
  const int nt = K / BK;

  // prologue: stage tile0 (group order), drain, publish
  stageB(0, curB); stageB(1, curB);
  if constexpr (BN == 256) { stageB(2, curB); stageB(3, curB); }
  stageA(0, curA); stageA(2, curA);
  stageA(1, curA); stageA(3, curA);
  asm volatile("s_waitcnt vmcnt(0)" ::: "memory");
  __builtin_amdgcn_s_barrier();

  for (int t = 0; t < nt; ++t) {
    const bool pre = (t + 1 < nt);
    // ---- P0: Q0 = rf0-3 x kk0 ----
    bf16x8 af[4], bv[WTN];
    #pragma unroll
    for (int r = 0; r < 4; ++r) af[r] = *(const bf16x8*)(curA + aOff[r]);
    #pragma unroll
    for (int c = 0; c < WTN; ++c) bv[c] = *(const bf16x8*)(curB + bOff[c]);
    if (pre) {
      stageB(0, nxtB); stageB(1, nxtB);
      asm volatile("s_waitcnt vmcnt(2)" ::: "memory");  // A13(t) landed
    } else {
      asm volatile("s_waitcnt vmcnt(0)" ::: "memory");
    }
    __builtin_amdgcn_s_barrier();
    __builtin_amdgcn_sched_barrier(0);
    __builtin_amdgcn_s_setprio(1);
    #pragma unroll
    for (int c = 0; c < WTN; ++c)
      #pragma unroll
      for (int r = 0; r < 4; ++r)
        acc[r][c] = __builtin_amdgcn_mfma_f32_16x16x32_bf16(af[r], bv[c], acc[r][c], 0, 0, 0);
    __builtin_amdgcn_s_setprio(0);
    __builtin_amdgcn_s_barrier();
    // ---- P1: Q1 = rf4-7 x kk0 ----
    bf16x8 ag[4];
    #pragma unroll
    for (int r = 0; r < 4; ++r) ag[r] = *(const bf16x8*)(curA + aOff[4 + r]);
    if (pre) {
      if constexpr (BN == 256) { stageB(2, nxtB); stageB(3, nxtB); }
      else                     { stageA(0, nxtA); stageA(2, nxtA); }
    }
    __builtin_amdgcn_s_barrier();
    __builtin_amdgcn_sched_barrier(0);
    __builtin_amdgcn_s_setprio(1);
    #pragma unroll
    for (int c = 0; c < WTN; ++c)
      #pragma unroll
      for (int r = 0; r < 4; ++r)
        acc[4 + r][c] = __builtin_amdgcn_mfma_f32_16x16x32_bf16(ag[r], bv[c], acc[4 + r][c], 0, 0, 0);
    __builtin_amdgcn_s_setprio(0);
    __builtin_amdgcn_s_barrier();
    // ---- P2: Q2 = rf0-3 x kk1 ----
    bf16x8 af2[4], bw[WTN];
    #pragma unroll
    for (int r = 0; r < 4; ++r) af2[r] = *(const bf16x8*)(curA + (aOff[r] ^ 32));
    #pragma unroll
    for (int c = 0; c < WTN; ++c) bw[c] = *(const bf16x8*)(curB + (bOff[c] ^ 32));
    if (pre) {
      if constexpr (BN == 256) { stageA(0, nxtA); stageA(2, nxtA); }
      else {
        stageA(1, nxtA); stageA(3, nxtA);
        asm volatile("s_waitcnt vmcnt(2)" ::: "memory");  // B01+A02(t+1) landed
      }
    }
    __builtin_amdgcn_s_barrier();
    __builtin_amdgcn_sched_barrier(0);
    __builtin_amdgcn_s_setprio(1);
    #pragma unroll
    for (int c = 0; c < WTN; ++c)
      #pragma unroll
      for (int r = 0; r < 4; ++r)
        acc[r][c] = __builtin_amdgcn_mfma_f32_16x16x32_bf16(af2[r], bw[c], acc[r][c], 0, 0, 0);
    __builtin_amdgcn_s_setprio(0);
    __builtin_amdgcn_s_barrier();
    // ---- P3: Q3 = rf4-7 x kk1 ----
    bf16x8 ag2[4];
    #pragma unroll
    for (int r = 0; r < 4; ++r) ag2[r] = *(const bf16x8*)(curA + (aOff[4 + r] ^ 32));
    if (pre) {
      if constexpr (BN == 256) {
        stageA(1, nxtA); stageA(3, nxtA);
        asm volatile("s_waitcnt vmcnt(2)" ::: "memory");  // B+A02(t+1) landed
      }
    }
    __builtin_amdgcn_s_barrier();
    __builtin_amdgcn_sched_barrier(0);
    __builtin_amdgcn_s_setprio(1);
    #pragma unroll
    for (int c = 0; c < WTN; ++c)
      #pragma unroll
      for (int r = 0; r < 4; ++r)
        acc[4 + r][c] = __builtin_amdgcn_mfma_f32_16x16x32_bf16(ag2[r], bw[c], acc[4 + r][c], 0, 0, 0);
    __builtin_amdgcn_s_setprio(0);
    __builtin_amdgcn_s_barrier();   // seals cur; frees it for staging t+2

    __bf16* x;
    x = curA; curA = nxtA; nxtA = x;
    x = curB; curB = nxtB; nxtB = x;
  }

  #pragma unroll
  for (int rf = 0; rf < 8; ++rf)
    #pragma unroll
    for (int cf = 0; cf < WTN; ++cf)
      #pragma unroll
      for (int r = 0; r < 4; ++r) {
        int m = m0 + wm + rf * 16 + quad * 4 + r;
        int n = n0 + wn + cf * 16 + l16;
        float v = acc[rf][cf][r];
        if (BIAS) v += bias[n];
        if (ACT == 1) v = 1.0f / (1.0f + __expf(-v));
        if (OUT_BF16)
          ((__bf16*)Cout)[(size_t)m * N + n] = (__bf16)v;
        else
          ((float*)Cout)[(size_t)m * N + n] = v;
      }
}

// ============================================================================
// gemm_bt: R1 measured-best simple structure. Used for GEMM2 (split-K, N=64)
// and GEMM3 (SUMA, K=64 one-shot).
// ============================================================================
template <int BM, int BN, int WAVES, int OUT_BF16, int ACT, int BIAS, int SUMA>
__global__ __launch_bounds__(WAVES * 64) void gemm_bt(
    const __bf16* __restrict__ A, const __bf16* __restrict__ Bt,
    const float* __restrict__ bias, void* __restrict__ Cout,
    int M, int N, int K, const __bf16* __restrict__ A2) {
  constexpr int BK = 64;               // 8 chunks of 16B per row
  constexpr int WAVES_N = WAVES / 2;
  constexpr int WTM = BM / 32;
  constexpr int WTN = BN / (WAVES_N * 16);
  constexpr int NBUF = SUMA ? 1 : 2;
  constexpr int A_ISSUES = BM / (8 * WAVES);
  constexpr int B_ISSUES = BN / (8 * WAVES);
  __shared__ __bf16 As[NBUF * BM * BK];
  __shared__ __bf16 Bs[NBUF * BN * BK];
  const int tid = threadIdx.x;
  const int wave = tid >> 6, lane = tid & 63;
  const int quad = lane >> 4, l16 = lane & 15;
  const int m0 = blockIdx.x * BM, n0 = blockIdx.y * BN;
  const int ks = K / gridDim.z;
  const int kbeg = blockIdx.z * ks;
  const int wm = (wave & 1) * (BM / 2);
  const int wn = (wave >> 1) * (BN / WAVES_N);
  const int lrow = lane >> 3;
  const int lchunk = lane & 7;
  f32x4 acc[WTM][WTN] = {};

  const __bf16* aSrc[A_ISSUES];
  const __bf16* bSrc[B_ISSUES];
  #pragma unroll
  for (int t = 0; t < A_ISSUES; ++t) {
    int row = (t * WAVES + wave) * 8 + lrow;
    aSrc[t] = A + (size_t)(m0 + row) * K + kbeg + (lchunk ^ (row & 7)) * 8;
  }
  #pragma unroll
  for (int t = 0; t < B_ISSUES; ++t) {
    int row = (t * WAVES + wave) * 8 + lrow;
    bSrc[t] = Bt + (size_t)(n0 + row) * K + kbeg + (lchunk ^ (row & 7)) * 8;
  }
  int aOff[WTM][2], bOff[WTN][2];
  #pragma unroll
  for (int i = 0; i < WTM; ++i) {
    int row = wm + i * 16 + l16;
    #pragma unroll
    for (int kk = 0; kk < 2; ++kk)
      aOff[i][kk] = row * BK + (((kk * 4 + quad) ^ (row & 7)) * 8);
  }
  #pragma unroll
  for (int j = 0; j < WTN; ++j) {
    int row = wn + j * 16 + l16;
    #pragma unroll
    for (int kk = 0; kk < 2; ++kk)
      bOff[j][kk] = row * BK + (((kk * 4 + quad) ^ (row & 7)) * 8);
  }

  auto stage = [&](__bf16* Ad, __bf16* Bd) {
    #pragma unroll
    for (int t = 0; t < A_ISSUES; ++t) {
      async16(aSrc[t], Ad + (t * WAVES + wave) * 8 * BK);
      aSrc[t] += BK;
    }
    #pragma unroll
    for (int t = 0; t < B_ISSUES; ++t) {
      async16(bSrc[t], Bd + (t * WAVES + wave) * 8 * BK);
      bSrc[t] += BK;
    }
  };
  auto compute = [&](const __bf16* Ab, const __bf16* Bb) {
    #pragma unroll
    for (int kk = 0; kk < 2; ++kk) {
      bf16x8 af[WTM], bfr[WTN];
      #pragma unroll
      for (int i = 0; i < WTM; ++i) af[i] = *(const bf16x8*)(Ab + aOff[i][kk]);
      #pragma unroll
      for (int j = 0; j < WTN; ++j) bfr[j] = *(const bf16x8*)(Bb + bOff[j][kk]);
      #pragma unroll
      for (int i = 0; i < WTM; ++i)
        #pragma unroll
        for (int j = 0; j < WTN; ++j)
          acc[i][j] = __builtin_amdgcn_mfma_f32_16x16x32_bf16(af[i], bfr[j], acc[i][j], 0, 0, 0);
    }
  };

  const int niter = ks / BK;
  if constexpr (SUMA) {
    for (int it = 0; it < niter; ++it) {
      __syncthreads();
      #pragma unroll
      for (int t = 0; t < A_ISSUES; ++t) {
        int row = (t * WAVES + wave) * 8 + lrow;
        size_t go = (size_t)(m0 + row) * K + kbeg + it * BK + lchunk * 8;
        bf16x8 a0 = *(const bf16x8*)(A + go);
        bf16x8 a1 = *(const bf16x8*)(A2 + go);
        bf16x8 s;
        #pragma unroll
        for (int q = 0; q < 8; ++q) s[q] = (__bf16)((float)a0[q] + (float)a1[q]);
        *(bf16x8*)(As + row * BK + ((lchunk ^ (row & 7)) * 8)) = s;
      }
      #pragma unroll
      for (int t = 0; t < B_ISSUES; ++t) {
        async16(bSrc[t], Bs + (t * WAVES + wave) * 8 * BK);
        bSrc[t] += BK;
      }
      __syncthreads();
      compute(As, Bs);
    }
  } else {
    __bf16* curA = As;  __bf16* nxtA = As + BM * BK;
    __bf16* curB = Bs;  __bf16* nxtB = Bs + BN * BK;
    stage(curA, curB);
    asm volatile("s_waitcnt vmcnt(0)" ::: "memory");
    __builtin_amdgcn_s_barrier();
    for (int it = 0; it < niter - 1; ++it) {
      stage(nxtA, nxtB);            // tile it+1 flies under compute(it)
      compute(curA, curB);
      asm volatile("s_waitcnt vmcnt(0)" ::: "memory");
      __builtin_amdgcn_s_barrier();
      { __bf16* t = curA; curA = nxtA; nxtA = t; }
      { __bf16* t = curB; curB = nxtB; nxtB = t; }
    }
    compute(curA, curB);
  }

  char* Cz = (char*)Cout + (size_t)blockIdx.z * M * N * (OUT_BF16 ? 2 : 4);
  #pragma unroll
  for (int i = 0; i < WTM; ++i)
    #pragma unroll
    for (int j = 0; j < WTN; ++j)
      #pragma unroll
      for (int r = 0; r < 4; ++r) {
        int m = m0 + wm + i * 16 + quad * 4 + r;
        int n = n0 + wn + j * 16 + l16;
        float v = acc[i][j][r];
        if (BIAS) v += bias[n];
        if (ACT == 1) v = 1.0f / (1.0f + __expf(-v));
        if (OUT_BF16)
          ((__bf16*)Cz)[(size_t)m * N + n] = (__bf16)v;
        else
          ((float*)Cz)[(size_t)m * N + n] = v;
      }
}

// Router: split-K reduce + 2-layer router + top-2 -> packed e01 + g01.
// Block 0 also zeroes the per-expert counters for the fill kernel.
__global__ __launch_bounds__(256) void router_kernel(
    const float* __restrict__ contP, const float* __restrict__ s2c_b,
    const float* __restrict__ rW1, const float* __restrict__ rb1,
    const float* __restrict__ rW2, const float* __restrict__ rb2,
    __bf16* __restrict__ contB, int* __restrict__ e01,
    float2* __restrict__ g01, int* __restrict__ cnt) {
  if (blockIdx.x == 0 && threadIdx.x < NEXP) cnt[threadIdx.x] = 0;
  const int wave = threadIdx.x >> 6, lane = threadIdx.x & 63;
  const int n = blockIdx.x * 4 + wave;
  const size_t base = (size_t)n * 64 + lane;
  const size_t slab = (size_t)TOK * 64;
  float c = contP[base] + contP[base + slab] + contP[base + 2 * slab] +
            contP[base + 3 * slab] + s2c_b[lane];
  contB[base] = (__bf16)c;
  float acc = rb1[lane];
  #pragma unroll
  for (int i = 0; i < 64; ++i) {
    float ci = __shfl(c, i);
    acc = fmaf(ci, rW1[i * 64 + lane], acc);
  }
  float t = tanhf(acc);
  float logit[8];
  #pragma unroll
  for (int e = 0; e < 8; ++e) {
    float v = t * rW2[lane * 8 + e];
    #pragma unroll
    for (int o = 32; o; o >>= 1) v += __shfl_xor(v, o);
    logit[e] = v + rb2[e];
  }
  float mx = logit[0];
  #pragma unroll
  for (int e = 1; e < 8; ++e) mx = fmaxf(mx, logit[e]);
  float p[8];
  #pragma unroll
  for (int e = 0; e < 8; ++e) p[e] = __expf(logit[e] - mx);
  float v0 = p[0]; int e0 = 0;
  #pragma unroll
  for (int e = 1; e < 8; ++e) if (p[e] > v0) { v0 = p[e]; e0 = e; }
  float v1 = -1.0f; int e1 = 0;
  #pragma unroll
  for (int e = 0; e < 8; ++e) if (e != e0 && p[e] > v1) { v1 = p[e]; e1 = e; }
  float inv = 1.0f / (v0 + v1);
  if (lane == 0) {
    e01[n] = e0 | (e1 << 8);
    g01[n] = make_float2(v0 * inv, v1 * inv);
  }
}

// Fill: build per-expert token lists (tok | rank<<31) with LDS-aggregated
// histogram; 8 global atomics per block (256 total -- no hot-address serial).
__global__ __launch_bounds__(256) void fill_kernel(
    const int* __restrict__ e01, int* __restrict__ cnt,
    unsigned* __restrict__ idxb) {
  __shared__ int lcnt[NEXP], lbase[NEXP];
  const int tid = threadIdx.x;
  if (tid < NEXP) lcnt[tid] = 0;
  __syncthreads();
  const int n = blockIdx.x * 256 + tid;
  const int pe = e01[n];
  const int e0 = pe & 0xff, e1 = (pe >> 8) & 0xff;
  const int p0 = atomicAdd(&lcnt[e0], 1);
  const int p1 = atomicAdd(&lcnt[e1], 1);
  __syncthreads();
  if (tid < NEXP) lbase[tid] = atomicAdd(&cnt[tid], lcnt[tid]);
  __syncthreads();
  idxb[e0 * TOK + lbase[e0] + p0] = (unsigned)n;
  idxb[e1 * TOK + lbase[e1] + p1] = (unsigned)n | 0x80000000u;
}

// Sparse MoE: block = (chunk of 64 tokens of expert e's list). Gathers contB
// rows by token index (L2-resident), computes the expert MLP, scatters gated
// bf16 rows to slab0 (rank 0) / slab1 (rank 1). Per-token math identical to
// the dense version (row-independent MFMAs) -> bit-exact outputs.
__global__ __launch_bounds__(256) void moe_sparse_kernel(
    const __bf16* __restrict__ contB, const __bf16* __restrict__ We1T,
    const __bf16* __restrict__ We2T, const float* __restrict__ be1,
    const float* __restrict__ be2, const unsigned* __restrict__ idxb,
    const int* __restrict__ cnt, const float2* __restrict__ g01,
    __bf16* __restrict__ slab0, __bf16* __restrict__ slab1) {
  constexpr int TT = 64;
  const int e = blockIdx.y;
  const int start = blockIdx.x * TT;
  const int ne = cnt[e];
  if (start >= ne) return;
  const int nval = min(TT, ne - start);
  __shared__ __bf16 cont_s[TT * 64];
  __shared__ __bf16 w1_s[64 * 64];
  __shared__ __bf16 w2_s[64 * 64];
  __shared__ __bf16 h_s[TT * 64];
  __shared__ unsigned tok_s[TT];
  __shared__ float gate_s[TT];
  const int tid = threadIdx.x;
  const int wave = tid >> 6, lane = tid & 63;
  const int quad = lane >> 4, l16 = lane & 15;
  if (tid < TT) {
    unsigned v = idxb[e * TOK + start + ((tid < nval) ? tid : 0)];
    unsigned tok = v & 0x7fffffffu;
    float2 g = g01[tok];
    tok_s[tid] = v;
    gate_s[tid] = (v >> 31) ? g.y : g.x;
  }
  __syncthreads();
  // gather cont rows into swizzled LDS (rows are 128B contiguous in contB)
  for (int i = tid; i < TT * 8; i += 256) {
    int r = i >> 3, cc = i & 7;
    unsigned tok = tok_s[r] & 0x7fffffffu;
    *(uint4*)(cont_s + r * 64 + ((cc ^ (r & 7)) * 8)) =
        *(const uint4*)(contB + (size_t)tok * 64 + cc * 8);
  }
  const int wtok = wave * 16;
  f32x4 acc2[4] = {};
  for (int hc = 0; hc < HHALF; hc += 64) {
    __syncthreads();
    for (int c = tid; c < 512; c += 256) {
      int r = c >> 3, cc = c & 7;
      *(uint4*)(w1_s + r * 64 + ((cc ^ (r & 7)) * 8)) =
          *(const uint4*)(We1T + ((size_t)e * HHALF + hc + r) * 64 + cc * 8);
      *(uint4*)(w2_s + r * 64 + ((cc ^ (r & 7)) * 8)) =
          *(const uint4*)(We2T + ((size_t)e * 64 + r) * HHALF + hc + cc * 8);
    }
    __syncthreads();
    f32x4 acc1[4] = {};
    #pragma unroll
    for (int kk = 0; kk < 2; ++kk) {
      bf16x8 af, bfr[4];
      {
        int row = wtok + l16;
        af = *(const bf16x8*)(cont_s + row * 64 + (((kk * 4 + quad) ^ (row & 7)) * 8));
      }
      #pragma unroll
      for (int j = 0; j < 4; ++j) {
        int row = j * 16 + l16;
        bfr[j] = *(const bf16x8*)(w1_s + row * 64 + (((kk * 4 + quad) ^ (row & 7)) * 8));
      }
      #pragma unroll
      for (int j = 0; j < 4; ++j)
        acc1[j] = __builtin_amdgcn_mfma_f32_16x16x32_bf16(af, bfr[j], acc1[j], 0, 0, 0);
    }
    // h = relu(acc1 + be1) -> wave-private h_s rows (no barrier needed)
    #pragma unroll
    for (int j = 0; j < 4; ++j)
      #pragma unroll
      for (int r = 0; r < 4; ++r) {
        int tr = wtok + quad * 4 + r;
        int hcol = j * 16 + l16;
        float v = acc1[j][r] + be1[e * HHALF + hc + hcol];
        h_s[tr * 64 + (((hcol >> 3) ^ (tr & 7)) * 8) + (hcol & 7)] =
            (__bf16)fmaxf(v, 0.0f);
      }
    #pragma unroll
    for (int kk = 0; kk < 2; ++kk) {
      bf16x8 af, bfr[4];
      {
        int row = wtok + l16;
        af = *(const bf16x8*)(h_s + row * 64 + (((kk * 4 + quad) ^ (row & 7)) * 8));
      }
      #pragma unroll
      for (int j = 0; j < 4; ++j) {
        int row = j * 16 + l16;
        bfr[j] = *(const bf16x8*)(w2_s + row * 64 + (((kk * 4 + quad) ^ (row & 7)) * 8));
      }
      #pragma unroll
      for (int j = 0; j < 4; ++j)
        acc2[j] = __builtin_amdgcn_mfma_f32_16x16x32_bf16(af, bfr[j], acc2[j], 0, 0, 0);
    }
  }
  #pragma unroll
  for (int j = 0; j < 4; ++j)
    #pragma unroll
    for (int r = 0; r < 4; ++r) {
      int tr = wtok + quad * 4 + r;
      if (tr < nval) {
        unsigned v = tok_s[tr];
        unsigned tok = v & 0x7fffffffu;
        int m = j * 16 + l16;
        float o = gate_s[tr] * (acc2[j][r] + be2[e * 64 + m]);
        __bf16* slab = (v >> 31) ? slab1 : slab0;
        slab[(size_t)tok * 64 + m] = (__bf16)o;
      }
    }
}

__global__ __launch_bounds__(256) void ln_kernel(
    const float* __restrict__ x, const float* __restrict__ g,
    const float* __restrict__ b, float* __restrict__ out) {
  const int row = blockIdx.x;
  const float4 v = ((const float4*)(x + (size_t)row * 1024))[threadIdx.x];
  float s1 = v.x + v.y + v.z + v.w;
  float s2 = v.x * v.x + v.y * v.y + v.z * v.z + v.w * v.w;
  #pragma unroll
  for (int o = 32; o; o >>= 1) { s1 += __shfl_xor(s1, o); s2 += __shfl_xor(s2, o); }
  __shared__ float ws1[4], ws2[4];
  const int wave = threadIdx.x >> 6, lane = threadIdx.x & 63;
  if (lane == 0) { ws1[wave] = s1; ws2[wave] = s2; }
  __syncthreads();
  s1 = ws1[0] + ws1[1] + ws1[2] + ws1[3];
  s2 = ws2[0] + ws2[1] + ws2[2] + ws2[3];
  const float mu = s1 * (1.0f / 1024.0f);
  const float var = s2 * (1.0f / 1024.0f) - mu * mu;
  const float inv = rsqrtf(var + 1e-5f);
  const int col = threadIdx.x * 4;
  const float4 gv = *(const float4*)(g + col);
  const float4 bv = *(const float4*)(b + col);
  float4 o;
  o.x = (v.x - mu) * inv * gv.x + bv.x;
  o.y = (v.y - mu) * inv * gv.y + bv.y;
  o.z = (v.z - mu) * inv * gv.z + bv.z;
  o.w = (v.w - mu) * inv * gv.w + bv.w;
  *(float4*)(out + (size_t)row * 1024 + col) = o;
}

extern "C" void kernel_launch(void* const* d_in, const int* in_sizes, int n_in,
                              void* d_out, int out_size, void* d_ws, size_t ws_size,
                              hipStream_t stream) {
  const float* X     = (const float*)d_in[0];
  const float* enc_W = (const float*)d_in[1];
  const float* enc_b = (const float*)d_in[2];
  const float* s2c_W = (const float*)d_in[3];
  const float* s2c_b = (const float*)d_in[4];
  const float* rW1   = (const float*)d_in[5];
  const float* rb1   = (const float*)d_in[6];
  const float* rW2   = (const float*)d_in[7];
  const float* rb2   = (const float*)d_in[8];
  const float* We1   = (const float*)d_in[9];
  const float* be1   = (const float*)d_in[10];
  const float* We2   = (const float*)d_in[11];
  const float* be2   = (const float*)d_in[12];
  const float* c2s_W = (const float*)d_in[13];
  const float* c2s_b = (const float*)d_in[14];
  const float* dec_W = (const float*)d_in[15];
  const float* dec_b = (const float*)d_in[16];
  const float* ln_g  = (const float*)d_in[17];
  const float* ln_b  = (const float*)d_in[18];
  float* out = (float*)d_out;

  // ---- workspace layout with explicit aliasing (~78 MB total) ----
  char* ws = (char*)d_ws;
  size_t off = 0;
  auto take = [&](size_t bytes) -> char* {
    char* p = ws + off;
    off = (off + bytes + 255) & ~(size_t)255;
    return p;
  };
  const size_t SLAB = (size_t)TOK * HDIM * 2;       // 33,554,432
  char*   slabA     = take(SLAB);
  char*   slabB     = take(SLAB);
  __bf16* encWT     = (__bf16*)take((size_t)HDIM * DMODEL * 2);
  __bf16* s2cWT     = (__bf16*)take((size_t)MDIM * HDIM * 2);
  __bf16* c2sWT     = (__bf16*)take((size_t)HDIM * MDIM * 2);
  __bf16* decWT     = (__bf16*)take((size_t)DMODEL * HDIM * 2);
  __bf16* We1T      = (__bf16*)take((size_t)NEXP * HHALF * MDIM * 2);
  __bf16* We2T      = (__bf16*)take((size_t)NEXP * MDIM * HHALF * 2);
  __bf16* contB     = (__bf16*)take((size_t)TOK * MDIM * 2);
  int*    e01       = (int*)take((size_t)TOK * 4);
  float2* g01       = (float2*)take((size_t)TOK * 8);
  __bf16* oslab0    = (__bf16*)take((size_t)TOK * MDIM * 2);
  __bf16* oslab1    = (__bf16*)take((size_t)TOK * MDIM * 2);
  int*     cnt      = (int*)take((size_t)NEXP * 4);
  unsigned* idxb    = (unsigned*)take((size_t)NEXP * TOK * 4);
  if (off > ws_size) return;  // insufficient workspace -> clean correctness fail

  __bf16* Xb        = (__bf16*)slabA;                       // dead after GEMM1
  float*  contP     = (float*)(slabA + (size_t)TOK * DMODEL * 2);  // dead after router
  __bf16* spikesMoe = (__bf16*)slabA;                       // born at GEMM3
  __bf16* spikesEnc = (__bf16*)slabB;                       // dead after GEMM2
  float*  decoded   = (float*)slabB;                        // born at GEMM4

  // fused preamble: cvt(X) + 6 weight transposes in ONE launch
  preamble_kernel<<<PREAMBLE_BLOCKS, 256, 0, stream>>>(
      X, Xb, enc_W, encWT, s2c_W, s2cWT, c2s_W, c2sWT, dec_W, decWT,
      We1, We1T, We2, We2T);

  // GEMM1 (8-phase 256x256): spikesEnc = sigmoid(X @ enc_W + b)  K=1024
  gemm_8p<256, 1, 1, 1><<<dim3(TOK / 256, HDIM / 256), 512, 0, stream>>>(
      Xb, encWT, enc_b, spikesEnc, TOK, HDIM, DMODEL);
  // GEMM2 (split-K x4): contP[z] = spikesEnc @ s2c_W partials   8192x64, K=2048
  gemm_bt<128, 64, 4, 0, 0, 0, 0><<<dim3(TOK / 128, 1, 4), 256, 0, stream>>>(
      spikesEnc, s2cWT, nullptr, contP, TOK, MDIM, HDIM, nullptr);
  // router: reduce partials + bias, top-2 -> e01/g01 (+ zero cnt)
  router_kernel<<<TOK / 4, 256, 0, stream>>>(contP, s2c_b, rW1, rb1, rW2, rb2,
                                             contB, e01, g01, cnt);
  // fill: per-expert token lists (LDS-aggregated; 256 global atomics total)
  fill_kernel<<<TOK / 256, 256, 0, stream>>>(e01, cnt, idxb);
  // sparse MoE (top-2 only: 4.3 GFLOP vs 17.2 dense) -> rank-slabs
  moe_sparse_kernel<<<dim3(TOK / 64, NEXP), 256, 0, stream>>>(
      contB, We1T, We2T, be1, be2, idxb, cnt, g01, oslab0, oslab1);
  // GEMM3 (SUMA): spikesMoe = sigmoid((slab0+slab1) @ c2s_W + b)  8192x2048, K=64
  gemm_bt<128, 128, 4, 1, 1, 1, 1><<<dim3(TOK / 128, HDIM / 128, 1), 256, 0, stream>>>(
      oslab0, c2sWT, c2s_b, spikesMoe, TOK, HDIM, MDIM, oslab1);
  // GEMM4 (8-phase 256x128): decoded = sigmoid(spikesMoe @ dec_W + b)  K=2048
  gemm_8p<128, 0, 1, 1><<<dim3(TOK / 256, DMODEL / 128), 512, 0, stream>>>(
      spikesMoe, decWT, dec_b, decoded, TOK, DMODEL, HDIM);
  ln_kernel<<<TOK, 256, 0, stream>>>(decoded, ln_g, ln_b, out);
}

// Round 6
// 300.441 us; speedup vs baseline: 1.0745x; 1.0143x over previous
//
#include <hip/hip_runtime.h>
#include <hip/hip_bf16.h>
#include <cstdint>
#include <cstddef>

#define TOK    8192
#define DMODEL 1024
#define HDIM   2048
#define MDIM   64
#define NEXP   8
#define HHALF  1024

using f32x4  = __attribute__((ext_vector_type(4))) float;
using bf16x8 = __attribute__((ext_vector_type(8))) __bf16;
using bf16x4 = __attribute__((ext_vector_type(4))) __bf16;

// async global->LDS, 16B per lane. LDS dest is wave-uniform base + lane*16.
__device__ __forceinline__ void async16(const void* g, void* l) {
  __builtin_amdgcn_global_load_lds(
      (const __attribute__((address_space(1))) unsigned int*)g,
      (__attribute__((address_space(3))) unsigned int*)l, 16, 0, 0);
}

// One-launch preamble: cvt(X) + transpose-cvt of all 6 weight tensors.
__global__ __launch_bounds__(256) void preamble_kernel(
    const float* __restrict__ X, __bf16* __restrict__ Xb,
    const float* __restrict__ encW, __bf16* __restrict__ encWT,
    const float* __restrict__ s2cW, __bf16* __restrict__ s2cWT,
    const float* __restrict__ c2sW, __bf16* __restrict__ c2sWT,
    const float* __restrict__ decW, __bf16* __restrict__ decWT,
    const float* __restrict__ We1, __bf16* __restrict__ We1T,
    const float* __restrict__ We2, __bf16* __restrict__ We2T) {
  __shared__ float ts[32][33];
  const int tid = threadIdx.x;
  int b = blockIdx.x;
  if (b < 8192) {  // X: 8192x1024 fp32 -> bf16 (float4 per thread)
    int i = b * 256 + tid;
    float4 v = ((const float4*)X)[i];
    bf16x4 o = { (__bf16)v.x, (__bf16)v.y, (__bf16)v.z, (__bf16)v.w };
    ((bf16x4*)Xb)[i] = o;
    return;
  }
  b -= 8192;
  const float* in; __bf16* outp; int R, C, tx, ty;
  if (b < 2048)              { in = encW; outp = encWT; R = 1024; C = 2048; tx = b % 64; ty = b / 64; }
  else if ((b -= 2048) < 128){ in = s2cW; outp = s2cWT; R = 2048; C = 64;   tx = b % 2;  ty = b / 2;  }
  else if ((b -= 128) < 128) { in = c2sW; outp = c2sWT; R = 64;   C = 2048; tx = b % 64; ty = b / 64; }
  else if ((b -= 128) < 2048){ in = decW; outp = decWT; R = 2048; C = 1024; tx = b % 32; ty = b / 32; }
  else if ((b -= 2048) < 512){ int s = b / 64, t = b % 64;
                               in = We1 + (size_t)s * 65536; outp = We1T + (size_t)s * 65536;
                               R = 64; C = 1024; tx = t % 32; ty = t / 32; }
  else                       { b -= 512; int s = b / 64, t = b % 64;
                               in = We2 + (size_t)s * 65536; outp = We2T + (size_t)s * 65536;
                               R = 1024; C = 64; tx = t % 2; ty = t / 2; }
  const int c0 = tx * 32, r0 = ty * 32;
  const int x = tid & 31, y = tid >> 5;
  #pragma unroll
  for (int i = y; i < 32; i += 8) ts[i][x] = in[(size_t)(r0 + i) * C + c0 + x];
  __syncthreads();
  #pragma unroll
  for (int i = y; i < 32; i += 8)
    outp[(size_t)(c0 + i) * R + r0 + x] = (__bf16)ts[x][i];
}
#define PREAMBLE_BLOCKS (8192 + 2048 + 128 + 128 + 2048 + 512 + 512)

// ============================================================================
// gemm_8p: m201-style phase schedule. BM=256, BK=64, 8 waves, NBUF=2.
// Per-wave output 128 x (BN/4): BN=256 -> acc[8][4], BN=128 -> acc[8][2].
// R6 change: stage groups FRONT-LOADED so every group has >=2 phases of slack
// before its wait (R5 had A02 with 1 phase -> exposed HBM latency ~500cyc/tile):
//   P0: stage A02+B01(t+1) [4 loads]; wait vmcnt(4)  (waits A13(t), issued t-1.P2,
//       2 phases prior); barrier publishes A13(t) for P1's reads.
//   P1: stage B23(t+1) [BN=256 only].
//   P2: stage A13(t+1).
//   P3: wait vmcnt(2) (waits A02/B01/B23(t+1), issued >=2 phases prior; A13(t+1)
//       stays in flight); barrier publishes them for t+1.P0's reads.
// Each phase: { ds_read quadrant frags ; stage ; [wait] ; s_barrier ;
//   sched_barrier(0) ; setprio(1) ; MFMA quadrant ; setprio(0) ; s_barrier }.
// Overwrite safety: stages at t.P* write nxt = tile t-1's buffer, whose last
// readers completed before t-1.P3's trailing barrier (< any t.P0 stage issue).
// Last tile (pre=false): P0 waits vmcnt(0) (drains A13(t)); P3 vmcnt(0) no-op.
// Arithmetic order per acc element unchanged (K-tiles in order, kk0 then kk1).
// ============================================================================
template <int BN, int OUT_BF16, int ACT, int BIAS>
__global__ __launch_bounds__(512, 2) void gemm_8p(
    const __bf16* __restrict__ A, const __bf16* __restrict__ Bt,
    const float* __restrict__ bias, void* __restrict__ Cout,
    int M, int N, int K) {
  constexpr int BM = 256, BK = 64;
  constexpr int WTN = BN / 64;            // per-wave N frags (4 or 2)
  constexpr int A_LOADS = 4;              // BM / (8 waves * 8 rows)
  constexpr int B_LOADS = BN / 64;        // 4 or 2
  __shared__ __bf16 As[2 * BM * BK];
  __shared__ __bf16 Bs[2 * BN * BK];
  const int tid = threadIdx.x;
  const int wave = tid >> 6, lane = tid & 63;
  const int quad = lane >> 4, l16 = lane & 15;
  const int m0 = blockIdx.x * BM, n0 = blockIdx.y * BN;
  const int wm = (wave & 1) * 128;        // 2 waves in M
  const int wn = (wave >> 1) * (BN / 4);  // 4 waves in N
  const int lrow = lane >> 3, lchunk = lane & 7;
  f32x4 acc[8][WTN] = {};

  const __bf16* aSrc[A_LOADS];
  const __bf16* bSrc[B_LOADS];
  #pragma unroll
  for (int t = 0; t < A_LOADS; ++t) {
    int row = (t * 8 + wave) * 8 + lrow;
    aSrc[t] = A + (size_t)(m0 + row) * K + (lchunk ^ (row & 7)) * 8;
  }
  #pragma unroll
  for (int t = 0; t < B_LOADS; ++t) {
    int row = (t * 8 + wave) * 8 + lrow;
    bSrc[t] = Bt + (size_t)(n0 + row) * K + (lchunk ^ (row & 7)) * 8;
  }
  int aOff[8], bOff[WTN];
  #pragma unroll
  for (int rf = 0; rf < 8; ++rf) {
    int row = wm + rf * 16 + l16;
    aOff[rf] = row * BK + ((quad ^ (row & 7)) * 8);
  }
  #pragma unroll
  for (int cf = 0; cf < WTN; ++cf) {
    int row = wn + cf * 16 + l16;
    bOff[cf] = row * BK + ((quad ^ (row & 7)) * 8);
  }

  auto stageA = [&](int t, __bf16* Ad) {
    async16(aSrc[t], Ad + (t * 8 + wave) * 8 * BK);
    aSrc[t] += BK;
  };
  auto stageB = [&](int t, __bf16* Bd) {
    async16(bSrc[t], Bd + (t * 8 + wave) * 8 * BK);
    bSrc[t] += BK;
  };

  __bf16 *curA = As, *nxtA = As + BM * BK;
  __bf16 *curB = Bs, *nxtB = Bs + BN * BK;
  const int nt = K / BK;

  // prologue: stage tile0, drain, publish
  stageA(0, curA); stageA(2, curA);
  stageB(0, curB); stageB(1, curB);
  if constexpr (BN == 256) { stageB(2, curB); stageB(3, curB); }
  stageA(1, curA); stageA(3, curA);
  asm volatile("s_waitcnt vmcnt(0)" ::: "memory");
  __builtin_amdgcn_s_barrier();

  for (int t = 0; t < nt; ++t) {
    const bool pre = (t + 1 < nt);
    // ---- P0: Q0 = rf0-3 x kk0 ----
    bf16x8 af[4], bv[WTN];
    #pragma unroll
    for (int r = 0; r < 4; ++r) af[r] = *(const bf16x8*)(curA + aOff[r]);
    #pragma unroll
    for (int c = 0; c < WTN; ++c) bv[c] = *(const bf16x8*)(curB + bOff[c]);
    if (pre) {
      stageA(0, nxtA); stageA(2, nxtA);
      stageB(0, nxtB); stageB(1, nxtB);
      asm volatile("s_waitcnt vmcnt(4)" ::: "memory");  // A13(t) landed (2-phase slack)
    } else {
      asm volatile("s_waitcnt vmcnt(0)" ::: "memory");
    }
    __builtin_amdgcn_s_barrier();   // publishes A13(t) for P1 reads
    __builtin_amdgcn_sched_barrier(0);
    __builtin_amdgcn_s_setprio(1);
    #pragma unroll
    for (int c = 0; c < WTN; ++c)
      #pragma unroll
      for (int r = 0; r < 4; ++r)
        acc[r][c] = __builtin_amdgcn_mfma_f32_16x16x32_bf16(af[r], bv[c], acc[r][c], 0, 0, 0);
    __builtin_amdgcn_s_setprio(0);
    __builtin_amdgcn_s_barrier();
    // ---- P1: Q1 = rf4-7 x kk0 ----
    bf16x8 ag[4];
    #pragma unroll
    for (int r = 0; r < 4; ++r) ag[r] = *(const bf16x8*)(curA + aOff[4 + r]);
    if (pre) {
      if constexpr (BN == 256) { stageB(2, nxtB); stageB(3, nxtB); }
    }
    __builtin_amdgcn_s_barrier();
    __builtin_amdgcn_sched_barrier(0);
    __builtin_amdgcn_s_setprio(1);
    #pragma unroll
    for (int c = 0; c < WTN; ++c)
      #pragma unroll
      for (int r = 0; r < 4; ++r)
        acc[4 + r][c] = __builtin_amdgcn_mfma_f32_16x16x32_bf16(ag[r], bv[c], acc[4 + r][c], 0, 0, 0);
    __builtin_amdgcn_s_setprio(0);
    __builtin_amdgcn_s_barrier();
    // ---- P2: Q2 = rf0-3 x kk1 ----
    bf16x8 af2[4], bw[WTN];
    #pragma unroll
    for (int r = 0; r < 4; ++r) af2[r] = *(const bf16x8*)(curA + (aOff[r] ^ 32));
    #pragma unroll
    for (int c = 0; c < WTN; ++c) bw[c] = *(const bf16x8*)(curB + (bOff[c] ^ 32));
    if (pre) { stageA(1, nxtA); stageA(3, nxtA); }
    __builtin_amdgcn_s_barrier();
    __builtin_amdgcn_sched_barrier(0);
    __builtin_amdgcn_s_setprio(1);
    #pragma unroll
    for (int c = 0; c < WTN; ++c)
      #pragma unroll
      for (int r = 0; r < 4; ++r)
        acc[r][c] = __builtin_amdgcn_mfma_f32_16x16x32_bf16(af2[r], bw[c], acc[r][c], 0, 0, 0);
    __builtin_amdgcn_s_setprio(0);
    __builtin_amdgcn_s_barrier();
    // ---- P3: Q3 = rf4-7 x kk1 ----
    bf16x8 ag2[4];
    #pragma unroll
    for (int r = 0; r < 4; ++r) ag2[r] = *(const bf16x8*)(curA + (aOff[4 + r] ^ 32));
    if (pre) {
      asm volatile("s_waitcnt vmcnt(2)" ::: "memory");  // A02/B01/B23(t+1) landed
    } else {
      asm volatile("s_waitcnt vmcnt(0)" ::: "memory");
    }
    __builtin_amdgcn_s_barrier();   // publishes them for t+1.P0 reads
    __builtin_amdgcn_sched_barrier(0);
    __builtin_amdgcn_s_setprio(1);
    #pragma unroll
    for (int c = 0; c < WTN; ++c)
      #pragma unroll
      for (int r = 0; r < 4; ++r)
        acc[4 + r][c] = __builtin_amdgcn_mfma_f32_16x16x32_bf16(ag2[r], bw[c], acc[4 + r][c], 0, 0, 0);
    __builtin_amdgcn_s_setprio(0);
    __builtin_amdgcn_s_barrier();   // seals cur; frees it for staging t+2

    __bf16* x;
    x = curA; curA = nxtA; nxtA = x;
    x = curB; curB = nxtB; nxtB = x;
  }

  #pragma unroll
  for (int rf = 0; rf < 8; ++rf)
    #pragma unroll
    for (int cf = 0; cf < WTN; ++cf)
      #pragma unroll
      for (int r = 0; r < 4; ++r) {
        int m = m0 + wm + rf * 16 + quad * 4 + r;
        int n = n0 + wn + cf * 16 + l16;
        float v = acc[rf][cf][r];
        if (BIAS) v += bias[n];
        if (ACT == 1) v = 1.0f / (1.0f + __expf(-v));
        if (OUT_BF16)
          ((__bf16*)Cout)[(size_t)m * N + n] = (__bf16)v;
        else
          ((float*)Cout)[(size_t)m * N + n] = v;
      }
}

// ============================================================================
// gemm_bt: R1 measured-best simple structure. Used for GEMM2 (split-K, N=64)
// and GEMM3 (SUMA, K=64 one-shot).
// ============================================================================
template <int BM, int BN, int WAVES, int OUT_BF16, int ACT, int BIAS, int SUMA>
__global__ __launch_bounds__(WAVES * 64) void gemm_bt(
    const __bf16* __restrict__ A, const __bf16* __restrict__ Bt,
    const float* __restrict__ bias, void* __restrict__ Cout,
    int M, int N, int K, const __bf16* __restrict__ A2) {
  constexpr int BK = 64;               // 8 chunks of 16B per row
  constexpr int WAVES_N = WAVES / 2;
  constexpr int WTM = BM / 32;
  constexpr int WTN = BN / (WAVES_N * 16);
  constexpr int NBUF = SUMA ? 1 : 2;
  constexpr int A_ISSUES = BM / (8 * WAVES);
  constexpr int B_ISSUES = BN / (8 * WAVES);
  __shared__ __bf16 As[NBUF * BM * BK];
  __shared__ __bf16 Bs[NBUF * BN * BK];
  const int tid = threadIdx.x;
  const int wave = tid >> 6, lane = tid & 63;
  const int quad = lane >> 4, l16 = lane & 15;
  const int m0 = blockIdx.x * BM, n0 = blockIdx.y * BN;
  const int ks = K / gridDim.z;
  const int kbeg = blockIdx.z * ks;
  const int wm = (wave & 1) * (BM / 2);
  const int wn = (wave >> 1) * (BN / WAVES_N);
  const int lrow = lane >> 3;
  const int lchunk = lane & 7;
  f32x4 acc[WTM][WTN] = {};

  const __bf16* aSrc[A_ISSUES];
  const __bf16* bSrc[B_ISSUES];
  #pragma unroll
  for (int t = 0; t < A_ISSUES; ++t) {
    int row = (t * WAVES + wave) * 8 + lrow;
    aSrc[t] = A + (size_t)(m0 + row) * K + kbeg + (lchunk ^ (row & 7)) * 8;
  }
  #pragma unroll
  for (int t = 0; t < B_ISSUES; ++t) {
    int row = (t * WAVES + wave) * 8 + lrow;
    bSrc[t] = Bt + (size_t)(n0 + row) * K + kbeg + (lchunk ^ (row & 7)) * 8;
  }
  int aOff[WTM][2], bOff[WTN][2];
  #pragma unroll
  for (int i = 0; i < WTM; ++i) {
    int row = wm + i * 16 + l16;
    #pragma unroll
    for (int kk = 0; kk < 2; ++kk)
      aOff[i][kk] = row * BK + (((kk * 4 + quad) ^ (row & 7)) * 8);
  }
  #pragma unroll
  for (int j = 0; j < WTN; ++j) {
    int row = wn + j * 16 + l16;
    #pragma unroll
    for (int kk = 0; kk < 2; ++kk)
      bOff[j][kk] = row * BK + (((kk * 4 + quad) ^ (row & 7)) * 8);
  }

  auto stage = [&](__bf16* Ad, __bf16* Bd) {
    #pragma unroll
    for (int t = 0; t < A_ISSUES; ++t) {
      async16(aSrc[t], Ad + (t * WAVES + wave) * 8 * BK);
      aSrc[t] += BK;
    }
    #pragma unroll
    for (int t = 0; t < B_ISSUES; ++t) {
      async16(bSrc[t], Bd + (t * WAVES + wave) * 8 * BK);
      bSrc[t] += BK;
    }
  };
  auto compute = [&](const __bf16* Ab, const __bf16* Bb) {
    #pragma unroll
    for (int kk = 0; kk < 2; ++kk) {
      bf16x8 af[WTM], bfr[WTN];
      #pragma unroll
      for (int i = 0; i < WTM; ++i) af[i] = *(const bf16x8*)(Ab + aOff[i][kk]);
      #pragma unroll
      for (int j = 0; j < WTN; ++j) bfr[j] = *(const bf16x8*)(Bb + bOff[j][kk]);
      #pragma unroll
      for (int i = 0; i < WTM; ++i)
        #pragma unroll
        for (int j = 0; j < WTN; ++j)
          acc[i][j] = __builtin_amdgcn_mfma_f32_16x16x32_bf16(af[i], bfr[j], acc[i][j], 0, 0, 0);
    }
  };

  const int niter = ks / BK;
  if constexpr (SUMA) {
    for (int it = 0; it < niter; ++it) {
      __syncthreads();
      #pragma unroll
      for (int t = 0; t < A_ISSUES; ++t) {
        int row = (t * WAVES + wave) * 8 + lrow;
        size_t go = (size_t)(m0 + row) * K + kbeg + it * BK + lchunk * 8;
        bf16x8 a0 = *(const bf16x8*)(A + go);
        bf16x8 a1 = *(const bf16x8*)(A2 + go);
        bf16x8 s;
        #pragma unroll
        for (int q = 0; q < 8; ++q) s[q] = (__bf16)((float)a0[q] + (float)a1[q]);
        *(bf16x8*)(As + row * BK + ((lchunk ^ (row & 7)) * 8)) = s;
      }
      #pragma unroll
      for (int t = 0; t < B_ISSUES; ++t) {
        async16(bSrc[t], Bs + (t * WAVES + wave) * 8 * BK);
        bSrc[t] += BK;
      }
      __syncthreads();
      compute(As, Bs);
    }
  } else {
    __bf16* curA = As;  __bf16* nxtA = As + BM * BK;
    __bf16* curB = Bs;  __bf16* nxtB = Bs + BN * BK;
    stage(curA, curB);
    asm volatile("s_waitcnt vmcnt(0)" ::: "memory");
    __builtin_amdgcn_s_barrier();
    for (int it = 0; it < niter - 1; ++it) {
      stage(nxtA, nxtB);            // tile it+1 flies under compute(it)
      compute(curA, curB);
      asm volatile("s_waitcnt vmcnt(0)" ::: "memory");
      __builtin_amdgcn_s_barrier();
      { __bf16* t = curA; curA = nxtA; nxtA = t; }
      { __bf16* t = curB; curB = nxtB; nxtB = t; }
    }
    compute(curA, curB);
  }

  char* Cz = (char*)Cout + (size_t)blockIdx.z * M * N * (OUT_BF16 ? 2 : 4);
  #pragma unroll
  for (int i = 0; i < WTM; ++i)
    #pragma unroll
    for (int j = 0; j < WTN; ++j)
      #pragma unroll
      for (int r = 0; r < 4; ++r) {
        int m = m0 + wm + i * 16 + quad * 4 + r;
        int n = n0 + wn + j * 16 + l16;
        float v = acc[i][j][r];
        if (BIAS) v += bias[n];
        if (ACT == 1) v = 1.0f / (1.0f + __expf(-v));
        if (OUT_BF16)
          ((__bf16*)Cz)[(size_t)m * N + n] = (__bf16)v;
        else
          ((float*)Cz)[(size_t)m * N + n] = v;
      }
}

// Router: split-K reduce + 2-layer router + top-2 -> packed e01 + g01.
// Block 0 also zeroes the per-expert counters for the fill kernel.
__global__ __launch_bounds__(256) void router_kernel(
    const float* __restrict__ contP, const float* __restrict__ s2c_b,
    const float* __restrict__ rW1, const float* __restrict__ rb1,
    const float* __restrict__ rW2, const float* __restrict__ rb2,
    __bf16* __restrict__ contB, int* __restrict__ e01,
    float2* __restrict__ g01, int* __restrict__ cnt) {
  if (blockIdx.x == 0 && threadIdx.x < NEXP) cnt[threadIdx.x] = 0;
  const int wave = threadIdx.x >> 6, lane = threadIdx.x & 63;
  const int n = blockIdx.x * 4 + wave;
  const size_t base = (size_t)n * 64 + lane;
  const size_t slab = (size_t)TOK * 64;
  float c = contP[base] + contP[base + slab] + contP[base + 2 * slab] +
            contP[base + 3 * slab] + s2c_b[lane];
  contB[base] = (__bf16)c;
  float acc = rb1[lane];
  #pragma unroll
  for (int i = 0; i < 64; ++i) {
    float ci = __shfl(c, i);
    acc = fmaf(ci, rW1[i * 64 + lane], acc);
  }
  float t = tanhf(acc);
  float logit[8];
  #pragma unroll
  for (int e = 0; e < 8; ++e) {
    float v = t * rW2[lane * 8 + e];
    #pragma unroll
    for (int o = 32; o; o >>= 1) v += __shfl_xor(v, o);
    logit[e] = v + rb2[e];
  }
  float mx = logit[0];
  #pragma unroll
  for (int e = 1; e < 8; ++e) mx = fmaxf(mx, logit[e]);
  float p[8];
  #pragma unroll
  for (int e = 0; e < 8; ++e) p[e] = __expf(logit[e] - mx);
  float v0 = p[0]; int e0 = 0;
  #pragma unroll
  for (int e = 1; e < 8; ++e) if (p[e] > v0) { v0 = p[e]; e0 = e; }
  float v1 = -1.0f; int e1 = 0;
  #pragma unroll
  for (int e = 0; e < 8; ++e) if (e != e0 && p[e] > v1) { v1 = p[e]; e1 = e; }
  float inv = 1.0f / (v0 + v1);
  if (lane == 0) {
    e01[n] = e0 | (e1 << 8);
    g01[n] = make_float2(v0 * inv, v1 * inv);
  }
}

// Fill: build per-expert token lists (tok | rank<<31) with LDS-aggregated
// histogram; 8 global atomics per block (256 total -- no hot-address serial).
__global__ __launch_bounds__(256) void fill_kernel(
    const int* __restrict__ e01, int* __restrict__ cnt,
    unsigned* __restrict__ idxb) {
  __shared__ int lcnt[NEXP], lbase[NEXP];
  const int tid = threadIdx.x;
  if (tid < NEXP) lcnt[tid] = 0;
  __syncthreads();
  const int n = blockIdx.x * 256 + tid;
  const int pe = e01[n];
  const int e0 = pe & 0xff, e1 = (pe >> 8) & 0xff;
  const int p0 = atomicAdd(&lcnt[e0], 1);
  const int p1 = atomicAdd(&lcnt[e1], 1);
  __syncthreads();
  if (tid < NEXP) lbase[tid] = atomicAdd(&cnt[tid], lcnt[tid]);
  __syncthreads();
  idxb[e0 * TOK + lbase[e0] + p0] = (unsigned)n;
  idxb[e1 * TOK + lbase[e1] + p1] = (unsigned)n | 0x80000000u;
}

// Sparse MoE: block = (chunk of 64 tokens of expert e's list). Gathers contB
// rows by index, expert MLP, scatters gated bf16 rows to rank slabs.
// R6: weight staging via async16 double-buffer (pre-swizzled SOURCE chunk,
// linear LDS dest -- m173 pattern); next hc chunk flies under current compute;
// one vmcnt(0)+barrier per iteration (was: serial store-stage between 2 syncs).
__global__ __launch_bounds__(256) void moe_sparse_kernel(
    const __bf16* __restrict__ contB, const __bf16* __restrict__ We1T,
    const __bf16* __restrict__ We2T, const float* __restrict__ be1,
    const float* __restrict__ be2, const unsigned* __restrict__ idxb,
    const int* __restrict__ cnt, const float2* __restrict__ g01,
    __bf16* __restrict__ slab0, __bf16* __restrict__ slab1) {
  constexpr int TT = 64;
  const int e = blockIdx.y;
  const int start = blockIdx.x * TT;
  const int ne = cnt[e];
  if (start >= ne) return;
  const int nval = min(TT, ne - start);
  __shared__ __bf16 cont_s[TT * 64];
  __shared__ __bf16 w1_s[2][64 * 64];
  __shared__ __bf16 w2_s[2][64 * 64];
  __shared__ __bf16 h_s[TT * 64];
  __shared__ unsigned tok_s[TT];
  __shared__ float gate_s[TT];
  const int tid = threadIdx.x;
  const int wave = tid >> 6, lane = tid & 63;
  const int quad = lane >> 4, l16 = lane & 15;
  if (tid < TT) {
    unsigned v = idxb[e * TOK + start + ((tid < nval) ? tid : 0)];
    unsigned tok = v & 0x7fffffffu;
    float2 g = g01[tok];
    tok_s[tid] = v;
    gate_s[tid] = (v >> 31) ? g.y : g.x;
  }
  __syncthreads();
  // gather cont rows into swizzled LDS (rows are 128B contiguous in contB)
  for (int i = tid; i < TT * 8; i += 256) {
    int r = i >> 3, cc = i & 7;
    unsigned tok = tok_s[r] & 0x7fffffffu;
    *(uint4*)(cont_s + r * 64 + ((cc ^ (r & 7)) * 8)) =
        *(const uint4*)(contB + (size_t)tok * 64 + cc * 8);
  }
  // async weight staging: chunk c = b*256 + wave*64 + lane; slot (r,s) linear
  // in LDS; SOURCE chunk = s^(r&7) so readers' XOR-swizzled reads see chunk cc
  // at slot cc^(r&7). Dest base is wave-uniform; lane*16 auto-offset.
  auto stageW = [&](int hc, int buf) {
    #pragma unroll
    for (int b = 0; b < 2; ++b) {
      int c = b * 256 + wave * 64 + lane;
      int r = c >> 3, s = c & 7;
      async16(We1T + ((size_t)e * HHALF + hc + r) * 64 + ((s ^ (r & 7)) * 8),
              w1_s[buf] + (b * 256 + wave * 64) * 8);
      async16(We2T + ((size_t)e * 64 + r) * HHALF + hc + ((s ^ (r & 7)) * 8),
              w2_s[buf] + (b * 256 + wave * 64) * 8);
    }
  };
  stageW(0, 0);
  asm volatile("s_waitcnt vmcnt(0)" ::: "memory");
  __syncthreads();   // publishes cont_s stores + w chunk0

  const int wtok = wave * 16;
  f32x4 acc2[4] = {};
  int cur = 0;
  for (int i = 0; i < HHALF / 64; ++i) {
    const int hc = i * 64;
    if (i + 1 < HHALF / 64) stageW(hc + 64, cur ^ 1);  // next chunk flies
    const __bf16* w1c = w1_s[cur];
    const __bf16* w2c = w2_s[cur];
    f32x4 acc1[4] = {};
    #pragma unroll
    for (int kk = 0; kk < 2; ++kk) {
      bf16x8 af, bfr[4];
      {
        int row = wtok + l16;
        af = *(const bf16x8*)(cont_s + row * 64 + (((kk * 4 + quad) ^ (row & 7)) * 8));
      }
      #pragma unroll
      for (int j = 0; j < 4; ++j) {
        int row = j * 16 + l16;
        bfr[j] = *(const bf16x8*)(w1c + row * 64 + (((kk * 4 + quad) ^ (row & 7)) * 8));
      }
      #pragma unroll
      for (int j = 0; j < 4; ++j)
        acc1[j] = __builtin_amdgcn_mfma_f32_16x16x32_bf16(af, bfr[j], acc1[j], 0, 0, 0);
    }
    // h = relu(acc1 + be1) -> wave-private h_s rows (no barrier needed)
    #pragma unroll
    for (int j = 0; j < 4; ++j)
      #pragma unroll
      for (int r = 0; r < 4; ++r) {
        int tr = wtok + quad * 4 + r;
        int hcol = j * 16 + l16;
        float v = acc1[j][r] + be1[e * HHALF + hc + hcol];
        h_s[tr * 64 + (((hcol >> 3) ^ (tr & 7)) * 8) + (hcol & 7)] =
            (__bf16)fmaxf(v, 0.0f);
      }
    #pragma unroll
    for (int kk = 0; kk < 2; ++kk) {
      bf16x8 af, bfr[4];
      {
        int row = wtok + l16;
        af = *(const bf16x8*)(h_s + row * 64 + (((kk * 4 + quad) ^ (row & 7)) * 8));
      }
      #pragma unroll
      for (int j = 0; j < 4; ++j) {
        int row = j * 16 + l16;
        bfr[j] = *(const bf16x8*)(w2c + row * 64 + (((kk * 4 + quad) ^ (row & 7)) * 8));
      }
      #pragma unroll
      for (int j = 0; j < 4; ++j)
        acc2[j] = __builtin_amdgcn_mfma_f32_16x16x32_bf16(af, bfr[j], acc2[j], 0, 0, 0);
    }
    if (i + 1 < HHALF / 64) {
      asm volatile("s_waitcnt vmcnt(0)" ::: "memory");  // next chunk landed
      __syncthreads();   // publish next; seal cur (overwritten at i+2)
      cur ^= 1;
    }
  }
  #pragma unroll
  for (int j = 0; j < 4; ++j)
    #pragma unroll
    for (int r = 0; r < 4; ++r) {
      int tr = wtok + quad * 4 + r;
      if (tr < nval) {
        unsigned v = tok_s[tr];
        unsigned tok = v & 0x7fffffffu;
        int m = j * 16 + l16;
        float o = gate_s[tr] * (acc2[j][r] + be2[e * 64 + m]);
        __bf16* slab = (v >> 31) ? slab1 : slab0;
        slab[(size_t)tok * 64 + m] = (__bf16)o;
      }
    }
}

__global__ __launch_bounds__(256) void ln_kernel(
    const float* __restrict__ x, const float* __restrict__ g,
    const float* __restrict__ b, float* __restrict__ out) {
  const int row = blockIdx.x;
  const float4 v = ((const float4*)(x + (size_t)row * 1024))[threadIdx.x];
  float s1 = v.x + v.y + v.z + v.w;
  float s2 = v.x * v.x + v.y * v.y + v.z * v.z + v.w * v.w;
  #pragma unroll
  for (int o = 32; o; o >>= 1) { s1 += __shfl_xor(s1, o); s2 += __shfl_xor(s2, o); }
  __shared__ float ws1[4], ws2[4];
  const int wave = threadIdx.x >> 6, lane = threadIdx.x & 63;
  if (lane == 0) { ws1[wave] = s1; ws2[wave] = s2; }
  __syncthreads();
  s1 = ws1[0] + ws1[1] + ws1[2] + ws1[3];
  s2 = ws2[0] + ws2[1] + ws2[2] + ws2[3];
  const float mu = s1 * (1.0f / 1024.0f);
  const float var = s2 * (1.0f / 1024.0f) - mu * mu;
  const float inv = rsqrtf(var + 1e-5f);
  const int col = threadIdx.x * 4;
  const float4 gv = *(const float4*)(g + col);
  const float4 bv = *(const float4*)(b + col);
  float4 o;
  o.x = (v.x - mu) * inv * gv.x + bv.x;
  o.y = (v.y - mu) * inv * gv.y + bv.y;
  o.z = (v.z - mu) * inv * gv.z + bv.z;
  o.w = (v.w - mu) * inv * gv.w + bv.w;
  *(float4*)(out + (size_t)row * 1024 + col) = o;
}

extern "C" void kernel_launch(void* const* d_in, const int* in_sizes, int n_in,
                              void* d_out, int out_size, void* d_ws, size_t ws_size,
                              hipStream_t stream) {
  const float* X     = (const float*)d_in[0];
  const float* enc_W = (const float*)d_in[1];
  const float* enc_b = (const float*)d_in[2];
  const float* s2c_W = (const float*)d_in[3];
  const float* s2c_b = (const float*)d_in[4];
  const float* rW1   = (const float*)d_in[5];
  const float* rb1   = (const float*)d_in[6];
  const float* rW2   = (const float*)d_in[7];
  const float* rb2   = (const float*)d_in[8];
  const float* We1   = (const float*)d_in[9];
  const float* be1   = (const float*)d_in[10];
  const float* We2   = (const float*)d_in[11];
  const float* be2   = (const float*)d_in[12];
  const float* c2s_W = (const float*)d_in[13];
  const float* c2s_b = (const float*)d_in[14];
  const float* dec_W = (const float*)d_in[15];
  const float* dec_b = (const float*)d_in[16];
  const float* ln_g  = (const float*)d_in[17];
  const float* ln_b  = (const float*)d_in[18];
  float* out = (float*)d_out;

  // ---- workspace layout with explicit aliasing (~78 MB total) ----
  char* ws = (char*)d_ws;
  size_t off = 0;
  auto take = [&](size_t bytes) -> char* {
    char* p = ws + off;
    off = (off + bytes + 255) & ~(size_t)255;
    return p;
  };
  const size_t SLAB = (size_t)TOK * HDIM * 2;       // 33,554,432
  char*   slabA     = take(SLAB);
  char*   slabB     = take(SLAB);
  __bf16* encWT     = (__bf16*)take((size_t)HDIM * DMODEL * 2);
  __bf16* s2cWT     = (__bf16*)take((size_t)MDIM * HDIM * 2);
  __bf16* c2sWT     = (__bf16*)take((size_t)HDIM * MDIM * 2);
  __bf16* decWT     = (__bf16*)take((size_t)DMODEL * HDIM * 2);
  __bf16* We1T      = (__bf16*)take((size_t)NEXP * HHALF * MDIM * 2);
  __bf16* We2T      = (__bf16*)take((size_t)NEXP * MDIM * HHALF * 2);
  __bf16* contB     = (__bf16*)take((size_t)TOK * MDIM * 2);
  int*    e01       = (int*)take((size_t)TOK * 4);
  float2* g01       = (float2*)take((size_t)TOK * 8);
  __bf16* oslab0    = (__bf16*)take((size_t)TOK * MDIM * 2);
  __bf16* oslab1    = (__bf16*)take((size_t)TOK * MDIM * 2);
  int*     cnt      = (int*)take((size_t)NEXP * 4);
  unsigned* idxb    = (unsigned*)take((size_t)NEXP * TOK * 4);
  if (off > ws_size) return;  // insufficient workspace -> clean correctness fail

  __bf16* Xb        = (__bf16*)slabA;                       // dead after GEMM1
  float*  contP     = (float*)(slabA + (size_t)TOK * DMODEL * 2);  // dead after router
  __bf16* spikesMoe = (__bf16*)slabA;                       // born at GEMM3
  __bf16* spikesEnc = (__bf16*)slabB;                       // dead after GEMM2
  float*  decoded   = (float*)slabB;                        // born at GEMM4

  // fused preamble: cvt(X) + 6 weight transposes in ONE launch
  preamble_kernel<<<PREAMBLE_BLOCKS, 256, 0, stream>>>(
      X, Xb, enc_W, encWT, s2c_W, s2cWT, c2s_W, c2sWT, dec_W, decWT,
      We1, We1T, We2, We2T);

  // GEMM1 (8-phase 256x256): spikesEnc = sigmoid(X @ enc_W + b)  K=1024
  gemm_8p<256, 1, 1, 1><<<dim3(TOK / 256, HDIM / 256), 512, 0, stream>>>(
      Xb, encWT, enc_b, spikesEnc, TOK, HDIM, DMODEL);
  // GEMM2 (split-K x4): contP[z] = spikesEnc @ s2c_W partials   8192x64, K=2048
  gemm_bt<128, 64, 4, 0, 0, 0, 0><<<dim3(TOK / 128, 1, 4), 256, 0, stream>>>(
      spikesEnc, s2cWT, nullptr, contP, TOK, MDIM, HDIM, nullptr);
  // router: reduce partials + bias, top-2 -> e01/g01 (+ zero cnt)
  router_kernel<<<TOK / 4, 256, 0, stream>>>(contP, s2c_b, rW1, rb1, rW2, rb2,
                                             contB, e01, g01, cnt);
  // fill: per-expert token lists (LDS-aggregated; 256 global atomics total)
  fill_kernel<<<TOK / 256, 256, 0, stream>>>(e01, cnt, idxb);
  // sparse MoE (top-2 only: 4.3 GFLOP vs 17.2 dense) -> rank-slabs
  moe_sparse_kernel<<<dim3(TOK / 64, NEXP), 256, 0, stream>>>(
      contB, We1T, We2T, be1, be2, idxb, cnt, g01, oslab0, oslab1);
  // GEMM3 (SUMA): spikesMoe = sigmoid((slab0+slab1) @ c2s_W + b)  8192x2048, K=64
  gemm_bt<128, 128, 4, 1, 1, 1, 1><<<dim3(TOK / 128, HDIM / 128, 1), 256, 0, stream>>>(
      oslab0, c2sWT, c2s_b, spikesMoe, TOK, HDIM, MDIM, oslab1);
  // GEMM4 (8-phase 256x128): decoded = sigmoid(spikesMoe @ dec_W + b)  K=2048
  gemm_8p<128, 0, 1, 1><<<dim3(TOK / 256, DMODEL / 128), 512, 0, stream>>>(
      spikesMoe, decWT, dec_b, decoded, TOK, DMODEL, HDIM);
  ln_kernel<<<TOK, 256, 0, stream>>>(decoded, ln_g, ln_b, out);
}

// Round 7
// 298.696 us; speedup vs baseline: 1.0808x; 1.0058x over previous
//
#include <hip/hip_runtime.h>
#include <hip/hip_bf16.h>
#include <cstdint>
#include <cstddef>

#define TOK    8192
#define DMODEL 1024
#define HDIM   2048
#define MDIM   64
#define NEXP   8
#define HHALF  1024

using f32x4  = __attribute__((ext_vector_type(4))) float;
using bf16x8 = __attribute__((ext_vector_type(8))) __bf16;
using bf16x4 = __attribute__((ext_vector_type(4))) __bf16;

// async global->LDS, 16B per lane. LDS dest is wave-uniform base + lane*16.
__device__ __forceinline__ void async16(const void* g, void* l) {
  __builtin_amdgcn_global_load_lds(
      (const __attribute__((address_space(1))) unsigned int*)g,
      (__attribute__((address_space(3))) unsigned int*)l, 16, 0, 0);
}

// One-launch preamble: cvt(X) + transpose-cvt of all 6 weight tensors.
__global__ __launch_bounds__(256) void preamble_kernel(
    const float* __restrict__ X, __bf16* __restrict__ Xb,
    const float* __restrict__ encW, __bf16* __restrict__ encWT,
    const float* __restrict__ s2cW, __bf16* __restrict__ s2cWT,
    const float* __restrict__ c2sW, __bf16* __restrict__ c2sWT,
    const float* __restrict__ decW, __bf16* __restrict__ decWT,
    const float* __restrict__ We1, __bf16* __restrict__ We1T,
    const float* __restrict__ We2, __bf16* __restrict__ We2T) {
  __shared__ float ts[32][33];
  const int tid = threadIdx.x;
  int b = blockIdx.x;
  if (b < 8192) {  // X: 8192x1024 fp32 -> bf16 (float4 per thread)
    int i = b * 256 + tid;
    float4 v = ((const float4*)X)[i];
    bf16x4 o = { (__bf16)v.x, (__bf16)v.y, (__bf16)v.z, (__bf16)v.w };
    ((bf16x4*)Xb)[i] = o;
    return;
  }
  b -= 8192;
  const float* in; __bf16* outp; int R, C, tx, ty;
  if (b < 2048)              { in = encW; outp = encWT; R = 1024; C = 2048; tx = b % 64; ty = b / 64; }
  else if ((b -= 2048) < 128){ in = s2cW; outp = s2cWT; R = 2048; C = 64;   tx = b % 2;  ty = b / 2;  }
  else if ((b -= 128) < 128) { in = c2sW; outp = c2sWT; R = 64;   C = 2048; tx = b % 64; ty = b / 64; }
  else if ((b -= 128) < 2048){ in = decW; outp = decWT; R = 2048; C = 1024; tx = b % 32; ty = b / 32; }
  else if ((b -= 2048) < 512){ int s = b / 64, t = b % 64;
                               in = We1 + (size_t)s * 65536; outp = We1T + (size_t)s * 65536;
                               R = 64; C = 1024; tx = t % 32; ty = t / 32; }
  else                       { b -= 512; int s = b / 64, t = b % 64;
                               in = We2 + (size_t)s * 65536; outp = We2T + (size_t)s * 65536;
                               R = 1024; C = 64; tx = t % 2; ty = t / 2; }
  const int c0 = tx * 32, r0 = ty * 32;
  const int x = tid & 31, y = tid >> 5;
  #pragma unroll
  for (int i = y; i < 32; i += 8) ts[i][x] = in[(size_t)(r0 + i) * C + c0 + x];
  __syncthreads();
  #pragma unroll
  for (int i = y; i < 32; i += 8)
    outp[(size_t)(c0 + i) * R + r0 + x] = (__bf16)ts[x][i];
}
#define PREAMBLE_BLOCKS (8192 + 2048 + 128 + 128 + 2048 + 512 + 512)

// ============================================================================
// gemm_8p: m201-style phase schedule. BM=256, BK=64, 8 waves, NBUF=2.
// Per-wave output 128 x (BN/4): BN=256 -> acc[8][4], BN=128 -> acc[8][2].
// R7: per-BN stage placement, each at its MEASURED-best order:
//  BN=256 (R5 order, even 2-per-phase spread; R6's front-load regressed 46->75):
//    P0: stage B01(t+1); vmcnt(2) [A13(t), staged t-1.P3]
//    P1: stage B23(t+1)
//    P2: stage A02(t+1)
//    P3: stage A13(t+1); vmcnt(2) [B01,B23,A02(t+1)]
//  BN=128 (R6 order):
//    P0: stage A02+B01(t+1); vmcnt(4) [A13(t), staged t-1.P2, 2-phase slack]
//    P2: stage A13(t+1)
//    P3: vmcnt(2) [A02,B01(t+1), 3-phase slack]
// Each phase: { ds_read quadrant frags ; stage ; [wait] ; s_barrier ;
//   sched_barrier(0) ; setprio(1) ; MFMA quadrant ; setprio(0) ; s_barrier }.
// Publication audit (BN=256): t.P0 reads af(A02(t)) + bv(all B chunks of t):
//   published at t-1.P3's vmcnt(2)+barrier (drains B01,B23,A02(t)); ag(A13(t))
//   read at P1: published at t.P0's vmcnt(2)+barrier. BN=128: t.P0 reads
//   af/bv published at t-1.P3's vmcnt(2)+barrier; ag published at t.P0.
// Overwrite audit: stages at t.P* write tile t-1's buffer; its last readers'
// lgkm waits precede their MFMA < t-1.P3 trailing barrier < any t.P0 stage.
// Last tile (pre=false): P0/P3 wait vmcnt(0).
// Arithmetic order per acc element unchanged (K-tiles in order, kk0 then kk1).
// ============================================================================
template <int BN, int OUT_BF16, int ACT, int BIAS>
__global__ __launch_bounds__(512, 2) void gemm_8p(
    const __bf16* __restrict__ A, const __bf16* __restrict__ Bt,
    const float* __restrict__ bias, void* __restrict__ Cout,
    int M, int N, int K) {
  constexpr int BM = 256, BK = 64;
  constexpr int WTN = BN / 64;            // per-wave N frags (4 or 2)
  constexpr int A_LOADS = 4;              // BM / (8 waves * 8 rows)
  constexpr int B_LOADS = BN / 64;        // 4 or 2
  __shared__ __bf16 As[2 * BM * BK];
  __shared__ __bf16 Bs[2 * BN * BK];
  const int tid = threadIdx.x;
  const int wave = tid >> 6, lane = tid & 63;
  const int quad = lane >> 4, l16 = lane & 15;
  const int m0 = blockIdx.x * BM, n0 = blockIdx.y * BN;
  const int wm = (wave & 1) * 128;        // 2 waves in M
  const int wn = (wave >> 1) * (BN / 4);  // 4 waves in N
  const int lrow = lane >> 3, lchunk = lane & 7;
  f32x4 acc[8][WTN] = {};

  const __bf16* aSrc[A_LOADS];
  const __bf16* bSrc[B_LOADS];
  #pragma unroll
  for (int t = 0; t < A_LOADS; ++t) {
    int row = (t * 8 + wave) * 8 + lrow;
    aSrc[t] = A + (size_t)(m0 + row) * K + (lchunk ^ (row & 7)) * 8;
  }
  #pragma unroll
  for (int t = 0; t < B_LOADS; ++t) {
    int row = (t * 8 + wave) * 8 + lrow;
    bSrc[t] = Bt + (size_t)(n0 + row) * K + (lchunk ^ (row & 7)) * 8;
  }
  int aOff[8], bOff[WTN];
  #pragma unroll
  for (int rf = 0; rf < 8; ++rf) {
    int row = wm + rf * 16 + l16;
    aOff[rf] = row * BK + ((quad ^ (row & 7)) * 8);
  }
  #pragma unroll
  for (int cf = 0; cf < WTN; ++cf) {
    int row = wn + cf * 16 + l16;
    bOff[cf] = row * BK + ((quad ^ (row & 7)) * 8);
  }

  auto stageA = [&](int t, __bf16* Ad) {
    async16(aSrc[t], Ad + (t * 8 + wave) * 8 * BK);
    aSrc[t] += BK;
  };
  auto stageB = [&](int t, __bf16* Bd) {
    async16(bSrc[t], Bd + (t * 8 + wave) * 8 * BK);
    bSrc[t] += BK;
  };

  __bf16 *curA = As, *nxtA = As + BM * BK;
  __bf16 *curB = Bs, *nxtB = Bs + BN * BK;
  const int nt = K / BK;

  // prologue: stage tile0, drain, publish
  stageB(0, curB); stageB(1, curB);
  if constexpr (BN == 256) { stageB(2, curB); stageB(3, curB); }
  stageA(0, curA); stageA(2, curA);
  stageA(1, curA); stageA(3, curA);
  asm volatile("s_waitcnt vmcnt(0)" ::: "memory");
  __builtin_amdgcn_s_barrier();

  for (int t = 0; t < nt; ++t) {
    const bool pre = (t + 1 < nt);
    // ---- P0: Q0 = rf0-3 x kk0 ----
    bf16x8 af[4], bv[WTN];
    #pragma unroll
    for (int r = 0; r < 4; ++r) af[r] = *(const bf16x8*)(curA + aOff[r]);
    #pragma unroll
    for (int c = 0; c < WTN; ++c) bv[c] = *(const bf16x8*)(curB + bOff[c]);
    if (pre) {
      if constexpr (BN == 256) {
        stageB(0, nxtB); stageB(1, nxtB);
        asm volatile("s_waitcnt vmcnt(2)" ::: "memory");  // A13(t) landed
      } else {
        stageA(0, nxtA); stageA(2, nxtA);
        stageB(0, nxtB); stageB(1, nxtB);
        asm volatile("s_waitcnt vmcnt(4)" ::: "memory");  // A13(t) landed
      }
    } else {
      asm volatile("s_waitcnt vmcnt(0)" ::: "memory");
    }
    __builtin_amdgcn_s_barrier();   // publishes A13(t) for P1 reads
    __builtin_amdgcn_sched_barrier(0);
    __builtin_amdgcn_s_setprio(1);
    #pragma unroll
    for (int c = 0; c < WTN; ++c)
      #pragma unroll
      for (int r = 0; r < 4; ++r)
        acc[r][c] = __builtin_amdgcn_mfma_f32_16x16x32_bf16(af[r], bv[c], acc[r][c], 0, 0, 0);
    __builtin_amdgcn_s_setprio(0);
    __builtin_amdgcn_s_barrier();
    // ---- P1: Q1 = rf4-7 x kk0 ----
    bf16x8 ag[4];
    #pragma unroll
    for (int r = 0; r < 4; ++r) ag[r] = *(const bf16x8*)(curA + aOff[4 + r]);
    if (pre) {
      if constexpr (BN == 256) { stageB(2, nxtB); stageB(3, nxtB); }
    }
    __builtin_amdgcn_s_barrier();
    __builtin_amdgcn_sched_barrier(0);
    __builtin_amdgcn_s_setprio(1);
    #pragma unroll
    for (int c = 0; c < WTN; ++c)
      #pragma unroll
      for (int r = 0; r < 4; ++r)
        acc[4 + r][c] = __builtin_amdgcn_mfma_f32_16x16x32_bf16(ag[r], bv[c], acc[4 + r][c], 0, 0, 0);
    __builtin_amdgcn_s_setprio(0);
    __builtin_amdgcn_s_barrier();
    // ---- P2: Q2 = rf0-3 x kk1 ----
    bf16x8 af2[4], bw[WTN];
    #pragma unroll
    for (int r = 0; r < 4; ++r) af2[r] = *(const bf16x8*)(curA + (aOff[r] ^ 32));
    #pragma unroll
    for (int c = 0; c < WTN; ++c) bw[c] = *(const bf16x8*)(curB + (bOff[c] ^ 32));
    if (pre) {
      if constexpr (BN == 256) { stageA(0, nxtA); stageA(2, nxtA); }
      else                     { stageA(1, nxtA); stageA(3, nxtA); }
    }
    __builtin_amdgcn_s_barrier();
    __builtin_amdgcn_sched_barrier(0);
    __builtin_amdgcn_s_setprio(1);
    #pragma unroll
    for (int c = 0; c < WTN; ++c)
      #pragma unroll
      for (int r = 0; r < 4; ++r)
        acc[r][c] = __builtin_amdgcn_mfma_f32_16x16x32_bf16(af2[r], bw[c], acc[r][c], 0, 0, 0);
    __builtin_amdgcn_s_setprio(0);
    __builtin_amdgcn_s_barrier();
    // ---- P3: Q3 = rf4-7 x kk1 ----
    bf16x8 ag2[4];
    #pragma unroll
    for (int r = 0; r < 4; ++r) ag2[r] = *(const bf16x8*)(curA + (aOff[4 + r] ^ 32));
    if (pre) {
      if constexpr (BN == 256) { stageA(1, nxtA); stageA(3, nxtA); }
      asm volatile("s_waitcnt vmcnt(2)" ::: "memory");  // next tile's early groups landed
    } else {
      asm volatile("s_waitcnt vmcnt(0)" ::: "memory");
    }
    __builtin_amdgcn_s_barrier();   // publishes them for t+1.P0 reads
    __builtin_amdgcn_sched_barrier(0);
    __builtin_amdgcn_s_setprio(1);
    #pragma unroll
    for (int c = 0; c < WTN; ++c)
      #pragma unroll
      for (int r = 0; r < 4; ++r)
        acc[4 + r][c] = __builtin_amdgcn_mfma_f32_16x16x32_bf16(ag2[r], bw[c], acc[4 + r][c], 0, 0, 0);
    __builtin_amdgcn_s_setprio(0);
    __builtin_amdgcn_s_barrier();   // seals cur; frees it for staging t+2

    __bf16* x;
    x = curA; curA = nxtA; nxtA = x;
    x = curB; curB = nxtB; nxtB = x;
  }

  #pragma unroll
  for (int rf = 0; rf < 8; ++rf)
    #pragma unroll
    for (int cf = 0; cf < WTN; ++cf)
      #pragma unroll
      for (int r = 0; r < 4; ++r) {
        int m = m0 + wm + rf * 16 + quad * 4 + r;
        int n = n0 + wn + cf * 16 + l16;
        float v = acc[rf][cf][r];
        if (BIAS) v += bias[n];
        if (ACT == 1) v = 1.0f / (1.0f + __expf(-v));
        if (OUT_BF16)
          ((__bf16*)Cout)[(size_t)m * N + n] = (__bf16)v;
        else
          ((float*)Cout)[(size_t)m * N + n] = v;
      }
}

// ============================================================================
// gemm_bt: R1 measured-best simple structure. Used for GEMM2 (split-K, N=64)
// and GEMM3 (SUMA, K=64 one-shot).
// ============================================================================
template <int BM, int BN, int WAVES, int OUT_BF16, int ACT, int BIAS, int SUMA>
__global__ __launch_bounds__(WAVES * 64) void gemm_bt(
    const __bf16* __restrict__ A, const __bf16* __restrict__ Bt,
    const float* __restrict__ bias, void* __restrict__ Cout,
    int M, int N, int K, const __bf16* __restrict__ A2) {
  constexpr int BK = 64;               // 8 chunks of 16B per row
  constexpr int WAVES_N = WAVES / 2;
  constexpr int WTM = BM / 32;
  constexpr int WTN = BN / (WAVES_N * 16);
  constexpr int NBUF = SUMA ? 1 : 2;
  constexpr int A_ISSUES = BM / (8 * WAVES);
  constexpr int B_ISSUES = BN / (8 * WAVES);
  __shared__ __bf16 As[NBUF * BM * BK];
  __shared__ __bf16 Bs[NBUF * BN * BK];
  const int tid = threadIdx.x;
  const int wave = tid >> 6, lane = tid & 63;
  const int quad = lane >> 4, l16 = lane & 15;
  const int m0 = blockIdx.x * BM, n0 = blockIdx.y * BN;
  const int ks = K / gridDim.z;
  const int kbeg = blockIdx.z * ks;
  const int wm = (wave & 1) * (BM / 2);
  const int wn = (wave >> 1) * (BN / WAVES_N);
  const int lrow = lane >> 3;
  const int lchunk = lane & 7;
  f32x4 acc[WTM][WTN] = {};

  const __bf16* aSrc[A_ISSUES];
  const __bf16* bSrc[B_ISSUES];
  #pragma unroll
  for (int t = 0; t < A_ISSUES; ++t) {
    int row = (t * WAVES + wave) * 8 + lrow;
    aSrc[t] = A + (size_t)(m0 + row) * K + kbeg + (lchunk ^ (row & 7)) * 8;
  }
  #pragma unroll
  for (int t = 0; t < B_ISSUES; ++t) {
    int row = (t * WAVES + wave) * 8 + lrow;
    bSrc[t] = Bt + (size_t)(n0 + row) * K + kbeg + (lchunk ^ (row & 7)) * 8;
  }
  int aOff[WTM][2], bOff[WTN][2];
  #pragma unroll
  for (int i = 0; i < WTM; ++i) {
    int row = wm + i * 16 + l16;
    #pragma unroll
    for (int kk = 0; kk < 2; ++kk)
      aOff[i][kk] = row * BK + (((kk * 4 + quad) ^ (row & 7)) * 8);
  }
  #pragma unroll
  for (int j = 0; j < WTN; ++j) {
    int row = wn + j * 16 + l16;
    #pragma unroll
    for (int kk = 0; kk < 2; ++kk)
      bOff[j][kk] = row * BK + (((kk * 4 + quad) ^ (row & 7)) * 8);
  }

  auto stage = [&](__bf16* Ad, __bf16* Bd) {
    #pragma unroll
    for (int t = 0; t < A_ISSUES; ++t) {
      async16(aSrc[t], Ad + (t * WAVES + wave) * 8 * BK);
      aSrc[t] += BK;
    }
    #pragma unroll
    for (int t = 0; t < B_ISSUES; ++t) {
      async16(bSrc[t], Bd + (t * WAVES + wave) * 8 * BK);
      bSrc[t] += BK;
    }
  };
  auto compute = [&](const __bf16* Ab, const __bf16* Bb) {
    #pragma unroll
    for (int kk = 0; kk < 2; ++kk) {
      bf16x8 af[WTM], bfr[WTN];
      #pragma unroll
      for (int i = 0; i < WTM; ++i) af[i] = *(const bf16x8*)(Ab + aOff[i][kk]);
      #pragma unroll
      for (int j = 0; j < WTN; ++j) bfr[j] = *(const bf16x8*)(Bb + bOff[j][kk]);
      #pragma unroll
      for (int i = 0; i < WTM; ++i)
        #pragma unroll
        for (int j = 0; j < WTN; ++j)
          acc[i][j] = __builtin_amdgcn_mfma_f32_16x16x32_bf16(af[i], bfr[j], acc[i][j], 0, 0, 0);
    }
  };

  const int niter = ks / BK;
  if constexpr (SUMA) {
    for (int it = 0; it < niter; ++it) {
      __syncthreads();
      #pragma unroll
      for (int t = 0; t < A_ISSUES; ++t) {
        int row = (t * WAVES + wave) * 8 + lrow;
        size_t go = (size_t)(m0 + row) * K + kbeg + it * BK + lchunk * 8;
        bf16x8 a0 = *(const bf16x8*)(A + go);
        bf16x8 a1 = *(const bf16x8*)(A2 + go);
        bf16x8 s;
        #pragma unroll
        for (int q = 0; q < 8; ++q) s[q] = (__bf16)((float)a0[q] + (float)a1[q]);
        *(bf16x8*)(As + row * BK + ((lchunk ^ (row & 7)) * 8)) = s;
      }
      #pragma unroll
      for (int t = 0; t < B_ISSUES; ++t) {
        async16(bSrc[t], Bs + (t * WAVES + wave) * 8 * BK);
        bSrc[t] += BK;
      }
      __syncthreads();
      compute(As, Bs);
    }
  } else {
    __bf16* curA = As;  __bf16* nxtA = As + BM * BK;
    __bf16* curB = Bs;  __bf16* nxtB = Bs + BN * BK;
    stage(curA, curB);
    asm volatile("s_waitcnt vmcnt(0)" ::: "memory");
    __builtin_amdgcn_s_barrier();
    for (int it = 0; it < niter - 1; ++it) {
      stage(nxtA, nxtB);            // tile it+1 flies under compute(it)
      compute(curA, curB);
      asm volatile("s_waitcnt vmcnt(0)" ::: "memory");
      __builtin_amdgcn_s_barrier();
      { __bf16* t = curA; curA = nxtA; nxtA = t; }
      { __bf16* t = curB; curB = nxtB; nxtB = t; }
    }
    compute(curA, curB);
  }

  char* Cz = (char*)Cout + (size_t)blockIdx.z * M * N * (OUT_BF16 ? 2 : 4);
  #pragma unroll
  for (int i = 0; i < WTM; ++i)
    #pragma unroll
    for (int j = 0; j < WTN; ++j)
      #pragma unroll
      for (int r = 0; r < 4; ++r) {
        int m = m0 + wm + i * 16 + quad * 4 + r;
        int n = n0 + wn + j * 16 + l16;
        float v = acc[i][j][r];
        if (BIAS) v += bias[n];
        if (ACT == 1) v = 1.0f / (1.0f + __expf(-v));
        if (OUT_BF16)
          ((__bf16*)Cz)[(size_t)m * N + n] = (__bf16)v;
        else
          ((float*)Cz)[(size_t)m * N + n] = v;
      }
}

// Router: split-K reduce + 2-layer router + top-2 -> packed e01 + g01.
// Block 0 also zeroes the per-expert counters for the fill kernel.
__global__ __launch_bounds__(256) void router_kernel(
    const float* __restrict__ contP, const float* __restrict__ s2c_b,
    const float* __restrict__ rW1, const float* __restrict__ rb1,
    const float* __restrict__ rW2, const float* __restrict__ rb2,
    __bf16* __restrict__ contB, int* __restrict__ e01,
    float2* __restrict__ g01, int* __restrict__ cnt) {
  if (blockIdx.x == 0 && threadIdx.x < NEXP) cnt[threadIdx.x] = 0;
  const int wave = threadIdx.x >> 6, lane = threadIdx.x & 63;
  const int n = blockIdx.x * 4 + wave;
  const size_t base = (size_t)n * 64 + lane;
  const size_t slab = (size_t)TOK * 64;
  float c = contP[base] + contP[base + slab] + contP[base + 2 * slab] +
            contP[base + 3 * slab] + s2c_b[lane];
  contB[base] = (__bf16)c;
  float acc = rb1[lane];
  #pragma unroll
  for (int i = 0; i < 64; ++i) {
    float ci = __shfl(c, i);
    acc = fmaf(ci, rW1[i * 64 + lane], acc);
  }
  float t = tanhf(acc);
  float logit[8];
  #pragma unroll
  for (int e = 0; e < 8; ++e) {
    float v = t * rW2[lane * 8 + e];
    #pragma unroll
    for (int o = 32; o; o >>= 1) v += __shfl_xor(v, o);
    logit[e] = v + rb2[e];
  }
  float mx = logit[0];
  #pragma unroll
  for (int e = 1; e < 8; ++e) mx = fmaxf(mx, logit[e]);
  float p[8];
  #pragma unroll
  for (int e = 0; e < 8; ++e) p[e] = __expf(logit[e] - mx);
  float v0 = p[0]; int e0 = 0;
  #pragma unroll
  for (int e = 1; e < 8; ++e) if (p[e] > v0) { v0 = p[e]; e0 = e; }
  float v1 = -1.0f; int e1 = 0;
  #pragma unroll
  for (int e = 0; e < 8; ++e) if (e != e0 && p[e] > v1) { v1 = p[e]; e1 = e; }
  float inv = 1.0f / (v0 + v1);
  if (lane == 0) {
    e01[n] = e0 | (e1 << 8);
    g01[n] = make_float2(v0 * inv, v1 * inv);
  }
}

// Fill: build per-expert token lists (tok | rank<<31) with LDS-aggregated
// histogram; 8 global atomics per block (256 total -- no hot-address serial).
__global__ __launch_bounds__(256) void fill_kernel(
    const int* __restrict__ e01, int* __restrict__ cnt,
    unsigned* __restrict__ idxb) {
  __shared__ int lcnt[NEXP], lbase[NEXP];
  const int tid = threadIdx.x;
  if (tid < NEXP) lcnt[tid] = 0;
  __syncthreads();
  const int n = blockIdx.x * 256 + tid;
  const int pe = e01[n];
  const int e0 = pe & 0xff, e1 = (pe >> 8) & 0xff;
  const int p0 = atomicAdd(&lcnt[e0], 1);
  const int p1 = atomicAdd(&lcnt[e1], 1);
  __syncthreads();
  if (tid < NEXP) lbase[tid] = atomicAdd(&cnt[tid], lcnt[tid]);
  __syncthreads();
  idxb[e0 * TOK + lbase[e0] + p0] = (unsigned)n;
  idxb[e1 * TOK + lbase[e1] + p1] = (unsigned)n | 0x80000000u;
}

// Sparse MoE: block = (chunk of 64 tokens of expert e's list). Gathers contB
// rows by index, expert MLP, scatters gated bf16 rows to rank slabs.
// Weight staging via async16 double-buffer (pre-swizzled SOURCE chunk,
// linear LDS dest); next hc chunk flies under current compute.
__global__ __launch_bounds__(256) void moe_sparse_kernel(
    const __bf16* __restrict__ contB, const __bf16* __restrict__ We1T,
    const __bf16* __restrict__ We2T, const float* __restrict__ be1,
    const float* __restrict__ be2, const unsigned* __restrict__ idxb,
    const int* __restrict__ cnt, const float2* __restrict__ g01,
    __bf16* __restrict__ slab0, __bf16* __restrict__ slab1) {
  constexpr int TT = 64;
  const int e = blockIdx.y;
  const int start = blockIdx.x * TT;
  const int ne = cnt[e];
  if (start >= ne) return;
  const int nval = min(TT, ne - start);
  __shared__ __bf16 cont_s[TT * 64];
  __shared__ __bf16 w1_s[2][64 * 64];
  __shared__ __bf16 w2_s[2][64 * 64];
  __shared__ __bf16 h_s[TT * 64];
  __shared__ unsigned tok_s[TT];
  __shared__ float gate_s[TT];
  const int tid = threadIdx.x;
  const int wave = tid >> 6, lane = tid & 63;
  const int quad = lane >> 4, l16 = lane & 15;
  if (tid < TT) {
    unsigned v = idxb[e * TOK + start + ((tid < nval) ? tid : 0)];
    unsigned tok = v & 0x7fffffffu;
    float2 g = g01[tok];
    tok_s[tid] = v;
    gate_s[tid] = (v >> 31) ? g.y : g.x;
  }
  __syncthreads();
  // gather cont rows into swizzled LDS (rows are 128B contiguous in contB)
  for (int i = tid; i < TT * 8; i += 256) {
    int r = i >> 3, cc = i & 7;
    unsigned tok = tok_s[r] & 0x7fffffffu;
    *(uint4*)(cont_s + r * 64 + ((cc ^ (r & 7)) * 8)) =
        *(const uint4*)(contB + (size_t)tok * 64 + cc * 8);
  }
  // async weight staging: chunk c = b*256 + wave*64 + lane; slot (r,s) linear
  // in LDS; SOURCE chunk = s^(r&7) so readers' XOR-swizzled reads see chunk cc
  // at slot cc^(r&7). Dest base is wave-uniform; lane*16 auto-offset.
  auto stageW = [&](int hc, int buf) {
    #pragma unroll
    for (int b = 0; b < 2; ++b) {
      int c = b * 256 + wave * 64 + lane;
      int r = c >> 3, s = c & 7;
      async16(We1T + ((size_t)e * HHALF + hc + r) * 64 + ((s ^ (r & 7)) * 8),
              w1_s[buf] + (b * 256 + wave * 64) * 8);
      async16(We2T + ((size_t)e * 64 + r) * HHALF + hc + ((s ^ (r & 7)) * 8),
              w2_s[buf] + (b * 256 + wave * 64) * 8);
    }
  };
  stageW(0, 0);
  asm volatile("s_waitcnt vmcnt(0)" ::: "memory");
  __syncthreads();   // publishes cont_s stores + w chunk0

  const int wtok = wave * 16;
  f32x4 acc2[4] = {};
  int cur = 0;
  for (int i = 0; i < HHALF / 64; ++i) {
    const int hc = i * 64;
    if (i + 1 < HHALF / 64) stageW(hc + 64, cur ^ 1);  // next chunk flies
    const __bf16* w1c = w1_s[cur];
    const __bf16* w2c = w2_s[cur];
    f32x4 acc1[4] = {};
    #pragma unroll
    for (int kk = 0; kk < 2; ++kk) {
      bf16x8 af, bfr[4];
      {
        int row = wtok + l16;
        af = *(const bf16x8*)(cont_s + row * 64 + (((kk * 4 + quad) ^ (row & 7)) * 8));
      }
      #pragma unroll
      for (int j = 0; j < 4; ++j) {
        int row = j * 16 + l16;
        bfr[j] = *(const bf16x8*)(w1c + row * 64 + (((kk * 4 + quad) ^ (row & 7)) * 8));
      }
      #pragma unroll
      for (int j = 0; j < 4; ++j)
        acc1[j] = __builtin_amdgcn_mfma_f32_16x16x32_bf16(af, bfr[j], acc1[j], 0, 0, 0);
    }
    // h = relu(acc1 + be1) -> wave-private h_s rows (no barrier needed)
    #pragma unroll
    for (int j = 0; j < 4; ++j)
      #pragma unroll
      for (int r = 0; r < 4; ++r) {
        int tr = wtok + quad * 4 + r;
        int hcol = j * 16 + l16;
        float v = acc1[j][r] + be1[e * HHALF + hc + hcol];
        h_s[tr * 64 + (((hcol >> 3) ^ (tr & 7)) * 8) + (hcol & 7)] =
            (__bf16)fmaxf(v, 0.0f);
      }
    #pragma unroll
    for (int kk = 0; kk < 2; ++kk) {
      bf16x8 af, bfr[4];
      {
        int row = wtok + l16;
        af = *(const bf16x8*)(h_s + row * 64 + (((kk * 4 + quad) ^ (row & 7)) * 8));
      }
      #pragma unroll
      for (int j = 0; j < 4; ++j) {
        int row = j * 16 + l16;
        bfr[j] = *(const bf16x8*)(w2c + row * 64 + (((kk * 4 + quad) ^ (row & 7)) * 8));
      }
      #pragma unroll
      for (int j = 0; j < 4; ++j)
        acc2[j] = __builtin_amdgcn_mfma_f32_16x16x32_bf16(af, bfr[j], acc2[j], 0, 0, 0);
    }
    if (i + 1 < HHALF / 64) {
      asm volatile("s_waitcnt vmcnt(0)" ::: "memory");  // next chunk landed
      __syncthreads();   // publish next; seal cur (overwritten at i+2)
      cur ^= 1;
    }
  }
  #pragma unroll
  for (int j = 0; j < 4; ++j)
    #pragma unroll
    for (int r = 0; r < 4; ++r) {
      int tr = wtok + quad * 4 + r;
      if (tr < nval) {
        unsigned v = tok_s[tr];
        unsigned tok = v & 0x7fffffffu;
        int m = j * 16 + l16;
        float o = gate_s[tr] * (acc2[j][r] + be2[e * 64 + m]);
        __bf16* slab = (v >> 31) ? slab1 : slab0;
        slab[(size_t)tok * 64 + m] = (__bf16)o;
      }
    }
}

__global__ __launch_bounds__(256) void ln_kernel(
    const float* __restrict__ x, const float* __restrict__ g,
    const float* __restrict__ b, float* __restrict__ out) {
  const int row = blockIdx.x;
  const float4 v = ((const float4*)(x + (size_t)row * 1024))[threadIdx.x];
  float s1 = v.x + v.y + v.z + v.w;
  float s2 = v.x * v.x + v.y * v.y + v.z * v.z + v.w * v.w;
  #pragma unroll
  for (int o = 32; o; o >>= 1) { s1 += __shfl_xor(s1, o); s2 += __shfl_xor(s2, o); }
  __shared__ float ws1[4], ws2[4];
  const int wave = threadIdx.x >> 6, lane = threadIdx.x & 63;
  if (lane == 0) { ws1[wave] = s1; ws2[wave] = s2; }
  __syncthreads();
  s1 = ws1[0] + ws1[1] + ws1[2] + ws1[3];
  s2 = ws2[0] + ws2[1] + ws2[2] + ws2[3];
  const float mu = s1 * (1.0f / 1024.0f);
  const float var = s2 * (1.0f / 1024.0f) - mu * mu;
  const float inv = rsqrtf(var + 1e-5f);
  const int col = threadIdx.x * 4;
  const float4 gv = *(const float4*)(g + col);
  const float4 bv = *(const float4*)(b + col);
  float4 o;
  o.x = (v.x - mu) * inv * gv.x + bv.x;
  o.y = (v.y - mu) * inv * gv.y + bv.y;
  o.z = (v.z - mu) * inv * gv.z + bv.z;
  o.w = (v.w - mu) * inv * gv.w + bv.w;
  *(float4*)(out + (size_t)row * 1024 + col) = o;
}

extern "C" void kernel_launch(void* const* d_in, const int* in_sizes, int n_in,
                              void* d_out, int out_size, void* d_ws, size_t ws_size,
                              hipStream_t stream) {
  const float* X     = (const float*)d_in[0];
  const float* enc_W = (const float*)d_in[1];
  const float* enc_b = (const float*)d_in[2];
  const float* s2c_W = (const float*)d_in[3];
  const float* s2c_b = (const float*)d_in[4];
  const float* rW1   = (const float*)d_in[5];
  const float* rb1   = (const float*)d_in[6];
  const float* rW2   = (const float*)d_in[7];
  const float* rb2   = (const float*)d_in[8];
  const float* We1   = (const float*)d_in[9];
  const float* be1   = (const float*)d_in[10];
  const float* We2   = (const float*)d_in[11];
  const float* be2   = (const float*)d_in[12];
  const float* c2s_W = (const float*)d_in[13];
  const float* c2s_b = (const float*)d_in[14];
  const float* dec_W = (const float*)d_in[15];
  const float* dec_b = (const float*)d_in[16];
  const float* ln_g  = (const float*)d_in[17];
  const float* ln_b  = (const float*)d_in[18];
  float* out = (float*)d_out;

  // ---- workspace layout with explicit aliasing (~78 MB total) ----
  char* ws = (char*)d_ws;
  size_t off = 0;
  auto take = [&](size_t bytes) -> char* {
    char* p = ws + off;
    off = (off + bytes + 255) & ~(size_t)255;
    return p;
  };
  const size_t SLAB = (size_t)TOK * HDIM * 2;       // 33,554,432
  char*   slabA     = take(SLAB);
  char*   slabB     = take(SLAB);
  __bf16* encWT     = (__bf16*)take((size_t)HDIM * DMODEL * 2);
  __bf16* s2cWT     = (__bf16*)take((size_t)MDIM * HDIM * 2);
  __bf16* c2sWT     = (__bf16*)take((size_t)HDIM * MDIM * 2);
  __bf16* decWT     = (__bf16*)take((size_t)DMODEL * HDIM * 2);
  __bf16* We1T      = (__bf16*)take((size_t)NEXP * HHALF * MDIM * 2);
  __bf16* We2T      = (__bf16*)take((size_t)NEXP * MDIM * HHALF * 2);
  __bf16* contB     = (__bf16*)take((size_t)TOK * MDIM * 2);
  int*    e01       = (int*)take((size_t)TOK * 4);
  float2* g01       = (float2*)take((size_t)TOK * 8);
  __bf16* oslab0    = (__bf16*)take((size_t)TOK * MDIM * 2);
  __bf16* oslab1    = (__bf16*)take((size_t)TOK * MDIM * 2);
  int*     cnt      = (int*)take((size_t)NEXP * 4);
  unsigned* idxb    = (unsigned*)take((size_t)NEXP * TOK * 4);
  if (off > ws_size) return;  // insufficient workspace -> clean correctness fail

  __bf16* Xb        = (__bf16*)slabA;                       // dead after GEMM1
  float*  contP     = (float*)(slabA + (size_t)TOK * DMODEL * 2);  // dead after router
  __bf16* spikesMoe = (__bf16*)slabA;                       // born at GEMM3
  __bf16* spikesEnc = (__bf16*)slabB;                       // dead after GEMM2
  float*  decoded   = (float*)slabB;                        // born at GEMM4

  // fused preamble: cvt(X) + 6 weight transposes in ONE launch
  preamble_kernel<<<PREAMBLE_BLOCKS, 256, 0, stream>>>(
      X, Xb, enc_W, encWT, s2c_W, s2cWT, c2s_W, c2sWT, dec_W, decWT,
      We1, We1T, We2, We2T);

  // GEMM1 (8-phase 256x256, R5 stage order): sigmoid(X @ enc_W + b)  K=1024
  gemm_8p<256, 1, 1, 1><<<dim3(TOK / 256, HDIM / 256), 512, 0, stream>>>(
      Xb, encWT, enc_b, spikesEnc, TOK, HDIM, DMODEL);
  // GEMM2 (split-K x4): contP[z] = spikesEnc @ s2c_W partials   8192x64, K=2048
  gemm_bt<128, 64, 4, 0, 0, 0, 0><<<dim3(TOK / 128, 1, 4), 256, 0, stream>>>(
      spikesEnc, s2cWT, nullptr, contP, TOK, MDIM, HDIM, nullptr);
  // router: reduce partials + bias, top-2 -> e01/g01 (+ zero cnt)
  router_kernel<<<TOK / 4, 256, 0, stream>>>(contP, s2c_b, rW1, rb1, rW2, rb2,
                                             contB, e01, g01, cnt);
  // fill: per-expert token lists (LDS-aggregated; 256 global atomics total)
  fill_kernel<<<TOK / 256, 256, 0, stream>>>(e01, cnt, idxb);
  // sparse MoE (top-2 only: 4.3 GFLOP vs 17.2 dense) -> rank-slabs
  moe_sparse_kernel<<<dim3(TOK / 64, NEXP), 256, 0, stream>>>(
      contB, We1T, We2T, be1, be2, idxb, cnt, g01, oslab0, oslab1);
  // GEMM3 (SUMA): spikesMoe = sigmoid((slab0+slab1) @ c2s_W + b)  8192x2048, K=64
  gemm_bt<128, 128, 4, 1, 1, 1, 1><<<dim3(TOK / 128, HDIM / 128, 1), 256, 0, stream>>>(
      oslab0, c2sWT, c2s_b, spikesMoe, TOK, HDIM, MDIM, oslab1);
  // GEMM4 (8-phase 256x128, R6 stage order): sigmoid(spikesMoe @ dec_W + b)  K=2048
  gemm_8p<128, 0, 1, 1><<<dim3(TOK / 256, DMODEL / 128), 512, 0, stream>>>(
      spikesMoe, decWT, dec_b, decoded, TOK, DMODEL, HDIM);
  ln_kernel<<<TOK, 256, 0, stream>>>(decoded, ln_g, ln_b, out);
}

// Round 8
// 293.523 us; speedup vs baseline: 1.0998x; 1.0176x over previous
//
#include <hip/hip_runtime.h>
#include <hip/hip_bf16.h>
#include <cstdint>
#include <cstddef>

#define TOK    8192
#define DMODEL 1024
#define HDIM   2048
#define MDIM   64
#define NEXP   8
#define HHALF  1024

using f32x4  = __attribute__((ext_vector_type(4))) float;
using bf16x8 = __attribute__((ext_vector_type(8))) __bf16;
using bf16x4 = __attribute__((ext_vector_type(4))) __bf16;

// async global->LDS, 16B per lane. LDS dest is wave-uniform base + lane*16.
__device__ __forceinline__ void async16(const void* g, void* l) {
  __builtin_amdgcn_global_load_lds(
      (const __attribute__((address_space(1))) unsigned int*)g,
      (__attribute__((address_space(3))) unsigned int*)l, 16, 0, 0);
}

// One-launch preamble: cvt(X) + transpose-cvt of all 6 weight tensors.
__global__ __launch_bounds__(256) void preamble_kernel(
    const float* __restrict__ X, __bf16* __restrict__ Xb,
    const float* __restrict__ encW, __bf16* __restrict__ encWT,
    const float* __restrict__ s2cW, __bf16* __restrict__ s2cWT,
    const float* __restrict__ c2sW, __bf16* __restrict__ c2sWT,
    const float* __restrict__ decW, __bf16* __restrict__ decWT,
    const float* __restrict__ We1, __bf16* __restrict__ We1T,
    const float* __restrict__ We2, __bf16* __restrict__ We2T) {
  __shared__ float ts[32][33];
  const int tid = threadIdx.x;
  int b = blockIdx.x;
  if (b < 8192) {  // X: 8192x1024 fp32 -> bf16 (float4 per thread)
    int i = b * 256 + tid;
    float4 v = ((const float4*)X)[i];
    bf16x4 o = { (__bf16)v.x, (__bf16)v.y, (__bf16)v.z, (__bf16)v.w };
    ((bf16x4*)Xb)[i] = o;
    return;
  }
  b -= 8192;
  const float* in; __bf16* outp; int R, C, tx, ty;
  if (b < 2048)              { in = encW; outp = encWT; R = 1024; C = 2048; tx = b % 64; ty = b / 64; }
  else if ((b -= 2048) < 128){ in = s2cW; outp = s2cWT; R = 2048; C = 64;   tx = b % 2;  ty = b / 2;  }
  else if ((b -= 128) < 128) { in = c2sW; outp = c2sWT; R = 64;   C = 2048; tx = b % 64; ty = b / 64; }
  else if ((b -= 128) < 2048){ in = decW; outp = decWT; R = 2048; C = 1024; tx = b % 32; ty = b / 32; }
  else if ((b -= 2048) < 512){ int s = b / 64, t = b % 64;
                               in = We1 + (size_t)s * 65536; outp = We1T + (size_t)s * 65536;
                               R = 64; C = 1024; tx = t % 32; ty = t / 32; }
  else                       { b -= 512; int s = b / 64, t = b % 64;
                               in = We2 + (size_t)s * 65536; outp = We2T + (size_t)s * 65536;
                               R = 1024; C = 64; tx = t % 2; ty = t / 2; }
  const int c0 = tx * 32, r0 = ty * 32;
  const int x = tid & 31, y = tid >> 5;
  #pragma unroll
  for (int i = y; i < 32; i += 8) ts[i][x] = in[(size_t)(r0 + i) * C + c0 + x];
  __syncthreads();
  #pragma unroll
  for (int i = y; i < 32; i += 8)
    outp[(size_t)(c0 + i) * R + r0 + x] = (__bf16)ts[x][i];
}
#define PREAMBLE_BLOCKS (8192 + 2048 + 128 + 128 + 2048 + 512 + 512)

// ============================================================================
// gemm_8p: m201-style phase schedule. BM=256, BK=64, 8 waves, NBUF=2.
// Per-wave output 128 x (BN/4): BN=256 -> acc[8][4], BN=128 -> acc[8][2].
// Stage placement per-BN at its MEASURED-best order (R7):
//  BN=256 (R5 order, even 2-per-phase spread):
//    P0: stage B01(t+1); vmcnt(2) [A13(t)]
//    P1: stage B23(t+1)
//    P2: stage A02(t+1)
//    P3: stage A13(t+1); vmcnt(2) [B01,B23,A02(t+1)]
//  BN=128 (R6 order):
//    P0: stage A02+B01(t+1); vmcnt(4) [A13(t)]
//    P2: stage A13(t+1)
//    P3: vmcnt(2) [A02,B01(t+1)]
// Each phase: { ds_read quadrant frags ; stage ; [wait] ; s_barrier ;
//   sched_barrier(0) ; setprio(1) ; MFMA quadrant ; setprio(0) ; s_barrier }.
// SWZ (GEMM1 only): bijective XCD-chunked remap for the 32x8 tile grid
// launched as flat 256 blocks. XCD k (ids == k mod 8) owns x in [4k,4k+4),
// all y -- each A-chunk's 8 y-sharers land on ONE XCD L2 (FETCH was 32.9MB
// vs 20MB ideal from 8x A replication). k=id&7, j=id>>3, bx=4k+(j>>3), by=j&7.
// Publication/overwrite audits unchanged from R7 (see per-line comments).
// Arithmetic order per acc element unchanged (K-tiles in order, kk0 then kk1).
// ============================================================================
template <int BN, int SWZ, int OUT_BF16, int ACT, int BIAS>
__global__ __launch_bounds__(512, 2) void gemm_8p(
    const __bf16* __restrict__ A, const __bf16* __restrict__ Bt,
    const float* __restrict__ bias, void* __restrict__ Cout,
    int M, int N, int K) {
  constexpr int BM = 256, BK = 64;
  constexpr int WTN = BN / 64;            // per-wave N frags (4 or 2)
  constexpr int A_LOADS = 4;              // BM / (8 waves * 8 rows)
  constexpr int B_LOADS = BN / 64;        // 4 or 2
  __shared__ __bf16 As[2 * BM * BK];
  __shared__ __bf16 Bs[2 * BN * BK];
  const int tid = threadIdx.x;
  const int wave = tid >> 6, lane = tid & 63;
  const int quad = lane >> 4, l16 = lane & 15;
  int bx, by;
  if constexpr (SWZ) {   // flat 256-block grid; 32x8 tiles; XCD-chunked
    const int id = blockIdx.x;
    const int k = id & 7, j = id >> 3;
    bx = 4 * k + (j >> 3);
    by = j & 7;
  } else {
    bx = blockIdx.x; by = blockIdx.y;
  }
  const int m0 = bx * BM, n0 = by * BN;
  const int wm = (wave & 1) * 128;        // 2 waves in M
  const int wn = (wave >> 1) * (BN / 4);  // 4 waves in N
  const int lrow = lane >> 3, lchunk = lane & 7;
  f32x4 acc[8][WTN] = {};

  const __bf16* aSrc[A_LOADS];
  const __bf16* bSrc[B_LOADS];
  #pragma unroll
  for (int t = 0; t < A_LOADS; ++t) {
    int row = (t * 8 + wave) * 8 + lrow;
    aSrc[t] = A + (size_t)(m0 + row) * K + (lchunk ^ (row & 7)) * 8;
  }
  #pragma unroll
  for (int t = 0; t < B_LOADS; ++t) {
    int row = (t * 8 + wave) * 8 + lrow;
    bSrc[t] = Bt + (size_t)(n0 + row) * K + (lchunk ^ (row & 7)) * 8;
  }
  int aOff[8], bOff[WTN];
  #pragma unroll
  for (int rf = 0; rf < 8; ++rf) {
    int row = wm + rf * 16 + l16;
    aOff[rf] = row * BK + ((quad ^ (row & 7)) * 8);
  }
  #pragma unroll
  for (int cf = 0; cf < WTN; ++cf) {
    int row = wn + cf * 16 + l16;
    bOff[cf] = row * BK + ((quad ^ (row & 7)) * 8);
  }

  auto stageA = [&](int t, __bf16* Ad) {
    async16(aSrc[t], Ad + (t * 8 + wave) * 8 * BK);
    aSrc[t] += BK;
  };
  auto stageB = [&](int t, __bf16* Bd) {
    async16(bSrc[t], Bd + (t * 8 + wave) * 8 * BK);
    bSrc[t] += BK;
  };

  __bf16 *curA = As, *nxtA = As + BM * BK;
  __bf16 *curB = Bs, *nxtB = Bs + BN * BK;
  const int nt = K / BK;

  // prologue: stage tile0, drain, publish
  stageB(0, curB); stageB(1, curB);
  if constexpr (BN == 256) { stageB(2, curB); stageB(3, curB); }
  stageA(0, curA); stageA(2, curA);
  stageA(1, curA); stageA(3, curA);
  asm volatile("s_waitcnt vmcnt(0)" ::: "memory");
  __builtin_amdgcn_s_barrier();

  for (int t = 0; t < nt; ++t) {
    const bool pre = (t + 1 < nt);
    // ---- P0: Q0 = rf0-3 x kk0 ----
    bf16x8 af[4], bv[WTN];
    #pragma unroll
    for (int r = 0; r < 4; ++r) af[r] = *(const bf16x8*)(curA + aOff[r]);
    #pragma unroll
    for (int c = 0; c < WTN; ++c) bv[c] = *(const bf16x8*)(curB + bOff[c]);
    if (pre) {
      if constexpr (BN == 256) {
        stageB(0, nxtB); stageB(1, nxtB);
        asm volatile("s_waitcnt vmcnt(2)" ::: "memory");  // A13(t) landed
      } else {
        stageA(0, nxtA); stageA(2, nxtA);
        stageB(0, nxtB); stageB(1, nxtB);
        asm volatile("s_waitcnt vmcnt(4)" ::: "memory");  // A13(t) landed
      }
    } else {
      asm volatile("s_waitcnt vmcnt(0)" ::: "memory");
    }
    __builtin_amdgcn_s_barrier();   // publishes A13(t) for P1 reads
    __builtin_amdgcn_sched_barrier(0);
    __builtin_amdgcn_s_setprio(1);
    #pragma unroll
    for (int c = 0; c < WTN; ++c)
      #pragma unroll
      for (int r = 0; r < 4; ++r)
        acc[r][c] = __builtin_amdgcn_mfma_f32_16x16x32_bf16(af[r], bv[c], acc[r][c], 0, 0, 0);
    __builtin_amdgcn_s_setprio(0);
    __builtin_amdgcn_s_barrier();
    // ---- P1: Q1 = rf4-7 x kk0 ----
    bf16x8 ag[4];
    #pragma unroll
    for (int r = 0; r < 4; ++r) ag[r] = *(const bf16x8*)(curA + aOff[4 + r]);
    if (pre) {
      if constexpr (BN == 256) { stageB(2, nxtB); stageB(3, nxtB); }
    }
    __builtin_amdgcn_s_barrier();
    __builtin_amdgcn_sched_barrier(0);
    __builtin_amdgcn_s_setprio(1);
    #pragma unroll
    for (int c = 0; c < WTN; ++c)
      #pragma unroll
      for (int r = 0; r < 4; ++r)
        acc[4 + r][c] = __builtin_amdgcn_mfma_f32_16x16x32_bf16(ag[r], bv[c], acc[4 + r][c], 0, 0, 0);
    __builtin_amdgcn_s_setprio(0);
    __builtin_amdgcn_s_barrier();
    // ---- P2: Q2 = rf0-3 x kk1 ----
    bf16x8 af2[4], bw[WTN];
    #pragma unroll
    for (int r = 0; r < 4; ++r) af2[r] = *(const bf16x8*)(curA + (aOff[r] ^ 32));
    #pragma unroll
    for (int c = 0; c < WTN; ++c) bw[c] = *(const bf16x8*)(curB + (bOff[c] ^ 32));
    if (pre) {
      if constexpr (BN == 256) { stageA(0, nxtA); stageA(2, nxtA); }
      else                     { stageA(1, nxtA); stageA(3, nxtA); }
    }
    __builtin_amdgcn_s_barrier();
    __builtin_amdgcn_sched_barrier(0);
    __builtin_amdgcn_s_setprio(1);
    #pragma unroll
    for (int c = 0; c < WTN; ++c)
      #pragma unroll
      for (int r = 0; r < 4; ++r)
        acc[r][c] = __builtin_amdgcn_mfma_f32_16x16x32_bf16(af2[r], bw[c], acc[r][c], 0, 0, 0);
    __builtin_amdgcn_s_setprio(0);
    __builtin_amdgcn_s_barrier();
    // ---- P3: Q3 = rf4-7 x kk1 ----
    bf16x8 ag2[4];
    #pragma unroll
    for (int r = 0; r < 4; ++r) ag2[r] = *(const bf16x8*)(curA + (aOff[4 + r] ^ 32));
    if (pre) {
      if constexpr (BN == 256) { stageA(1, nxtA); stageA(3, nxtA); }
      asm volatile("s_waitcnt vmcnt(2)" ::: "memory");  // next tile's early groups landed
    } else {
      asm volatile("s_waitcnt vmcnt(0)" ::: "memory");
    }
    __builtin_amdgcn_s_barrier();   // publishes them for t+1.P0 reads
    __builtin_amdgcn_sched_barrier(0);
    __builtin_amdgcn_s_setprio(1);
    #pragma unroll
    for (int c = 0; c < WTN; ++c)
      #pragma unroll
      for (int r = 0; r < 4; ++r)
        acc[4 + r][c] = __builtin_amdgcn_mfma_f32_16x16x32_bf16(ag2[r], bw[c], acc[4 + r][c], 0, 0, 0);
    __builtin_amdgcn_s_setprio(0);
    __builtin_amdgcn_s_barrier();   // seals cur; frees it for staging t+2

    __bf16* x;
    x = curA; curA = nxtA; nxtA = x;
    x = curB; curB = nxtB; nxtB = x;
  }

  #pragma unroll
  for (int rf = 0; rf < 8; ++rf)
    #pragma unroll
    for (int cf = 0; cf < WTN; ++cf)
      #pragma unroll
      for (int r = 0; r < 4; ++r) {
        int m = m0 + wm + rf * 16 + quad * 4 + r;
        int n = n0 + wn + cf * 16 + l16;
        float v = acc[rf][cf][r];
        if (BIAS) v += bias[n];
        if (ACT == 1) v = 1.0f / (1.0f + __expf(-v));
        if (OUT_BF16)
          ((__bf16*)Cout)[(size_t)m * N + n] = (__bf16)v;
        else
          ((float*)Cout)[(size_t)m * N + n] = v;
      }
}

// ============================================================================
// gemm_bt: R1 measured-best simple structure. Used for GEMM2 (split-K, N=64,
// R8: 8 waves -> 2/SIMD; was 4 waves = 1/SIMD with zero cross-wave overlap)
// and GEMM3 (SUMA, K=64 one-shot).
// ============================================================================
template <int BM, int BN, int WAVES, int OUT_BF16, int ACT, int BIAS, int SUMA>
__global__ __launch_bounds__(WAVES * 64) void gemm_bt(
    const __bf16* __restrict__ A, const __bf16* __restrict__ Bt,
    const float* __restrict__ bias, void* __restrict__ Cout,
    int M, int N, int K, const __bf16* __restrict__ A2) {
  constexpr int BK = 64;               // 8 chunks of 16B per row
  constexpr int WAVES_N = WAVES / 2;
  constexpr int WTM = BM / 32;
  constexpr int WTN = BN / (WAVES_N * 16);
  constexpr int NBUF = SUMA ? 1 : 2;
  constexpr int A_ISSUES = BM / (8 * WAVES);
  constexpr int B_ISSUES = BN / (8 * WAVES);
  __shared__ __bf16 As[NBUF * BM * BK];
  __shared__ __bf16 Bs[NBUF * BN * BK];
  const int tid = threadIdx.x;
  const int wave = tid >> 6, lane = tid & 63;
  const int quad = lane >> 4, l16 = lane & 15;
  const int m0 = blockIdx.x * BM, n0 = blockIdx.y * BN;
  const int ks = K / gridDim.z;
  const int kbeg = blockIdx.z * ks;
  const int wm = (wave & 1) * (BM / 2);
  const int wn = (wave >> 1) * (BN / WAVES_N);
  const int lrow = lane >> 3;
  const int lchunk = lane & 7;
  f32x4 acc[WTM][WTN] = {};

  const __bf16* aSrc[A_ISSUES];
  const __bf16* bSrc[B_ISSUES];
  #pragma unroll
  for (int t = 0; t < A_ISSUES; ++t) {
    int row = (t * WAVES + wave) * 8 + lrow;
    aSrc[t] = A + (size_t)(m0 + row) * K + kbeg + (lchunk ^ (row & 7)) * 8;
  }
  #pragma unroll
  for (int t = 0; t < B_ISSUES; ++t) {
    int row = (t * WAVES + wave) * 8 + lrow;
    bSrc[t] = Bt + (size_t)(n0 + row) * K + kbeg + (lchunk ^ (row & 7)) * 8;
  }
  int aOff[WTM][2], bOff[WTN][2];
  #pragma unroll
  for (int i = 0; i < WTM; ++i) {
    int row = wm + i * 16 + l16;
    #pragma unroll
    for (int kk = 0; kk < 2; ++kk)
      aOff[i][kk] = row * BK + (((kk * 4 + quad) ^ (row & 7)) * 8);
  }
  #pragma unroll
  for (int j = 0; j < WTN; ++j) {
    int row = wn + j * 16 + l16;
    #pragma unroll
    for (int kk = 0; kk < 2; ++kk)
      bOff[j][kk] = row * BK + (((kk * 4 + quad) ^ (row & 7)) * 8);
  }

  auto stage = [&](__bf16* Ad, __bf16* Bd) {
    #pragma unroll
    for (int t = 0; t < A_ISSUES; ++t) {
      async16(aSrc[t], Ad + (t * WAVES + wave) * 8 * BK);
      aSrc[t] += BK;
    }
    #pragma unroll
    for (int t = 0; t < B_ISSUES; ++t) {
      async16(bSrc[t], Bd + (t * WAVES + wave) * 8 * BK);
      bSrc[t] += BK;
    }
  };
  auto compute = [&](const __bf16* Ab, const __bf16* Bb) {
    #pragma unroll
    for (int kk = 0; kk < 2; ++kk) {
      bf16x8 af[WTM], bfr[WTN];
      #pragma unroll
      for (int i = 0; i < WTM; ++i) af[i] = *(const bf16x8*)(Ab + aOff[i][kk]);
      #pragma unroll
      for (int j = 0; j < WTN; ++j) bfr[j] = *(const bf16x8*)(Bb + bOff[j][kk]);
      #pragma unroll
      for (int i = 0; i < WTM; ++i)
        #pragma unroll
        for (int j = 0; j < WTN; ++j)
          acc[i][j] = __builtin_amdgcn_mfma_f32_16x16x32_bf16(af[i], bfr[j], acc[i][j], 0, 0, 0);
    }
  };

  const int niter = ks / BK;
  if constexpr (SUMA) {
    for (int it = 0; it < niter; ++it) {
      __syncthreads();
      #pragma unroll
      for (int t = 0; t < A_ISSUES; ++t) {
        int row = (t * WAVES + wave) * 8 + lrow;
        size_t go = (size_t)(m0 + row) * K + kbeg + it * BK + lchunk * 8;
        bf16x8 a0 = *(const bf16x8*)(A + go);
        bf16x8 a1 = *(const bf16x8*)(A2 + go);
        bf16x8 s;
        #pragma unroll
        for (int q = 0; q < 8; ++q) s[q] = (__bf16)((float)a0[q] + (float)a1[q]);
        *(bf16x8*)(As + row * BK + ((lchunk ^ (row & 7)) * 8)) = s;
      }
      #pragma unroll
      for (int t = 0; t < B_ISSUES; ++t) {
        async16(bSrc[t], Bs + (t * WAVES + wave) * 8 * BK);
        bSrc[t] += BK;
      }
      __syncthreads();
      compute(As, Bs);
    }
  } else {
    __bf16* curA = As;  __bf16* nxtA = As + BM * BK;
    __bf16* curB = Bs;  __bf16* nxtB = Bs + BN * BK;
    stage(curA, curB);
    asm volatile("s_waitcnt vmcnt(0)" ::: "memory");
    __builtin_amdgcn_s_barrier();
    for (int it = 0; it < niter - 1; ++it) {
      stage(nxtA, nxtB);            // tile it+1 flies under compute(it)
      compute(curA, curB);
      asm volatile("s_waitcnt vmcnt(0)" ::: "memory");
      __builtin_amdgcn_s_barrier();
      { __bf16* t = curA; curA = nxtA; nxtA = t; }
      { __bf16* t = curB; curB = nxtB; nxtB = t; }
    }
    compute(curA, curB);
  }

  char* Cz = (char*)Cout + (size_t)blockIdx.z * M * N * (OUT_BF16 ? 2 : 4);
  #pragma unroll
  for (int i = 0; i < WTM; ++i)
    #pragma unroll
    for (int j = 0; j < WTN; ++j)
      #pragma unroll
      for (int r = 0; r < 4; ++r) {
        int m = m0 + wm + i * 16 + quad * 4 + r;
        int n = n0 + wn + j * 16 + l16;
        float v = acc[i][j][r];
        if (BIAS) v += bias[n];
        if (ACT == 1) v = 1.0f / (1.0f + __expf(-v));
        if (OUT_BF16)
          ((__bf16*)Cz)[(size_t)m * N + n] = (__bf16)v;
        else
          ((float*)Cz)[(size_t)m * N + n] = v;
      }
}

// Router: split-K reduce + 2-layer router + top-2 -> packed e01 + g01.
// Block 0 also zeroes the per-expert counters for the fill kernel.
__global__ __launch_bounds__(256) void router_kernel(
    const float* __restrict__ contP, const float* __restrict__ s2c_b,
    const float* __restrict__ rW1, const float* __restrict__ rb1,
    const float* __restrict__ rW2, const float* __restrict__ rb2,
    __bf16* __restrict__ contB, int* __restrict__ e01,
    float2* __restrict__ g01, int* __restrict__ cnt) {
  if (blockIdx.x == 0 && threadIdx.x < NEXP) cnt[threadIdx.x] = 0;
  const int wave = threadIdx.x >> 6, lane = threadIdx.x & 63;
  const int n = blockIdx.x * 4 + wave;
  const size_t base = (size_t)n * 64 + lane;
  const size_t slab = (size_t)TOK * 64;
  float c = contP[base] + contP[base + slab] + contP[base + 2 * slab] +
            contP[base + 3 * slab] + s2c_b[lane];
  contB[base] = (__bf16)c;
  float acc = rb1[lane];
  #pragma unroll
  for (int i = 0; i < 64; ++i) {
    float ci = __shfl(c, i);
    acc = fmaf(ci, rW1[i * 64 + lane], acc);
  }
  float t = tanhf(acc);
  float logit[8];
  #pragma unroll
  for (int e = 0; e < 8; ++e) {
    float v = t * rW2[lane * 8 + e];
    #pragma unroll
    for (int o = 32; o; o >>= 1) v += __shfl_xor(v, o);
    logit[e] = v + rb2[e];
  }
  float mx = logit[0];
  #pragma unroll
  for (int e = 1; e < 8; ++e) mx = fmaxf(mx, logit[e]);
  float p[8];
  #pragma unroll
  for (int e = 0; e < 8; ++e) p[e] = __expf(logit[e] - mx);
  float v0 = p[0]; int e0 = 0;
  #pragma unroll
  for (int e = 1; e < 8; ++e) if (p[e] > v0) { v0 = p[e]; e0 = e; }
  float v1 = -1.0f; int e1 = 0;
  #pragma unroll
  for (int e = 0; e < 8; ++e) if (e != e0 && p[e] > v1) { v1 = p[e]; e1 = e; }
  float inv = 1.0f / (v0 + v1);
  if (lane == 0) {
    e01[n] = e0 | (e1 << 8);
    g01[n] = make_float2(v0 * inv, v1 * inv);
  }
}

// Fill: build per-expert token lists (tok | rank<<31) with LDS-aggregated
// histogram; 8 global atomics per block (256 total -- no hot-address serial).
__global__ __launch_bounds__(256) void fill_kernel(
    const int* __restrict__ e01, int* __restrict__ cnt,
    unsigned* __restrict__ idxb) {
  __shared__ int lcnt[NEXP], lbase[NEXP];
  const int tid = threadIdx.x;
  if (tid < NEXP) lcnt[tid] = 0;
  __syncthreads();
  const int n = blockIdx.x * 256 + tid;
  const int pe = e01[n];
  const int e0 = pe & 0xff, e1 = (pe >> 8) & 0xff;
  const int p0 = atomicAdd(&lcnt[e0], 1);
  const int p1 = atomicAdd(&lcnt[e1], 1);
  __syncthreads();
  if (tid < NEXP) lbase[tid] = atomicAdd(&cnt[tid], lcnt[tid]);
  __syncthreads();
  idxb[e0 * TOK + lbase[e0] + p0] = (unsigned)n;
  idxb[e1 * TOK + lbase[e1] + p1] = (unsigned)n | 0x80000000u;
}

// Sparse MoE: block = (chunk of 64 tokens of expert e's list). Gathers contB
// rows by index, expert MLP, scatters gated bf16 rows to rank slabs.
// Weight staging via async16 double-buffer (pre-swizzled SOURCE chunk,
// linear LDS dest); next hc chunk flies under current compute.
__global__ __launch_bounds__(256) void moe_sparse_kernel(
    const __bf16* __restrict__ contB, const __bf16* __restrict__ We1T,
    const __bf16* __restrict__ We2T, const float* __restrict__ be1,
    const float* __restrict__ be2, const unsigned* __restrict__ idxb,
    const int* __restrict__ cnt, const float2* __restrict__ g01,
    __bf16* __restrict__ slab0, __bf16* __restrict__ slab1) {
  constexpr int TT = 64;
  const int e = blockIdx.y;
  const int start = blockIdx.x * TT;
  const int ne = cnt[e];
  if (start >= ne) return;
  const int nval = min(TT, ne - start);
  __shared__ __bf16 cont_s[TT * 64];
  __shared__ __bf16 w1_s[2][64 * 64];
  __shared__ __bf16 w2_s[2][64 * 64];
  __shared__ __bf16 h_s[TT * 64];
  __shared__ unsigned tok_s[TT];
  __shared__ float gate_s[TT];
  const int tid = threadIdx.x;
  const int wave = tid >> 6, lane = tid & 63;
  const int quad = lane >> 4, l16 = lane & 15;
  if (tid < TT) {
    unsigned v = idxb[e * TOK + start + ((tid < nval) ? tid : 0)];
    unsigned tok = v & 0x7fffffffu;
    float2 g = g01[tok];
    tok_s[tid] = v;
    gate_s[tid] = (v >> 31) ? g.y : g.x;
  }
  __syncthreads();
  // gather cont rows into swizzled LDS (rows are 128B contiguous in contB)
  for (int i = tid; i < TT * 8; i += 256) {
    int r = i >> 3, cc = i & 7;
    unsigned tok = tok_s[r] & 0x7fffffffu;
    *(uint4*)(cont_s + r * 64 + ((cc ^ (r & 7)) * 8)) =
        *(const uint4*)(contB + (size_t)tok * 64 + cc * 8);
  }
  // async weight staging: chunk c = b*256 + wave*64 + lane; slot (r,s) linear
  // in LDS; SOURCE chunk = s^(r&7) so readers' XOR-swizzled reads see chunk cc
  // at slot cc^(r&7). Dest base is wave-uniform; lane*16 auto-offset.
  auto stageW = [&](int hc, int buf) {
    #pragma unroll
    for (int b = 0; b < 2; ++b) {
      int c = b * 256 + wave * 64 + lane;
      int r = c >> 3, s = c & 7;
      async16(We1T + ((size_t)e * HHALF + hc + r) * 64 + ((s ^ (r & 7)) * 8),
              w1_s[buf] + (b * 256 + wave * 64) * 8);
      async16(We2T + ((size_t)e * 64 + r) * HHALF + hc + ((s ^ (r & 7)) * 8),
              w2_s[buf] + (b * 256 + wave * 64) * 8);
    }
  };
  stageW(0, 0);
  asm volatile("s_waitcnt vmcnt(0)" ::: "memory");
  __syncthreads();   // publishes cont_s stores + w chunk0

  const int wtok = wave * 16;
  f32x4 acc2[4] = {};
  int cur = 0;
  for (int i = 0; i < HHALF / 64; ++i) {
    const int hc = i * 64;
    if (i + 1 < HHALF / 64) stageW(hc + 64, cur ^ 1);  // next chunk flies
    const __bf16* w1c = w1_s[cur];
    const __bf16* w2c = w2_s[cur];
    f32x4 acc1[4] = {};
    #pragma unroll
    for (int kk = 0; kk < 2; ++kk) {
      bf16x8 af, bfr[4];
      {
        int row = wtok + l16;
        af = *(const bf16x8*)(cont_s + row * 64 + (((kk * 4 + quad) ^ (row & 7)) * 8));
      }
      #pragma unroll
      for (int j = 0; j < 4; ++j) {
        int row = j * 16 + l16;
        bfr[j] = *(const bf16x8*)(w1c + row * 64 + (((kk * 4 + quad) ^ (row & 7)) * 8));
      }
      #pragma unroll
      for (int j = 0; j < 4; ++j)
        acc1[j] = __builtin_amdgcn_mfma_f32_16x16x32_bf16(af, bfr[j], acc1[j], 0, 0, 0);
    }
    // h = relu(acc1 + be1) -> wave-private h_s rows (no barrier needed)
    #pragma unroll
    for (int j = 0; j < 4; ++j)
      #pragma unroll
      for (int r = 0; r < 4; ++r) {
        int tr = wtok + quad * 4 + r;
        int hcol = j * 16 + l16;
        float v = acc1[j][r] + be1[e * HHALF + hc + hcol];
        h_s[tr * 64 + (((hcol >> 3) ^ (tr & 7)) * 8) + (hcol & 7)] =
            (__bf16)fmaxf(v, 0.0f);
      }
    #pragma unroll
    for (int kk = 0; kk < 2; ++kk) {
      bf16x8 af, bfr[4];
      {
        int row = wtok + l16;
        af = *(const bf16x8*)(h_s + row * 64 + (((kk * 4 + quad) ^ (row & 7)) * 8));
      }
      #pragma unroll
      for (int j = 0; j < 4; ++j) {
        int row = j * 16 + l16;
        bfr[j] = *(const bf16x8*)(w2c + row * 64 + (((kk * 4 + quad) ^ (row & 7)) * 8));
      }
      #pragma unroll
      for (int j = 0; j < 4; ++j)
        acc2[j] = __builtin_amdgcn_mfma_f32_16x16x32_bf16(af, bfr[j], acc2[j], 0, 0, 0);
    }
    if (i + 1 < HHALF / 64) {
      asm volatile("s_waitcnt vmcnt(0)" ::: "memory");  // next chunk landed
      __syncthreads();   // publish next; seal cur (overwritten at i+2)
      cur ^= 1;
    }
  }
  #pragma unroll
  for (int j = 0; j < 4; ++j)
    #pragma unroll
    for (int r = 0; r < 4; ++r) {
      int tr = wtok + quad * 4 + r;
      if (tr < nval) {
        unsigned v = tok_s[tr];
        unsigned tok = v & 0x7fffffffu;
        int m = j * 16 + l16;
        float o = gate_s[tr] * (acc2[j][r] + be2[e * 64 + m]);
        __bf16* slab = (v >> 31) ? slab1 : slab0;
        slab[(size_t)tok * 64 + m] = (__bf16)o;
      }
    }
}

__global__ __launch_bounds__(256) void ln_kernel(
    const float* __restrict__ x, const float* __restrict__ g,
    const float* __restrict__ b, float* __restrict__ out) {
  const int row = blockIdx.x;
  const float4 v = ((const float4*)(x + (size_t)row * 1024))[threadIdx.x];
  float s1 = v.x + v.y + v.z + v.w;
  float s2 = v.x * v.x + v.y * v.y + v.z * v.z + v.w * v.w;
  #pragma unroll
  for (int o = 32; o; o >>= 1) { s1 += __shfl_xor(s1, o); s2 += __shfl_xor(s2, o); }
  __shared__ float ws1[4], ws2[4];
  const int wave = threadIdx.x >> 6, lane = threadIdx.x & 63;
  if (lane == 0) { ws1[wave] = s1; ws2[wave] = s2; }
  __syncthreads();
  s1 = ws1[0] + ws1[1] + ws1[2] + ws1[3];
  s2 = ws2[0] + ws2[1] + ws2[2] + ws2[3];
  const float mu = s1 * (1.0f / 1024.0f);
  const float var = s2 * (1.0f / 1024.0f) - mu * mu;
  const float inv = rsqrtf(var + 1e-5f);
  const int col = threadIdx.x * 4;
  const float4 gv = *(const float4*)(g + col);
  const float4 bv = *(const float4*)(b + col);
  float4 o;
  o.x = (v.x - mu) * inv * gv.x + bv.x;
  o.y = (v.y - mu) * inv * gv.y + bv.y;
  o.z = (v.z - mu) * inv * gv.z + bv.z;
  o.w = (v.w - mu) * inv * gv.w + bv.w;
  *(float4*)(out + (size_t)row * 1024 + col) = o;
}

extern "C" void kernel_launch(void* const* d_in, const int* in_sizes, int n_in,
                              void* d_out, int out_size, void* d_ws, size_t ws_size,
                              hipStream_t stream) {
  const float* X     = (const float*)d_in[0];
  const float* enc_W = (const float*)d_in[1];
  const float* enc_b = (const float*)d_in[2];
  const float* s2c_W = (const float*)d_in[3];
  const float* s2c_b = (const float*)d_in[4];
  const float* rW1   = (const float*)d_in[5];
  const float* rb1   = (const float*)d_in[6];
  const float* rW2   = (const float*)d_in[7];
  const float* rb2   = (const float*)d_in[8];
  const float* We1   = (const float*)d_in[9];
  const float* be1   = (const float*)d_in[10];
  const float* We2   = (const float*)d_in[11];
  const float* be2   = (const float*)d_in[12];
  const float* c2s_W = (const float*)d_in[13];
  const float* c2s_b = (const float*)d_in[14];
  const float* dec_W = (const float*)d_in[15];
  const float* dec_b = (const float*)d_in[16];
  const float* ln_g  = (const float*)d_in[17];
  const float* ln_b  = (const float*)d_in[18];
  float* out = (float*)d_out;

  // ---- workspace layout with explicit aliasing (~78 MB total) ----
  char* ws = (char*)d_ws;
  size_t off = 0;
  auto take = [&](size_t bytes) -> char* {
    char* p = ws + off;
    off = (off + bytes + 255) & ~(size_t)255;
    return p;
  };
  const size_t SLAB = (size_t)TOK * HDIM * 2;       // 33,554,432
  char*   slabA     = take(SLAB);
  char*   slabB     = take(SLAB);
  __bf16* encWT     = (__bf16*)take((size_t)HDIM * DMODEL * 2);
  __bf16* s2cWT     = (__bf16*)take((size_t)MDIM * HDIM * 2);
  __bf16* c2sWT     = (__bf16*)take((size_t)HDIM * MDIM * 2);
  __bf16* decWT     = (__bf16*)take((size_t)DMODEL * HDIM * 2);
  __bf16* We1T      = (__bf16*)take((size_t)NEXP * HHALF * MDIM * 2);
  __bf16* We2T      = (__bf16*)take((size_t)NEXP * MDIM * HHALF * 2);
  __bf16* contB     = (__bf16*)take((size_t)TOK * MDIM * 2);
  int*    e01       = (int*)take((size_t)TOK * 4);
  float2* g01       = (float2*)take((size_t)TOK * 8);
  __bf16* oslab0    = (__bf16*)take((size_t)TOK * MDIM * 2);
  __bf16* oslab1    = (__bf16*)take((size_t)TOK * MDIM * 2);
  int*     cnt      = (int*)take((size_t)NEXP * 4);
  unsigned* idxb    = (unsigned*)take((size_t)NEXP * TOK * 4);
  if (off > ws_size) return;  // insufficient workspace -> clean correctness fail

  __bf16* Xb        = (__bf16*)slabA;                       // dead after GEMM1
  float*  contP     = (float*)(slabA + (size_t)TOK * DMODEL * 2);  // dead after router
  __bf16* spikesMoe = (__bf16*)slabA;                       // born at GEMM3
  __bf16* spikesEnc = (__bf16*)slabB;                       // dead after GEMM2
  float*  decoded   = (float*)slabB;                        // born at GEMM4

  // fused preamble: cvt(X) + 6 weight transposes in ONE launch
  preamble_kernel<<<PREAMBLE_BLOCKS, 256, 0, stream>>>(
      X, Xb, enc_W, encWT, s2c_W, s2cWT, c2s_W, c2sWT, dec_W, decWT,
      We1, We1T, We2, We2T);

  // GEMM1 (8-phase 256x256, R5 order, XCD-chunked swizzle; flat 256 blocks):
  // spikesEnc = sigmoid(X @ enc_W + b)  K=1024
  gemm_8p<256, 1, 1, 1, 1><<<256, 512, 0, stream>>>(
      Xb, encWT, enc_b, spikesEnc, TOK, HDIM, DMODEL);
  // GEMM2 (split-K x4, 8 waves -> 2/SIMD): contP[z] partials   8192x64, K=2048
  gemm_bt<128, 64, 8, 0, 0, 0, 0><<<dim3(TOK / 128, 1, 4), 512, 0, stream>>>(
      spikesEnc, s2cWT, nullptr, contP, TOK, MDIM, HDIM, nullptr);
  // router: reduce partials + bias, top-2 -> e01/g01 (+ zero cnt)
  router_kernel<<<TOK / 4, 256, 0, stream>>>(contP, s2c_b, rW1, rb1, rW2, rb2,
                                             contB, e01, g01, cnt);
  // fill: per-expert token lists (LDS-aggregated; 256 global atomics total)
  fill_kernel<<<TOK / 256, 256, 0, stream>>>(e01, cnt, idxb);
  // sparse MoE (top-2 only: 4.3 GFLOP vs 17.2 dense) -> rank-slabs
  moe_sparse_kernel<<<dim3(TOK / 64, NEXP), 256, 0, stream>>>(
      contB, We1T, We2T, be1, be2, idxb, cnt, g01, oslab0, oslab1);
  // GEMM3 (SUMA): spikesMoe = sigmoid((slab0+slab1) @ c2s_W + b)  8192x2048, K=64
  gemm_bt<128, 128, 4, 1, 1, 1, 1><<<dim3(TOK / 128, HDIM / 128, 1), 256, 0, stream>>>(
      oslab0, c2sWT, c2s_b, spikesMoe, TOK, HDIM, MDIM, oslab1);
  // GEMM4 (8-phase 256x128, R6 order, no swizzle): sigmoid(spikesMoe @ dec_W + b)
  gemm_8p<128, 0, 0, 1, 1><<<dim3(TOK / 256, DMODEL / 128), 512, 0, stream>>>(
      spikesMoe, decWT, dec_b, decoded, TOK, DMODEL, HDIM);
  ln_kernel<<<TOK, 256, 0, stream>>>(decoded, ln_g, ln_b, out);
}